// Round 6
// baseline (320.614 us; speedup 1.0000x reference)
//
#include <hip/hip_runtime.h>
#include <math.h>

typedef __bf16 bf16;
typedef __bf16 bf16x8 __attribute__((ext_vector_type(8)));
typedef __bf16 bf16x4 __attribute__((ext_vector_type(4)));
typedef float f32x2 __attribute__((ext_vector_type(2)));
typedef float f32x4 __attribute__((ext_vector_type(4)));
typedef float f32x16 __attribute__((ext_vector_type(16)));
typedef unsigned int uint;
typedef uint u32x4 __attribute__((ext_vector_type(4)));
typedef uint u32x2 __attribute__((ext_vector_type(2)));
typedef __bf16 bf16x8_a __attribute__((ext_vector_type(8), __may_alias__));
typedef uint u32x2_a __attribute__((ext_vector_type(2), __may_alias__));
typedef __bf16 bf16_a __attribute__((__may_alias__));

constexpr int BATCH = 2;
constexpr int SEQ   = 2048;
constexpr int HID   = 2048;
constexpr int NHEAD = 16;
constexpr int NKV   = 8;
constexpr int HD    = 128;
constexpr int MROWS = BATCH * SEQ; // 4096

#define DEVINL __device__ __forceinline__

DEVINL void async16(void* l, const void* g) {
  __builtin_amdgcn_global_load_lds((const __attribute__((address_space(1))) void*)g,
                                   (__attribute__((address_space(3))) void*)l, 16, 0, 0);
}

DEVINL f32x4 mfma16(bf16x8 a, bf16x8 b, f32x4 c) {
  return __builtin_amdgcn_mfma_f32_16x16x32_bf16(a, b, c, 0, 0, 0);
}
DEVINL f32x16 mfma32(bf16x8 a, bf16x8 b, f32x16 c) {
  return __builtin_amdgcn_mfma_f32_32x32x16_bf16(a, b, c, 0, 0, 0);
}

DEVINL f32x4 fzero4() { f32x4 z; z[0] = 0.f; z[1] = 0.f; z[2] = 0.f; z[3] = 0.f; return z; }

DEVINL float ex2(float x) {
#if __has_builtin(__builtin_amdgcn_exp2f)
  return __builtin_amdgcn_exp2f(x);
#else
  return __expf(x * 0.6931471805599453f);
#endif
}

DEVINL uint pkbf16(float lo, float hi) {
  unsigned short l = __builtin_bit_cast(unsigned short, (bf16)lo);
  unsigned short h = __builtin_bit_cast(unsigned short, (bf16)hi);
  return (uint)l | ((uint)h << 16);
}

// ---------------- elementwise cast f32 -> bf16 ----------------
__global__ __launch_bounds__(256) void cast_f32_bf16(const float* __restrict__ x,
                                                     bf16* __restrict__ y, int n) {
  int i = (blockIdx.x * 256 + threadIdx.x) * 4;
  if (i + 3 < n) {
    float4 v = *(const float4*)(x + i);
    bf16x4 o;
    o[0] = (bf16)v.x; o[1] = (bf16)v.y; o[2] = (bf16)v.z; o[3] = (bf16)v.w;
    *(bf16x4*)(y + i) = o;
  }
}

// ---------------- all-W transpose f32[K][N] -> bf16 WT[N][K], K=2048 ----------------
__global__ __launch_bounds__(256) void wtrans4(const float* __restrict__ Wq,
                                               const float* __restrict__ Wk,
                                               const float* __restrict__ Wv,
                                               const float* __restrict__ Wo,
                                               bf16* __restrict__ WqT, bf16* __restrict__ WkT,
                                               bf16* __restrict__ WvT, bf16* __restrict__ WoT) {
  __shared__ bf16 t[64][65];
  const float* W; bf16* WT; int N;
  switch (blockIdx.z) {
    case 0: W = Wq; WT = WqT; N = 2048; break;
    case 1: W = Wk; WT = WkT; N = 1024; break;
    case 2: W = Wv; WT = WvT; N = 1024; break;
    default: W = Wo; WT = WoT; N = 2048; break;
  }
  int n0 = blockIdx.x * 64, k0 = blockIdx.y * 64;
  if (n0 >= N) return;
  for (int i = threadIdx.x; i < 4096; i += 256) {
    int r = i >> 6, c = i & 63;
    t[r][c] = (bf16)W[(size_t)(k0 + r) * N + n0 + c];
  }
  __syncthreads();
  for (int i = threadIdx.x; i < 4096; i += 256) {
    int r = i >> 6, c = i & 63;
    WT[(size_t)(n0 + r) * 2048 + k0 + c] = t[c][r];
  }
}

// ---------------- V[b*S+s][kvh*128+d] -> VT[(b*8+kvh)*128+d][s] ----------------
__global__ __launch_bounds__(256) void vtrans(const bf16* __restrict__ V, bf16* __restrict__ VT) {
  __shared__ bf16 t[64][65];
  int s0 = blockIdx.x * 64, d0 = blockIdx.y * 64;
  int bh = blockIdx.z, b = bh >> 3, kvh = bh & 7;
  for (int i = threadIdx.x; i < 4096; i += 256) {
    int r = i >> 6, c = i & 63;
    t[r][c] = V[(size_t)(b * SEQ + s0 + r) * (NKV * HD) + kvh * HD + d0 + c];
  }
  __syncthreads();
  for (int i = threadIdx.x; i < 4096; i += 256) {
    int r = i >> 6, c = i & 63;
    VT[((size_t)bh * HD + d0 + r) * SEQ + s0 + c] = t[c][r];
  }
}

// ---------------- RoPE tables: cos/sin [SEQ][64] ----------------
__global__ void rope_tab(float* __restrict__ ct, float* __restrict__ st) {
  int s = blockIdx.x, d = threadIdx.x;
  float freq = powf(10000.0f, -(float)d * (1.0f / 64.0f));
  float a = (float)s * freq;
  ct[s * 64 + d] = cosf(a);
  st[s * 64 + d] = sinf(a);
}

// ---------------- 256x256-tile 8-wave GEMM, counted-vmcnt phase schedule ----------------
// Stage order per tile: A0, B0, A1, B1 (2 loads/thread each).
// P0: vmcnt(4) [A0,B0 ready], barrier, read A0+B0 frags, stage A0(t+1), MFMA Q00
// P1: vmcnt(2) [A1,B1 ready] (last tile: vmcnt(0)), barrier, read B1, stage B0(t+1), MFMA Q01
// P2: read A1, stage A1(t+1), MFMA Q11
// P3: stage B1(t+1), MFMA Q10   -> never drains fresh loads in steady state.
template <int EPI>
__global__ __launch_bounds__(512, 2) void gemm256(const bf16* __restrict__ A,
                                                  const bf16* __restrict__ BT,
                                                  void* __restrict__ C0, void* __restrict__ C1,
                                                  void* __restrict__ C2, int M, int N, int K,
                                                  const float* __restrict__ ct,
                                                  const float* __restrict__ st) {
  __shared__ alignas(16) char ldsA[65536];
  __shared__ alignas(16) char ldsB[65536];
  const int tid = threadIdx.x, lane = tid & 63, w = tid >> 6;
  const int l15 = lane & 15, l4 = lane >> 4;
  const int wm = w >> 2, wn = w & 3;
  const int gx = gridDim.x;
  const int nwg = gx * gridDim.y;
  int id = blockIdx.y * gx + blockIdx.x;
  id = (id & 7) * (nwg >> 3) + (id >> 3);
  const int row0 = (id / gx) * 256;
  const int col0 = (id % gx) * 256;

  f32x4 acc[8][4];
#pragma unroll
  for (int mt = 0; mt < 8; mt++)
#pragma unroll
    for (int nt = 0; nt < 4; nt++) acc[mt][nt] = fzero4();

  const int ci0 = w * 64 + lane;
  const int rG0 = ci0 >> 3, sG0 = ((ci0 & 7) ^ (rG0 & 7)) * 8;
  const int ci1 = 512 + ci0;
  const int rG1 = ci1 >> 3, sG1 = ((ci1 & 7) ^ (rG1 & 7)) * 8;
  const int dst0 = (w * 64) * 16, dst1 = (512 + w * 64) * 16;

  const bf16* Asrc = A + (size_t)row0 * K;
  const bf16* Bsrc = BT + (size_t)col0 * K;

  const int nk = K >> 6;

#define STG_A(half, kt, buf)                                                     \
  {                                                                              \
    char* d = ldsA + (buf) * 32768 + (half) * 16384;                             \
    const bf16* s = Asrc + (size_t)((half) * 128) * K + (kt) * 64;               \
    async16(d + dst0, s + (size_t)rG0 * K + sG0);                                \
    async16(d + dst1, s + (size_t)rG1 * K + sG1);                                \
  }
#define STG_B(half, kt, buf)                                                     \
  {                                                                              \
    char* d = ldsB + (buf) * 32768 + (half) * 16384;                             \
    const bf16* s = Bsrc + (size_t)((half) * 128) * K + (kt) * 64;               \
    async16(d + dst0, s + (size_t)rG0 * K + sG0);                                \
    async16(d + dst1, s + (size_t)rG1 * K + sG1);                                \
  }

  // prologue: stage tile 0 in consumption order
  STG_A(0, 0, 0) STG_B(0, 0, 0) STG_A(1, 0, 0) STG_B(1, 0, 0)

  bf16x8 af[8];
  bf16x8 bfr[2][4];

  for (int t = 0; t < nk; ++t) {
    const int buf = t & 1;
    const char* bA = ldsA + buf * 32768;
    const char* bB = ldsB + buf * 32768;
    const bool stg = (t + 1) < nk;
    const int nbuf = buf ^ 1;

    // ---- P0: needs A0,B0 of cur ----
    asm volatile("s_waitcnt vmcnt(4)" ::: "memory");
    __syncthreads();
    if (stg) STG_A(0, t + 1, nbuf)
#pragma unroll
    for (int mtp = 0; mtp < 4; mtp++)
#pragma unroll
      for (int kc = 0; kc < 2; kc++) {
        int r = wm * 128 + mtp * 16 + l15;
        int off = ((r << 7) + ((kc * 4 + l4) << 4)) ^ ((r & 7) << 4);
        af[mtp * 2 + kc] = *(const bf16x8_a*)(bA + off);
      }
#pragma unroll
    for (int ntp = 0; ntp < 2; ntp++)
#pragma unroll
      for (int kc = 0; kc < 2; kc++) {
        int c = wn * 16 + ntp * 64 + l15;
        int off = ((c << 7) + ((kc * 4 + l4) << 4)) ^ ((c & 7) << 4);
        bfr[0][ntp * 2 + kc] = *(const bf16x8_a*)(bB + off);
      }
    __builtin_amdgcn_s_setprio(1);
#pragma unroll
    for (int mtp = 0; mtp < 4; mtp++)
#pragma unroll
      for (int ntp = 0; ntp < 2; ntp++)
#pragma unroll
        for (int kc = 0; kc < 2; kc++)
          acc[mtp][ntp] = mfma16(af[mtp * 2 + kc], bfr[0][ntp * 2 + kc], acc[mtp][ntp]);
    __builtin_amdgcn_s_setprio(0);

    // ---- P1: needs B1 (and A1 for P2) of cur ----
    if (stg) {
      asm volatile("s_waitcnt vmcnt(2)" ::: "memory");
    } else {
      asm volatile("s_waitcnt vmcnt(0)" ::: "memory");
    }
    __syncthreads();
    if (stg) STG_B(0, t + 1, nbuf)
#pragma unroll
    for (int ntp = 0; ntp < 2; ntp++)
#pragma unroll
      for (int kc = 0; kc < 2; kc++) {
        int c = wn * 16 + (ntp + 2) * 64 + l15;
        int off = ((c << 7) + ((kc * 4 + l4) << 4)) ^ ((c & 7) << 4);
        bfr[1][ntp * 2 + kc] = *(const bf16x8_a*)(bB + off);
      }
    __builtin_amdgcn_s_setprio(1);
#pragma unroll
    for (int mtp = 0; mtp < 4; mtp++)
#pragma unroll
      for (int ntp = 0; ntp < 2; ntp++)
#pragma unroll
        for (int kc = 0; kc < 2; kc++)
          acc[mtp][ntp + 2] = mfma16(af[mtp * 2 + kc], bfr[1][ntp * 2 + kc], acc[mtp][ntp + 2]);
    __builtin_amdgcn_s_setprio(0);

    // ---- P2: read A1 of cur (valid since P1 wait+barrier) ----
    if (stg) STG_A(1, t + 1, nbuf)
#pragma unroll
    for (int mtp = 0; mtp < 4; mtp++)
#pragma unroll
      for (int kc = 0; kc < 2; kc++) {
        int r = wm * 128 + 64 + mtp * 16 + l15;
        int off = ((r << 7) + ((kc * 4 + l4) << 4)) ^ ((r & 7) << 4);
        af[mtp * 2 + kc] = *(const bf16x8_a*)(bA + off);
      }
    __builtin_amdgcn_s_setprio(1);
#pragma unroll
    for (int mtp = 0; mtp < 4; mtp++)
#pragma unroll
      for (int ntp = 0; ntp < 2; ntp++)
#pragma unroll
        for (int kc = 0; kc < 2; kc++)
          acc[mtp + 4][ntp + 2] = mfma16(af[mtp * 2 + kc], bfr[1][ntp * 2 + kc], acc[mtp + 4][ntp + 2]);
    __builtin_amdgcn_s_setprio(0);

    // ---- P3: reuse A1 x B0 ----
    if (stg) STG_B(1, t + 1, nbuf)
    __builtin_amdgcn_s_setprio(1);
#pragma unroll
    for (int mtp = 0; mtp < 4; mtp++)
#pragma unroll
      for (int ntp = 0; ntp < 2; ntp++)
#pragma unroll
        for (int kc = 0; kc < 2; kc++)
          acc[mtp + 4][ntp] = mfma16(af[mtp * 2 + kc], bfr[0][ntp * 2 + kc], acc[mtp + 4][ntp]);
    __builtin_amdgcn_s_setprio(0);
  }
#undef STG_A
#undef STG_B

#pragma unroll
  for (int mt = 0; mt < 8; mt++)
#pragma unroll
    for (int nt = 0; nt < 4; nt++)
#pragma unroll
      for (int rg = 0; rg < 4; rg++) {
        int row = row0 + wm * 128 + mt * 16 + l4 * 4 + rg;
        int cl = col0 + wn * 16 + nt * 64 + l15;
        float v = acc[mt][nt][rg];
        if (EPI == 2) {
          ((float*)C0)[(size_t)row * N + cl] = v;
        } else {
          if (cl < 3072) {
            int s = row & (SEQ - 1);
            float cc = ct[s * 64 + wn * 16 + l15];
            float ss = st[s * 64 + wn * 16 + l15];
            float pv = acc[mt][nt ^ 1][rg];
            v = (nt & 1) ? fmaf(v, cc, pv * ss) : fmaf(v, cc, -pv * ss);
          }
          if (cl < 2048)
            ((bf16*)C0)[(size_t)row * 2048 + cl] = (bf16)v;
          else if (cl < 3072)
            ((bf16*)C1)[(size_t)row * 1024 + (cl - 2048)] = (bf16)v;
          else
            ((bf16*)C2)[(size_t)row * 1024 + (cl - 3072)] = (bf16)v;
        }
      }
}

// ---------------- Flash attention v5: 16-slot K swizzle + packed softcap ----------------
__global__ __launch_bounds__(256, 2) void attn5(const bf16* __restrict__ Q,
                                                const bf16* __restrict__ Kg,
                                                const bf16* __restrict__ VTg,
                                                bf16* __restrict__ O) {
  __shared__ alignas(16) char ldsK[32768];   // 2 x [64 kv][128 d], 16-slot swizzle
  __shared__ alignas(16) char ldsV[32768];   // 2 x [128 d][64 kv], 8-slot swizzle
  const int tid = threadIdx.x, lane = tid & 63, w = tid >> 6;
  const int l31 = lane & 31, hl = lane >> 5;

  const int nx = gridDim.x, ny = gridDim.y;
  const int nwg = nx * ny * gridDim.z;  // 512
  int id = (blockIdx.z * ny + blockIdx.y) * nx + blockIdx.x;
  id = (id & 7) * (nwg >> 3) + (id >> 3);
  const int qt = id % nx; id /= nx;
  const int h = id % ny; const int b = id / ny;
  const int kvh = h >> 1;
  const int qrow = b * SEQ + qt * 128 + w * 32 + l31;

  // Q B-fragments: col=q=l31, k(d) = kc*16 + hl*8 + j
  bf16x8 qf[8];
  const bf16* qp = Q + (size_t)qrow * (NHEAD * HD) + h * HD + hl * 8;
#pragma unroll
  for (int kc = 0; kc < 8; kc++) qf[kc] = *(const bf16x8_a*)(qp + kc * 16);

  f32x16 oT[4];
#pragma unroll
  for (int dt = 0; dt < 4; dt++)
#pragma unroll
    for (int r = 0; r < 16; r++) oT[dt][r] = 0.f;
  f32x2 ls2; ls2[0] = 0.f; ls2[1] = 0.f;

  // staging (linear LDS dest, inverse-swizzled global source)
  const int dstc = tid * 16;
  const int rK = tid >> 4, lsK = (tid & 15) ^ rK;        // 16-slot swizzle
  const int rV = tid >> 3, lsV = (tid & 7) ^ (rV & 7);   // 8-slot swizzle
  const size_t koff0 = (size_t)(b * SEQ + rK) * (NKV * HD) + kvh * HD + lsK * 8;
  const size_t voff0 = ((size_t)(b * NKV + kvh) * HD + rV) * SEQ + lsV * 8;

  const float C1 = 1.7677669529663689e-3f;  // 1/(50*sqrt(128))
  const float CA = -0.33333333333f;         // tanh poly
  const float CB = 0.13333333333f;          // 2/15
  const float C2 = 72.13475204444817f;      // 50*log2(e)

  auto STAGE = [&](int buf, int t) {
    char* dK = ldsK + buf * 16384 + dstc;
    char* dV = ldsV + buf * 16384 + dstc;
    const bf16* ks = Kg + koff0 + (size_t)t * (64 * NKV * HD);
    const bf16* vs = VTg + voff0 + (size_t)t * 64;
#pragma unroll
    for (int j = 0; j < 4; j++) async16(dK + j * 4096, ks + j * 16 * (NKV * HD));
#pragma unroll
    for (int j = 0; j < 4; j++) async16(dV + j * 4096, vs + (size_t)j * 32 * SEQ);
  };

  STAGE(0, 0);
  asm volatile("s_waitcnt vmcnt(0)" ::: "memory");
  __syncthreads();

  for (int t = 0; t < SEQ / 64; ++t) {
    const int cur = t & 1;
    STAGE(cur ^ 1, (t + 1) & (SEQ / 64 - 1));  // issue next-tile loads first

    const char* lK = ldsK + cur * 16384;
    const char* lV = ldsV + cur * 16384;

    // ---- swapped QK^T: S^T[64 kv][32 q] ----
    f32x16 sc[2];
#pragma unroll
    for (int r = 0; r < 16; r++) { sc[0][r] = 0.f; sc[1][r] = 0.f; }
    const int kvr0 = l31;
    const int kvr1 = 32 + l31;
    __builtin_amdgcn_s_setprio(1);
#pragma unroll
    for (int kc = 0; kc < 8; kc++) {
      int slot = kc * 2 + hl;
      int off0 = (kvr0 << 8) | ((slot ^ (kvr0 & 15)) << 4);
      int off1 = (kvr1 << 8) | ((slot ^ (kvr1 & 15)) << 4);
      bf16x8 kf0 = *(const bf16x8_a*)(lK + off0);
      bf16x8 kf1 = *(const bf16x8_a*)(lK + off1);
      sc[0] = mfma32(kf0, qf[kc], sc[0]);
      sc[1] = mfma32(kf1, qf[kc], sc[1]);
    }
    __builtin_amdgcn_s_setprio(0);

    // ---- softcap+exp (packed f32x2 poly tanh, fixed max) + PV ----
#pragma unroll
    for (int ntb = 0; ntb < 2; ntb++) {
      uint u[4][2], us[4][2];
#pragma unroll
      for (int r2 = 0; r2 < 8; r2++) {
        f32x2 s2; s2[0] = sc[ntb][2 * r2]; s2[1] = sc[ntb][2 * r2 + 1];
        f32x2 z = s2 * C1;
        f32x2 z2 = z * z;
        f32x2 wv = z2 * (z2 * CB + CA) + 1.0f;
        f32x2 e = (z * wv) * C2;
        float p0 = ex2(e[0]), p1 = ex2(e[1]);
        ls2[0] += p0; ls2[1] += p1;
        uint uu = pkbf16(p0, p1);
        u[r2 >> 1][r2 & 1] = uu;
        us[r2 >> 1][r2 & 1] = __shfl_xor(uu, 32);
      }
      __builtin_amdgcn_s_setprio(1);
#pragma unroll
      for (int sub = 0; sub < 2; sub++) {
        u32x4 bu;
        bu[0] = hl ? us[2 * sub + 1][0] : u[2 * sub][0];
        bu[1] = hl ? us[2 * sub + 1][1] : u[2 * sub][1];
        bu[2] = hl ? u[2 * sub + 1][0] : us[2 * sub][0];
        bu[3] = hl ? u[2 * sub + 1][1] : us[2 * sub][1];
        bf16x8 pb = __builtin_bit_cast(bf16x8, bu);
        const int kvb = ntb * 2 + sub;
        const int slot = kvb * 2 + hl;
#pragma unroll
        for (int dt = 0; dt < 4; dt++) {
          int d = dt * 32 + l31;
          int off = (d << 7) | ((slot ^ (d & 7)) << 4);
          bf16x8 vf = *(const bf16x8_a*)(lV + off);
          oT[dt] = mfma32(vf, pb, oT[dt]);
        }
      }
      __builtin_amdgcn_s_setprio(0);
    }

    asm volatile("s_waitcnt vmcnt(0)" ::: "memory");  // next tile staged
    __syncthreads();
  }

  // ---- epilogue ----
  float lsum = ls2[0] + ls2[1];
  float lsf = lsum + __shfl_xor(lsum, 32);
  float inv = 1.0f / lsf;
  bf16* ob = O + (size_t)qrow * (NHEAD * HD) + h * HD;
#pragma unroll
  for (int dt = 0; dt < 4; dt++)
#pragma unroll
    for (int g = 0; g < 4; g++) {
      u32x2 pr;
      pr[0] = pkbf16(oT[dt][4 * g] * inv, oT[dt][4 * g + 1] * inv);
      pr[1] = pkbf16(oT[dt][4 * g + 2] * inv, oT[dt][4 * g + 3] * inv);
      *(u32x2_a*)(ob + dt * 32 + 8 * g + 4 * hl) = pr;
    }
}

extern "C" void kernel_launch(void* const* d_in, const int* in_sizes, int n_in,
                              void* d_out, int out_size, void* d_ws, size_t ws_size,
                              hipStream_t stream) {
  const float* X  = (const float*)d_in[0];
  const float* Wq = (const float*)d_in[1];
  const float* Wk = (const float*)d_in[2];
  const float* Wv = (const float*)d_in[3];
  const float* Wo = (const float*)d_in[4];
  float* out = (float*)d_out;

  char* ws = (char*)d_ws;
  size_t off = 0;
  auto alloc = [&](size_t bytes) {
    void* p = ws + off;
    off += (bytes + 255) & ~(size_t)255;
    return p;
  };
  bf16* Xb  = (bf16*)alloc((size_t)MROWS * HID * 2);
  // WqT/WkT/WvT adjacent & contiguous -> fused BT [4096][2048]
  bf16* WqT = (bf16*)alloc((size_t)2048 * 2048 * 2);
  bf16* WkT = (bf16*)alloc((size_t)1024 * 2048 * 2);
  bf16* WvT = (bf16*)alloc((size_t)1024 * 2048 * 2);
  bf16* WoT = (bf16*)alloc((size_t)2048 * 2048 * 2);
  bf16* Qb  = (bf16*)alloc((size_t)MROWS * 2048 * 2);
  bf16* Kb  = (bf16*)alloc((size_t)MROWS * 1024 * 2);
  bf16* Vb  = (bf16*)alloc((size_t)MROWS * 1024 * 2);
  bf16* VTb = (bf16*)alloc((size_t)16 * 128 * 2048 * 2);
  bf16* AOb = (bf16*)alloc((size_t)MROWS * 2048 * 2);
  float* ct = (float*)alloc((size_t)SEQ * 64 * 4);
  float* st = (float*)alloc((size_t)SEQ * 64 * 4);

  cast_f32_bf16<<<(MROWS * HID) / 1024, 256, 0, stream>>>(X, Xb, MROWS * HID);
  wtrans4<<<dim3(32, 32, 4), 256, 0, stream>>>(Wq, Wk, Wv, Wo, WqT, WkT, WvT, WoT);
  rope_tab<<<SEQ, 64, 0, stream>>>(ct, st);
  gemm256<1><<<dim3(16, 16), 512, 0, stream>>>(Xb, WqT, Qb, Kb, Vb, MROWS, 4096, 2048, ct, st);
  vtrans<<<dim3(32, 2, 16), 256, 0, stream>>>(Vb, VTb);
  attn5<<<dim3(16, 16, 2), 256, 0, stream>>>(Qb, Kb, VTb, AOb);
  gemm256<2><<<dim3(8, 16), 512, 0, stream>>>(AOb, WoT, out, nullptr, nullptr, MROWS, 2048, 2048,
                                              nullptr, nullptr);

  (void)in_sizes; (void)n_in; (void)out_size; (void)ws_size;
}

// Round 7
// 311.338 us; speedup vs baseline: 1.0298x; 1.0298x over previous
//
#include <hip/hip_runtime.h>
#include <math.h>

typedef __bf16 bf16;
typedef __bf16 bf16x8 __attribute__((ext_vector_type(8)));
typedef __bf16 bf16x4 __attribute__((ext_vector_type(4)));
typedef float f32x2 __attribute__((ext_vector_type(2)));
typedef float f32x4 __attribute__((ext_vector_type(4)));
typedef float f32x16 __attribute__((ext_vector_type(16)));
typedef unsigned int uint;
typedef uint u32x4 __attribute__((ext_vector_type(4)));
typedef uint u32x2 __attribute__((ext_vector_type(2)));
typedef __bf16 bf16x8_a __attribute__((ext_vector_type(8), __may_alias__));
typedef uint u32x2_a __attribute__((ext_vector_type(2), __may_alias__));
typedef __bf16 bf16_a __attribute__((__may_alias__));

constexpr int BATCH = 2;
constexpr int SEQ   = 2048;
constexpr int HID   = 2048;
constexpr int NHEAD = 16;
constexpr int NKV   = 8;
constexpr int HD    = 128;
constexpr int MROWS = BATCH * SEQ; // 4096

#define DEVINL __device__ __forceinline__

// counted-vmcnt wait + RAW barrier (no implicit vmcnt(0) drain like __syncthreads)
#define VMCNT_BAR(N)                                          \
  do {                                                        \
    asm volatile("s_waitcnt vmcnt(" #N ")" ::: "memory");     \
    __builtin_amdgcn_s_barrier();                             \
    asm volatile("" ::: "memory");                            \
  } while (0)

DEVINL void async16(void* l, const void* g) {
  __builtin_amdgcn_global_load_lds((const __attribute__((address_space(1))) void*)g,
                                   (__attribute__((address_space(3))) void*)l, 16, 0, 0);
}

DEVINL f32x4 mfma16(bf16x8 a, bf16x8 b, f32x4 c) {
  return __builtin_amdgcn_mfma_f32_16x16x32_bf16(a, b, c, 0, 0, 0);
}
DEVINL f32x16 mfma32(bf16x8 a, bf16x8 b, f32x16 c) {
  return __builtin_amdgcn_mfma_f32_32x32x16_bf16(a, b, c, 0, 0, 0);
}

DEVINL f32x4 fzero4() { f32x4 z; z[0] = 0.f; z[1] = 0.f; z[2] = 0.f; z[3] = 0.f; return z; }

DEVINL float ex2(float x) {
#if __has_builtin(__builtin_amdgcn_exp2f)
  return __builtin_amdgcn_exp2f(x);
#else
  return __expf(x * 0.6931471805599453f);
#endif
}

DEVINL uint pkbf16(float lo, float hi) {
  unsigned short l = __builtin_bit_cast(unsigned short, (bf16)lo);
  unsigned short h = __builtin_bit_cast(unsigned short, (bf16)hi);
  return (uint)l | ((uint)h << 16);
}

// ---------------- elementwise cast f32 -> bf16 ----------------
__global__ __launch_bounds__(256) void cast_f32_bf16(const float* __restrict__ x,
                                                     bf16* __restrict__ y, int n) {
  int i = (blockIdx.x * 256 + threadIdx.x) * 4;
  if (i + 3 < n) {
    float4 v = *(const float4*)(x + i);
    bf16x4 o;
    o[0] = (bf16)v.x; o[1] = (bf16)v.y; o[2] = (bf16)v.z; o[3] = (bf16)v.w;
    *(bf16x4*)(y + i) = o;
  }
}

// ---------------- all-W transpose f32[K][N] -> bf16 WT[N][K], K=2048 ----------------
__global__ __launch_bounds__(256) void wtrans4(const float* __restrict__ Wq,
                                               const float* __restrict__ Wk,
                                               const float* __restrict__ Wv,
                                               const float* __restrict__ Wo,
                                               bf16* __restrict__ WqT, bf16* __restrict__ WkT,
                                               bf16* __restrict__ WvT, bf16* __restrict__ WoT) {
  __shared__ bf16 t[64][65];
  const float* W; bf16* WT; int N;
  switch (blockIdx.z) {
    case 0: W = Wq; WT = WqT; N = 2048; break;
    case 1: W = Wk; WT = WkT; N = 1024; break;
    case 2: W = Wv; WT = WvT; N = 1024; break;
    default: W = Wo; WT = WoT; N = 2048; break;
  }
  int n0 = blockIdx.x * 64, k0 = blockIdx.y * 64;
  if (n0 >= N) return;
  for (int i = threadIdx.x; i < 4096; i += 256) {
    int r = i >> 6, c = i & 63;
    t[r][c] = (bf16)W[(size_t)(k0 + r) * N + n0 + c];
  }
  __syncthreads();
  for (int i = threadIdx.x; i < 4096; i += 256) {
    int r = i >> 6, c = i & 63;
    WT[(size_t)(n0 + r) * 2048 + k0 + c] = t[c][r];
  }
}

// ---------------- V[b*S+s][kvh*128+d] -> VT[(b*8+kvh)*128+d][s] ----------------
__global__ __launch_bounds__(256) void vtrans(const bf16* __restrict__ V, bf16* __restrict__ VT) {
  __shared__ bf16 t[64][65];
  int s0 = blockIdx.x * 64, d0 = blockIdx.y * 64;
  int bh = blockIdx.z, b = bh >> 3, kvh = bh & 7;
  for (int i = threadIdx.x; i < 4096; i += 256) {
    int r = i >> 6, c = i & 63;
    t[r][c] = V[(size_t)(b * SEQ + s0 + r) * (NKV * HD) + kvh * HD + d0 + c];
  }
  __syncthreads();
  for (int i = threadIdx.x; i < 4096; i += 256) {
    int r = i >> 6, c = i & 63;
    VT[((size_t)bh * HD + d0 + r) * SEQ + s0 + c] = t[c][r];
  }
}

// ---------------- RoPE tables: cos/sin [SEQ][64] ----------------
__global__ void rope_tab(float* __restrict__ ct, float* __restrict__ st) {
  int s = blockIdx.x, d = threadIdx.x;
  float freq = powf(10000.0f, -(float)d * (1.0f / 64.0f));
  float a = (float)s * freq;
  ct[s * 64 + d] = cosf(a);
  st[s * 64 + d] = sinf(a);
}

// ---------------- 256x256-tile 8-wave GEMM, counted-vmcnt + RAW barriers ----------------
// Stage order per tile: A0, B0, A1, B1 (2 loads/thread each).
// P0: vmcnt(4)+bar [A0,B0 ready], stage A0(t+1), read A0+B0, MFMA Q00
// P1: vmcnt(2)+bar [A1,B1 ready] (last: vmcnt(0)), stage B0(t+1), read B1, MFMA Q01
// P2: read A1, stage A1(t+1), MFMA Q11
// P3: stage B1(t+1), MFMA Q10   -> steady state never drains fresh loads.
template <int EPI>
__global__ __launch_bounds__(512, 2) void gemm256(const bf16* __restrict__ A,
                                                  const bf16* __restrict__ BT,
                                                  void* __restrict__ C0, void* __restrict__ C1,
                                                  void* __restrict__ C2, int M, int N, int K,
                                                  const float* __restrict__ ct,
                                                  const float* __restrict__ st) {
  __shared__ alignas(16) char ldsA[65536];
  __shared__ alignas(16) char ldsB[65536];
  const int tid = threadIdx.x, lane = tid & 63, w = tid >> 6;
  const int l15 = lane & 15, l4 = lane >> 4;
  const int wm = w >> 2, wn = w & 3;
  const int gx = gridDim.x;
  const int nwg = gx * gridDim.y;
  int id = blockIdx.y * gx + blockIdx.x;
  id = (id & 7) * (nwg >> 3) + (id >> 3);
  const int row0 = (id / gx) * 256;
  const int col0 = (id % gx) * 256;

  f32x4 acc[8][4];
#pragma unroll
  for (int mt = 0; mt < 8; mt++)
#pragma unroll
    for (int nt = 0; nt < 4; nt++) acc[mt][nt] = fzero4();

  const int ci0 = w * 64 + lane;
  const int rG0 = ci0 >> 3, sG0 = ((ci0 & 7) ^ (rG0 & 7)) * 8;
  const int ci1 = 512 + ci0;
  const int rG1 = ci1 >> 3, sG1 = ((ci1 & 7) ^ (rG1 & 7)) * 8;
  const int dst0 = (w * 64) * 16, dst1 = (512 + w * 64) * 16;

  const bf16* Asrc = A + (size_t)row0 * K;
  const bf16* Bsrc = BT + (size_t)col0 * K;

  const int nk = K >> 6;

#define STG_A(half, kt, buf)                                                     \
  {                                                                              \
    char* d = ldsA + (buf) * 32768 + (half) * 16384;                             \
    const bf16* s = Asrc + (size_t)((half) * 128) * K + (kt) * 64;               \
    async16(d + dst0, s + (size_t)rG0 * K + sG0);                                \
    async16(d + dst1, s + (size_t)rG1 * K + sG1);                                \
  }
#define STG_B(half, kt, buf)                                                     \
  {                                                                              \
    char* d = ldsB + (buf) * 32768 + (half) * 16384;                             \
    const bf16* s = Bsrc + (size_t)((half) * 128) * K + (kt) * 64;               \
    async16(d + dst0, s + (size_t)rG0 * K + sG0);                                \
    async16(d + dst1, s + (size_t)rG1 * K + sG1);                                \
  }

  // prologue: stage tile 0 in consumption order
  STG_A(0, 0, 0) STG_B(0, 0, 0) STG_A(1, 0, 0) STG_B(1, 0, 0)

  bf16x8 af[8];
  bf16x8 bfr[2][4];

  for (int t = 0; t < nk; ++t) {
    const int buf = t & 1;
    const char* bA = ldsA + buf * 32768;
    const char* bB = ldsB + buf * 32768;
    const bool stg = (t + 1) < nk;
    const int nbuf = buf ^ 1;

    // ---- P0: needs A0,B0 of cur ----
    VMCNT_BAR(4);
    if (stg) STG_A(0, t + 1, nbuf)
#pragma unroll
    for (int mtp = 0; mtp < 4; mtp++)
#pragma unroll
      for (int kc = 0; kc < 2; kc++) {
        int r = wm * 128 + mtp * 16 + l15;
        int off = ((r << 7) + ((kc * 4 + l4) << 4)) ^ ((r & 7) << 4);
        af[mtp * 2 + kc] = *(const bf16x8_a*)(bA + off);
      }
#pragma unroll
    for (int ntp = 0; ntp < 2; ntp++)
#pragma unroll
      for (int kc = 0; kc < 2; kc++) {
        int c = wn * 16 + ntp * 64 + l15;
        int off = ((c << 7) + ((kc * 4 + l4) << 4)) ^ ((c & 7) << 4);
        bfr[0][ntp * 2 + kc] = *(const bf16x8_a*)(bB + off);
      }
    __builtin_amdgcn_s_setprio(1);
#pragma unroll
    for (int mtp = 0; mtp < 4; mtp++)
#pragma unroll
      for (int ntp = 0; ntp < 2; ntp++)
#pragma unroll
        for (int kc = 0; kc < 2; kc++)
          acc[mtp][ntp] = mfma16(af[mtp * 2 + kc], bfr[0][ntp * 2 + kc], acc[mtp][ntp]);
    __builtin_amdgcn_s_setprio(0);

    // ---- P1: needs A1,B1 of cur ----
    if (stg) {
      VMCNT_BAR(2);
    } else {
      VMCNT_BAR(0);
    }
    if (stg) STG_B(0, t + 1, nbuf)
#pragma unroll
    for (int ntp = 0; ntp < 2; ntp++)
#pragma unroll
      for (int kc = 0; kc < 2; kc++) {
        int c = wn * 16 + (ntp + 2) * 64 + l15;
        int off = ((c << 7) + ((kc * 4 + l4) << 4)) ^ ((c & 7) << 4);
        bfr[1][ntp * 2 + kc] = *(const bf16x8_a*)(bB + off);
      }
    __builtin_amdgcn_s_setprio(1);
#pragma unroll
    for (int mtp = 0; mtp < 4; mtp++)
#pragma unroll
      for (int ntp = 0; ntp < 2; ntp++)
#pragma unroll
        for (int kc = 0; kc < 2; kc++)
          acc[mtp][ntp + 2] = mfma16(af[mtp * 2 + kc], bfr[1][ntp * 2 + kc], acc[mtp][ntp + 2]);
    __builtin_amdgcn_s_setprio(0);

    // ---- P2: read A1 of cur ----
    if (stg) STG_A(1, t + 1, nbuf)
#pragma unroll
    for (int mtp = 0; mtp < 4; mtp++)
#pragma unroll
      for (int kc = 0; kc < 2; kc++) {
        int r = wm * 128 + 64 + mtp * 16 + l15;
        int off = ((r << 7) + ((kc * 4 + l4) << 4)) ^ ((r & 7) << 4);
        af[mtp * 2 + kc] = *(const bf16x8_a*)(bA + off);
      }
    __builtin_amdgcn_s_setprio(1);
#pragma unroll
    for (int mtp = 0; mtp < 4; mtp++)
#pragma unroll
      for (int ntp = 0; ntp < 2; ntp++)
#pragma unroll
        for (int kc = 0; kc < 2; kc++)
          acc[mtp + 4][ntp + 2] = mfma16(af[mtp * 2 + kc], bfr[1][ntp * 2 + kc], acc[mtp + 4][ntp + 2]);
    __builtin_amdgcn_s_setprio(0);

    // ---- P3: reuse A1 x B0 ----
    if (stg) STG_B(1, t + 1, nbuf)
    __builtin_amdgcn_s_setprio(1);
#pragma unroll
    for (int mtp = 0; mtp < 4; mtp++)
#pragma unroll
      for (int ntp = 0; ntp < 2; ntp++)
#pragma unroll
        for (int kc = 0; kc < 2; kc++)
          acc[mtp + 4][ntp] = mfma16(af[mtp * 2 + kc], bfr[0][ntp * 2 + kc], acc[mtp + 4][ntp]);
    __builtin_amdgcn_s_setprio(0);
  }
#undef STG_A
#undef STG_B

#pragma unroll
  for (int mt = 0; mt < 8; mt++)
#pragma unroll
    for (int nt = 0; nt < 4; nt++)
#pragma unroll
      for (int rg = 0; rg < 4; rg++) {
        int row = row0 + wm * 128 + mt * 16 + l4 * 4 + rg;
        int cl = col0 + wn * 16 + nt * 64 + l15;
        float v = acc[mt][nt][rg];
        if (EPI == 2) {
          ((float*)C0)[(size_t)row * N + cl] = v;
        } else {
          if (cl < 3072) {
            int s = row & (SEQ - 1);
            float cc = ct[s * 64 + wn * 16 + l15];
            float ss = st[s * 64 + wn * 16 + l15];
            float pv = acc[mt][nt ^ 1][rg];
            v = (nt & 1) ? fmaf(v, cc, pv * ss) : fmaf(v, cc, -pv * ss);
          }
          if (cl < 2048)
            ((bf16*)C0)[(size_t)row * 2048 + cl] = (bf16)v;
          else if (cl < 3072)
            ((bf16*)C1)[(size_t)row * 1024 + (cl - 2048)] = (bf16)v;
          else
            ((bf16*)C2)[(size_t)row * 1024 + (cl - 3072)] = (bf16)v;
        }
      }
}

// ---------------- Flash attention v5 (raw barriers) ----------------
__global__ __launch_bounds__(256, 2) void attn5(const bf16* __restrict__ Q,
                                                const bf16* __restrict__ Kg,
                                                const bf16* __restrict__ VTg,
                                                bf16* __restrict__ O) {
  __shared__ alignas(16) char ldsK[32768];   // 2 x [64 kv][128 d], 16-slot swizzle
  __shared__ alignas(16) char ldsV[32768];   // 2 x [128 d][64 kv], 8-slot swizzle
  const int tid = threadIdx.x, lane = tid & 63, w = tid >> 6;
  const int l31 = lane & 31, hl = lane >> 5;

  const int nx = gridDim.x, ny = gridDim.y;
  const int nwg = nx * ny * gridDim.z;  // 512
  int id = (blockIdx.z * ny + blockIdx.y) * nx + blockIdx.x;
  id = (id & 7) * (nwg >> 3) + (id >> 3);
  const int qt = id % nx; id /= nx;
  const int h = id % ny; const int b = id / ny;
  const int kvh = h >> 1;
  const int qrow = b * SEQ + qt * 128 + w * 32 + l31;

  bf16x8 qf[8];
  const bf16* qp = Q + (size_t)qrow * (NHEAD * HD) + h * HD + hl * 8;
#pragma unroll
  for (int kc = 0; kc < 8; kc++) qf[kc] = *(const bf16x8_a*)(qp + kc * 16);

  f32x16 oT[4];
#pragma unroll
  for (int dt = 0; dt < 4; dt++)
#pragma unroll
    for (int r = 0; r < 16; r++) oT[dt][r] = 0.f;
  f32x2 ls2; ls2[0] = 0.f; ls2[1] = 0.f;

  const int dstc = tid * 16;
  const int rK = tid >> 4, lsK = (tid & 15) ^ rK;        // 16-slot swizzle
  const int rV = tid >> 3, lsV = (tid & 7) ^ (rV & 7);   // 8-slot swizzle
  const size_t koff0 = (size_t)(b * SEQ + rK) * (NKV * HD) + kvh * HD + lsK * 8;
  const size_t voff0 = ((size_t)(b * NKV + kvh) * HD + rV) * SEQ + lsV * 8;

  const float C1 = 1.7677669529663689e-3f;  // 1/(50*sqrt(128))
  const float CA = -0.33333333333f;         // tanh poly
  const float CB = 0.13333333333f;          // 2/15
  const float C2 = 72.13475204444817f;      // 50*log2(e)

  auto STAGE = [&](int buf, int t) {
    char* dK = ldsK + buf * 16384 + dstc;
    char* dV = ldsV + buf * 16384 + dstc;
    const bf16* ks = Kg + koff0 + (size_t)t * (64 * NKV * HD);
    const bf16* vs = VTg + voff0 + (size_t)t * 64;
#pragma unroll
    for (int j = 0; j < 4; j++) async16(dK + j * 4096, ks + j * 16 * (NKV * HD));
#pragma unroll
    for (int j = 0; j < 4; j++) async16(dV + j * 4096, vs + (size_t)j * 32 * SEQ);
  };

  STAGE(0, 0);
  VMCNT_BAR(0);

  for (int t = 0; t < SEQ / 64; ++t) {
    const int cur = t & 1;
    STAGE(cur ^ 1, (t + 1) & (SEQ / 64 - 1));  // issue next-tile loads first

    const char* lK = ldsK + cur * 16384;
    const char* lV = ldsV + cur * 16384;

    // ---- swapped QK^T: S^T[64 kv][32 q] ----
    f32x16 sc[2];
#pragma unroll
    for (int r = 0; r < 16; r++) { sc[0][r] = 0.f; sc[1][r] = 0.f; }
    const int kvr0 = l31;
    const int kvr1 = 32 + l31;
    __builtin_amdgcn_s_setprio(1);
#pragma unroll
    for (int kc = 0; kc < 8; kc++) {
      int slot = kc * 2 + hl;
      int off0 = (kvr0 << 8) | ((slot ^ (kvr0 & 15)) << 4);
      int off1 = (kvr1 << 8) | ((slot ^ (kvr1 & 15)) << 4);
      bf16x8 kf0 = *(const bf16x8_a*)(lK + off0);
      bf16x8 kf1 = *(const bf16x8_a*)(lK + off1);
      sc[0] = mfma32(kf0, qf[kc], sc[0]);
      sc[1] = mfma32(kf1, qf[kc], sc[1]);
    }
    __builtin_amdgcn_s_setprio(0);

    // ---- softcap+exp (packed f32x2 poly tanh, fixed max) + PV ----
#pragma unroll
    for (int ntb = 0; ntb < 2; ntb++) {
      uint u[4][2], us[4][2];
#pragma unroll
      for (int r2 = 0; r2 < 8; r2++) {
        f32x2 s2; s2[0] = sc[ntb][2 * r2]; s2[1] = sc[ntb][2 * r2 + 1];
        f32x2 z = s2 * C1;
        f32x2 z2 = z * z;
        f32x2 wv = z2 * (z2 * CB + CA) + 1.0f;
        f32x2 e = (z * wv) * C2;
        float p0 = ex2(e[0]), p1 = ex2(e[1]);
        ls2[0] += p0; ls2[1] += p1;
        uint uu = pkbf16(p0, p1);
        u[r2 >> 1][r2 & 1] = uu;
        us[r2 >> 1][r2 & 1] = __shfl_xor(uu, 32);
      }
      __builtin_amdgcn_s_setprio(1);
#pragma unroll
      for (int sub = 0; sub < 2; sub++) {
        u32x4 bu;
        bu[0] = hl ? us[2 * sub + 1][0] : u[2 * sub][0];
        bu[1] = hl ? us[2 * sub + 1][1] : u[2 * sub][1];
        bu[2] = hl ? u[2 * sub + 1][0] : us[2 * sub][0];
        bu[3] = hl ? u[2 * sub + 1][1] : us[2 * sub][1];
        bf16x8 pb = __builtin_bit_cast(bf16x8, bu);
        const int kvb = ntb * 2 + sub;
        const int slot = kvb * 2 + hl;
#pragma unroll
        for (int dt = 0; dt < 4; dt++) {
          int d = dt * 32 + l31;
          int off = (d << 7) | ((slot ^ (d & 7)) << 4);
          bf16x8 vf = *(const bf16x8_a*)(lV + off);
          oT[dt] = mfma32(vf, pb, oT[dt]);
        }
      }
      __builtin_amdgcn_s_setprio(0);
    }

    VMCNT_BAR(0);  // next tile staged (loads had a full tile of compute to land)
  }

  // ---- epilogue ----
  float lsum = ls2[0] + ls2[1];
  float lsf = lsum + __shfl_xor(lsum, 32);
  float inv = 1.0f / lsf;
  bf16* ob = O + (size_t)qrow * (NHEAD * HD) + h * HD;
#pragma unroll
  for (int dt = 0; dt < 4; dt++)
#pragma unroll
    for (int g = 0; g < 4; g++) {
      u32x2 pr;
      pr[0] = pkbf16(oT[dt][4 * g] * inv, oT[dt][4 * g + 1] * inv);
      pr[1] = pkbf16(oT[dt][4 * g + 2] * inv, oT[dt][4 * g + 3] * inv);
      *(u32x2_a*)(ob + dt * 32 + 8 * g + 4 * hl) = pr;
    }
}

extern "C" void kernel_launch(void* const* d_in, const int* in_sizes, int n_in,
                              void* d_out, int out_size, void* d_ws, size_t ws_size,
                              hipStream_t stream) {
  const float* X  = (const float*)d_in[0];
  const float* Wq = (const float*)d_in[1];
  const float* Wk = (const float*)d_in[2];
  const float* Wv = (const float*)d_in[3];
  const float* Wo = (const float*)d_in[4];
  float* out = (float*)d_out;

  char* ws = (char*)d_ws;
  size_t off = 0;
  auto alloc = [&](size_t bytes) {
    void* p = ws + off;
    off += (bytes + 255) & ~(size_t)255;
    return p;
  };
  bf16* Xb  = (bf16*)alloc((size_t)MROWS * HID * 2);
  // WqT/WkT/WvT adjacent & contiguous -> fused BT [4096][2048]
  bf16* WqT = (bf16*)alloc((size_t)2048 * 2048 * 2);
  bf16* WkT = (bf16*)alloc((size_t)1024 * 2048 * 2);
  bf16* WvT = (bf16*)alloc((size_t)1024 * 2048 * 2);
  bf16* WoT = (bf16*)alloc((size_t)2048 * 2048 * 2);
  bf16* Qb  = (bf16*)alloc((size_t)MROWS * 2048 * 2);
  bf16* Kb  = (bf16*)alloc((size_t)MROWS * 1024 * 2);
  bf16* Vb  = (bf16*)alloc((size_t)MROWS * 1024 * 2);
  bf16* VTb = (bf16*)alloc((size_t)16 * 128 * 2048 * 2);
  bf16* AOb = (bf16*)alloc((size_t)MROWS * 2048 * 2);
  float* ct = (float*)alloc((size_t)SEQ * 64 * 4);
  float* st = (float*)alloc((size_t)SEQ * 64 * 4);

  cast_f32_bf16<<<(MROWS * HID) / 1024, 256, 0, stream>>>(X, Xb, MROWS * HID);
  wtrans4<<<dim3(32, 32, 4), 256, 0, stream>>>(Wq, Wk, Wv, Wo, WqT, WkT, WvT, WoT);
  rope_tab<<<SEQ, 64, 0, stream>>>(ct, st);
  gemm256<1><<<dim3(16, 16), 512, 0, stream>>>(Xb, WqT, Qb, Kb, Vb, MROWS, 4096, 2048, ct, st);
  vtrans<<<dim3(32, 2, 16), 256, 0, stream>>>(Vb, VTb);
  attn5<<<dim3(16, 16, 2), 256, 0, stream>>>(Qb, Kb, VTb, AOb);
  gemm256<2><<<dim3(8, 16), 512, 0, stream>>>(AOb, WoT, out, nullptr, nullptr, MROWS, 2048, 2048,
                                              nullptr, nullptr);

  (void)in_sizes; (void)n_in; (void)out_size; (void)ws_size;
}

// Round 8
// 257.971 us; speedup vs baseline: 1.2428x; 1.2069x over previous
//
#include <hip/hip_runtime.h>
#include <math.h>

typedef __bf16 bf16;
typedef __bf16 bf16x8 __attribute__((ext_vector_type(8)));
typedef __bf16 bf16x4 __attribute__((ext_vector_type(4)));
typedef float f32x2 __attribute__((ext_vector_type(2)));
typedef float f32x4 __attribute__((ext_vector_type(4)));
typedef float f32x16 __attribute__((ext_vector_type(16)));
typedef unsigned int uint;
typedef uint u32x4 __attribute__((ext_vector_type(4)));
typedef uint u32x2 __attribute__((ext_vector_type(2)));
typedef __bf16 bf16x8_a __attribute__((ext_vector_type(8), __may_alias__));
typedef uint u32x2_a __attribute__((ext_vector_type(2), __may_alias__));
typedef __bf16 bf16_a __attribute__((__may_alias__));

constexpr int BATCH = 2;
constexpr int SEQ   = 2048;
constexpr int HID   = 2048;
constexpr int NHEAD = 16;
constexpr int NKV   = 8;
constexpr int HD    = 128;
constexpr int MROWS = BATCH * SEQ; // 4096

#define DEVINL __device__ __forceinline__

// raw barrier with compiler reorder fence (no implicit vmcnt/lgkm drain)
#define BAR()                                 \
  do {                                        \
    asm volatile("" ::: "memory");            \
    __builtin_amdgcn_s_barrier();             \
    asm volatile("" ::: "memory");            \
  } while (0)

#define WAITV(N) asm volatile("s_waitcnt vmcnt(" #N ")" ::: "memory")

DEVINL void async16(void* l, const void* g) {
  __builtin_amdgcn_global_load_lds((const __attribute__((address_space(1))) void*)g,
                                   (__attribute__((address_space(3))) void*)l, 16, 0, 0);
}

DEVINL f32x4 mfma16(bf16x8 a, bf16x8 b, f32x4 c) {
  return __builtin_amdgcn_mfma_f32_16x16x32_bf16(a, b, c, 0, 0, 0);
}
DEVINL f32x16 mfma32(bf16x8 a, bf16x8 b, f32x16 c) {
  return __builtin_amdgcn_mfma_f32_32x32x16_bf16(a, b, c, 0, 0, 0);
}

DEVINL f32x4 fzero4() { f32x4 z; z[0] = 0.f; z[1] = 0.f; z[2] = 0.f; z[3] = 0.f; return z; }

DEVINL float ex2(float x) {
#if __has_builtin(__builtin_amdgcn_exp2f)
  return __builtin_amdgcn_exp2f(x);
#else
  return __expf(x * 0.6931471805599453f);
#endif
}

DEVINL uint pkbf16(float lo, float hi) {
  unsigned short l = __builtin_bit_cast(unsigned short, (bf16)lo);
  unsigned short h = __builtin_bit_cast(unsigned short, (bf16)hi);
  return (uint)l | ((uint)h << 16);
}

// ---------------- elementwise cast f32 -> bf16 ----------------
__global__ __launch_bounds__(256) void cast_f32_bf16(const float* __restrict__ x,
                                                     bf16* __restrict__ y, int n) {
  int i = (blockIdx.x * 256 + threadIdx.x) * 4;
  if (i + 3 < n) {
    float4 v = *(const float4*)(x + i);
    bf16x4 o;
    o[0] = (bf16)v.x; o[1] = (bf16)v.y; o[2] = (bf16)v.z; o[3] = (bf16)v.w;
    *(bf16x4*)(y + i) = o;
  }
}

// ---------------- all-W transpose f32[K][N] -> bf16 WT[N][K], K=2048 ----------------
__global__ __launch_bounds__(256) void wtrans4(const float* __restrict__ Wq,
                                               const float* __restrict__ Wk,
                                               const float* __restrict__ Wv,
                                               const float* __restrict__ Wo,
                                               bf16* __restrict__ WqT, bf16* __restrict__ WkT,
                                               bf16* __restrict__ WvT, bf16* __restrict__ WoT) {
  __shared__ bf16 t[64][65];
  const float* W; bf16* WT; int N;
  switch (blockIdx.z) {
    case 0: W = Wq; WT = WqT; N = 2048; break;
    case 1: W = Wk; WT = WkT; N = 1024; break;
    case 2: W = Wv; WT = WvT; N = 1024; break;
    default: W = Wo; WT = WoT; N = 2048; break;
  }
  int n0 = blockIdx.x * 64, k0 = blockIdx.y * 64;
  if (n0 >= N) return;
  for (int i = threadIdx.x; i < 4096; i += 256) {
    int r = i >> 6, c = i & 63;
    t[r][c] = (bf16)W[(size_t)(k0 + r) * N + n0 + c];
  }
  __syncthreads();
  for (int i = threadIdx.x; i < 4096; i += 256) {
    int r = i >> 6, c = i & 63;
    WT[(size_t)(n0 + r) * 2048 + k0 + c] = t[c][r];
  }
}

// ---------------- V[b*S+s][kvh*128+d] -> VT[(b*8+kvh)*128+d][s] ----------------
__global__ __launch_bounds__(256) void vtrans(const bf16* __restrict__ V, bf16* __restrict__ VT) {
  __shared__ bf16 t[64][65];
  int s0 = blockIdx.x * 64, d0 = blockIdx.y * 64;
  int bh = blockIdx.z, b = bh >> 3, kvh = bh & 7;
  for (int i = threadIdx.x; i < 4096; i += 256) {
    int r = i >> 6, c = i & 63;
    t[r][c] = V[(size_t)(b * SEQ + s0 + r) * (NKV * HD) + kvh * HD + d0 + c];
  }
  __syncthreads();
  for (int i = threadIdx.x; i < 4096; i += 256) {
    int r = i >> 6, c = i & 63;
    VT[((size_t)bh * HD + d0 + r) * SEQ + s0 + c] = t[c][r];
  }
}

// ---------------- RoPE tables: cos/sin [SEQ][64] ----------------
__global__ void rope_tab(float* __restrict__ ct, float* __restrict__ st) {
  int s = blockIdx.x, d = threadIdx.x;
  float freq = powf(10000.0f, -(float)d * (1.0f / 64.0f));
  float a = (float)s * freq;
  ct[s * 64 + d] = cosf(a);
  st[s * 64 + d] = sinf(a);
}

// ================= 256x256 8-phase GEMM (m201-style) =================
// 512 thr / 8 waves (2M x 4N); wave tile 128x64 (cols wn*16 + nt*64).
// Per K-tile t (BK=64), 4 phases, each {reads; stage; BAR; setprio MFMA x16; BAR}:
//  p0: read A[wm] rows 0-63 (8x b128) + B-half0 (4x);              MFMA Q00
//  p1: read B-half1 (4x);             stage B0(t+2);               MFMA Q01
//  p2: read A[wm] rows 64-127 (8x);   stage B1(t+2);               MFMA Q11
//  p3:                                stage A0(t+2)+A1(t+2);       MFMA Q10; vmcnt(8)
// Single vmcnt(8)/tile: pending = exactly tile-(t+2)'s 8 loads (ages >= 4 phases).
// All halves of tile t+1 staged during tile t-1 -> landed at end-of-t wait.
template <int EPI>
__global__ __launch_bounds__(512, 2) void gemm8p(const bf16* __restrict__ A,
                                                 const bf16* __restrict__ BT,
                                                 void* __restrict__ C0, void* __restrict__ C1,
                                                 void* __restrict__ C2, int M, int N, int K,
                                                 const float* __restrict__ ct,
                                                 const float* __restrict__ st) {
  __shared__ alignas(16) char ldsA[65536];  // [buf][half][128r][64k]
  __shared__ alignas(16) char ldsB[65536];
  const int tid = threadIdx.x, lane = tid & 63, w = tid >> 6;
  const int l15 = lane & 15, l4 = lane >> 4;
  const int wm = w >> 2, wn = w & 3;
  const int gx = gridDim.x;
  const int nwg = gx * gridDim.y;
  int id = blockIdx.y * gx + blockIdx.x;
  id = (id & 7) * (nwg >> 3) + (id >> 3);
  const int row0 = (id / gx) * 256;
  const int col0 = (id % gx) * 256;

  f32x4 acc[8][4];
#pragma unroll
  for (int mt = 0; mt < 8; mt++)
#pragma unroll
    for (int nt = 0; nt < 4; nt++) acc[mt][nt] = fzero4();

  // staging granules: half = 128 rows x 64 k; 2x16B loads/thread
  const int rG0 = tid >> 3, sG0 = ((tid & 7) ^ (rG0 & 7)) * 8;
  const int ci1 = 512 + tid;
  const int rG1 = ci1 >> 3, sG1 = ((ci1 & 7) ^ (rG1 & 7)) * 8;
  const int dst0 = tid * 16, dst1 = (512 + tid) * 16;

  const bf16* Asrc = A + (size_t)row0 * K;
  const bf16* Bsrc = BT + (size_t)col0 * K;
  const int nk = K >> 6;

#define STG_A(half, kt, buf)                                         \
  {                                                                  \
    char* d = ldsA + (buf) * 32768 + (half) * 16384;                 \
    const bf16* s = Asrc + (size_t)((half) * 128) * K + (kt) * 64;   \
    async16(d + dst0, s + (size_t)rG0 * K + sG0);                    \
    async16(d + dst1, s + (size_t)rG1 * K + sG1);                    \
  }
#define STG_B(half, kt, buf)                                         \
  {                                                                  \
    char* d = ldsB + (buf) * 32768 + (half) * 16384;                 \
    const bf16* s = Bsrc + (size_t)((half) * 128) * K + (kt) * 64;   \
    async16(d + dst0, s + (size_t)rG0 * K + sG0);                    \
    async16(d + dst1, s + (size_t)rG1 * K + sG1);                    \
  }

  // prologue: tiles 0 and 1 fully staged (16 loads)
  STG_A(0, 0, 0) STG_A(1, 0, 0) STG_B(0, 0, 0) STG_B(1, 0, 0)
  STG_B(0, 1, 1) STG_B(1, 1, 1) STG_A(0, 1, 1) STG_A(1, 1, 1)
  WAITV(8);  // tile 0 landed; tile 1's 8 loads pending
  BAR();

  bf16x8 af[8];
  bf16x8 bfr[2][4];

  for (int t = 0; t < nk; ++t) {
    const int buf = t & 1;
    const char* bA = ldsA + buf * 32768 + wm * 16384;
    const char* bB = ldsB + buf * 32768;
    const bool s2 = (t + 2) < nk;

    // ---- p0: read A-lo + B-half0; MFMA Q00 ----
#pragma unroll
    for (int mtp = 0; mtp < 4; mtp++)
#pragma unroll
      for (int kc = 0; kc < 2; kc++) {
        int r = mtp * 16 + l15;
        int off = ((r << 7) + ((kc * 4 + l4) << 4)) ^ ((r & 7) << 4);
        af[mtp * 2 + kc] = *(const bf16x8_a*)(bA + off);
      }
#pragma unroll
    for (int ntp = 0; ntp < 2; ntp++)
#pragma unroll
      for (int kc = 0; kc < 2; kc++) {
        int c = wn * 16 + ntp * 64 + l15;
        int off = ((c << 7) + ((kc * 4 + l4) << 4)) ^ ((c & 7) << 4);
        bfr[0][ntp * 2 + kc] = *(const bf16x8_a*)(bB + off);
      }
    BAR();
    __builtin_amdgcn_s_setprio(1);
#pragma unroll
    for (int mtp = 0; mtp < 4; mtp++)
#pragma unroll
      for (int ntp = 0; ntp < 2; ntp++)
#pragma unroll
        for (int kc = 0; kc < 2; kc++)
          acc[mtp][ntp] = mfma16(af[mtp * 2 + kc], bfr[0][ntp * 2 + kc], acc[mtp][ntp]);
    __builtin_amdgcn_s_setprio(0);
    BAR();

    // ---- p1: read B-half1; stage B0(t+2); MFMA Q01 ----
#pragma unroll
    for (int ntp = 0; ntp < 2; ntp++)
#pragma unroll
      for (int kc = 0; kc < 2; kc++) {
        int c = wn * 16 + ntp * 64 + l15;  // local col within half1
        int off = 16384 + (((c << 7) + ((kc * 4 + l4) << 4)) ^ ((c & 7) << 4));
        bfr[1][ntp * 2 + kc] = *(const bf16x8_a*)(bB + off);
      }
    if (s2) STG_B(0, t + 2, buf)
    BAR();
    __builtin_amdgcn_s_setprio(1);
#pragma unroll
    for (int mtp = 0; mtp < 4; mtp++)
#pragma unroll
      for (int ntp = 0; ntp < 2; ntp++)
#pragma unroll
        for (int kc = 0; kc < 2; kc++)
          acc[mtp][ntp + 2] = mfma16(af[mtp * 2 + kc], bfr[1][ntp * 2 + kc], acc[mtp][ntp + 2]);
    __builtin_amdgcn_s_setprio(0);
    BAR();

    // ---- p2: read A-hi; stage B1(t+2); MFMA Q11 ----
#pragma unroll
    for (int mtp = 0; mtp < 4; mtp++)
#pragma unroll
      for (int kc = 0; kc < 2; kc++) {
        int r = 64 + mtp * 16 + l15;
        int off = ((r << 7) + ((kc * 4 + l4) << 4)) ^ ((r & 7) << 4);
        af[mtp * 2 + kc] = *(const bf16x8_a*)(bA + off);
      }
    if (s2) STG_B(1, t + 2, buf)
    BAR();
    __builtin_amdgcn_s_setprio(1);
#pragma unroll
    for (int mtp = 0; mtp < 4; mtp++)
#pragma unroll
      for (int ntp = 0; ntp < 2; ntp++)
#pragma unroll
        for (int kc = 0; kc < 2; kc++)
          acc[mtp + 4][ntp + 2] = mfma16(af[mtp * 2 + kc], bfr[1][ntp * 2 + kc], acc[mtp + 4][ntp + 2]);
    __builtin_amdgcn_s_setprio(0);
    BAR();

    // ---- p3: stage A0,A1(t+2); MFMA Q10; vmcnt; BAR ----
    if (s2) { STG_A(0, t + 2, buf) STG_A(1, t + 2, buf) }
    BAR();
    __builtin_amdgcn_s_setprio(1);
#pragma unroll
    for (int mtp = 0; mtp < 4; mtp++)
#pragma unroll
      for (int ntp = 0; ntp < 2; ntp++)
#pragma unroll
        for (int kc = 0; kc < 2; kc++)
          acc[mtp + 4][ntp] = mfma16(af[mtp * 2 + kc], bfr[0][ntp * 2 + kc], acc[mtp + 4][ntp]);
    __builtin_amdgcn_s_setprio(0);
    if (s2) { WAITV(8); } else { WAITV(0); }
    BAR();
  }
#undef STG_A
#undef STG_B

  // ---- epilogue ----
#pragma unroll
  for (int mt = 0; mt < 8; mt++)
#pragma unroll
    for (int nt = 0; nt < 4; nt++)
#pragma unroll
      for (int rg = 0; rg < 4; rg++) {
        int row = row0 + wm * 128 + mt * 16 + l4 * 4 + rg;
        int cl = col0 + wn * 16 + nt * 64 + l15;
        float v = acc[mt][nt][rg];
        if (EPI == 2) {
          ((float*)C0)[(size_t)row * N + cl] = v;
        } else {
          if (cl < 3072) {
            int s = row & (SEQ - 1);
            float cc = ct[s * 64 + wn * 16 + l15];
            float ss = st[s * 64 + wn * 16 + l15];
            float pv = acc[mt][nt ^ 1][rg];
            v = (nt & 1) ? fmaf(v, cc, pv * ss) : fmaf(v, cc, -pv * ss);
          }
          if (cl < 2048)
            ((bf16*)C0)[(size_t)row * 2048 + cl] = (bf16)v;
          else if (cl < 3072)
            ((bf16*)C1)[(size_t)row * 1024 + (cl - 2048)] = (bf16)v;
          else
            ((bf16*)C2)[(size_t)row * 1024 + (cl - 3072)] = (bf16)v;
        }
      }
}

// ================= 256x128 2-phase GEMM (Wo, full-GPU grid) =================
// 512 thr / 8 waves (4M x 2N); wave tile 64x64 (cols wn*16 + nt*32, nt 0..3).
// Per K-tile: p0 {read A(wm-half)+B nt0,1; stage B(t+1); BAR; MFMA; BAR}
//             p1 {read B nt2,3; stage A0,A1(t+2); BAR; MFMA; vmcnt(4); BAR}
__global__ __launch_bounds__(512, 2) void gemm2p(const bf16* __restrict__ A,
                                                 const bf16* __restrict__ BT,
                                                 float* __restrict__ C, int M, int N, int K) {
  __shared__ alignas(16) char ldsA[65536];  // [buf][half][128r][64k]
  __shared__ alignas(16) char ldsB[32768];  // [buf][128c][64k]
  const int tid = threadIdx.x, lane = tid & 63, w = tid >> 6;
  const int l15 = lane & 15, l4 = lane >> 4;
  const int wm = w >> 1, wn = w & 1;
  const int gx = gridDim.x;
  const int nwg = gx * gridDim.y;
  int id = blockIdx.y * gx + blockIdx.x;
  id = (id & 7) * (nwg >> 3) + (id >> 3);
  const int row0 = (id / gx) * 256;
  const int col0 = (id % gx) * 128;

  f32x4 acc[4][4];
#pragma unroll
  for (int mt = 0; mt < 4; mt++)
#pragma unroll
    for (int nt = 0; nt < 4; nt++) acc[mt][nt] = fzero4();

  const int rG0 = tid >> 3, sG0 = ((tid & 7) ^ (rG0 & 7)) * 8;
  const int ci1 = 512 + tid;
  const int rG1 = ci1 >> 3, sG1 = ((ci1 & 7) ^ (rG1 & 7)) * 8;
  const int dst0 = tid * 16, dst1 = (512 + tid) * 16;

  const bf16* Asrc = A + (size_t)row0 * K;
  const bf16* Bsrc = BT + (size_t)col0 * K;
  const int nk = K >> 6;

#define STG_A2(half, kt, buf)                                        \
  {                                                                  \
    char* d = ldsA + (buf) * 32768 + (half) * 16384;                 \
    const bf16* s = Asrc + (size_t)((half) * 128) * K + (kt) * 64;   \
    async16(d + dst0, s + (size_t)rG0 * K + sG0);                    \
    async16(d + dst1, s + (size_t)rG1 * K + sG1);                    \
  }
#define STG_B2(kt, buf)                                              \
  {                                                                  \
    char* d = ldsB + (buf) * 16384;                                  \
    const bf16* s = Bsrc + (kt) * 64;                                \
    async16(d + dst0, s + (size_t)rG0 * K + sG0);                    \
    async16(d + dst1, s + (size_t)rG1 * K + sG1);                    \
  }

  // prologue: A,B of tile 0 + A of tile 1
  STG_A2(0, 0, 0) STG_A2(1, 0, 0) STG_B2(0, 0)
  STG_A2(0, 1, 1) STG_A2(1, 1, 1)
  WAITV(4);  // tile 0 landed; A(t1) pending
  BAR();

  bf16x8 af[8];
  bf16x8 bfr[8];

  for (int t = 0; t < nk; ++t) {
    const int buf = t & 1;
    const char* bA = ldsA + buf * 32768 + (wm >> 1) * 16384;
    const char* bB = ldsB + buf * 16384;
    const bool s1 = (t + 1) < nk;
    const bool s2 = (t + 2) < nk;

    // ---- p0 ----
#pragma unroll
    for (int mt = 0; mt < 4; mt++)
#pragma unroll
      for (int kc = 0; kc < 2; kc++) {
        int r = (wm & 1) * 64 + mt * 16 + l15;
        int off = ((r << 7) + ((kc * 4 + l4) << 4)) ^ ((r & 7) << 4);
        af[mt * 2 + kc] = *(const bf16x8_a*)(bA + off);
      }
#pragma unroll
    for (int nt = 0; nt < 2; nt++)
#pragma unroll
      for (int kc = 0; kc < 2; kc++) {
        int c = wn * 16 + nt * 32 + l15;
        int off = ((c << 7) + ((kc * 4 + l4) << 4)) ^ ((c & 7) << 4);
        bfr[nt * 2 + kc] = *(const bf16x8_a*)(bB + off);
      }
    if (s1) STG_B2(t + 1, buf ^ 1)
    BAR();
    __builtin_amdgcn_s_setprio(1);
#pragma unroll
    for (int mt = 0; mt < 4; mt++)
#pragma unroll
      for (int nt = 0; nt < 2; nt++)
#pragma unroll
        for (int kc = 0; kc < 2; kc++)
          acc[mt][nt] = mfma16(af[mt * 2 + kc], bfr[nt * 2 + kc], acc[mt][nt]);
    __builtin_amdgcn_s_setprio(0);
    BAR();

    // ---- p1 ----
#pragma unroll
    for (int nt = 0; nt < 2; nt++)
#pragma unroll
      for (int kc = 0; kc < 2; kc++) {
        int c = wn * 16 + (nt + 2) * 32 + l15;
        int off = ((c << 7) + ((kc * 4 + l4) << 4)) ^ ((c & 7) << 4);
        bfr[4 + nt * 2 + kc] = *(const bf16x8_a*)(bB + off);
      }
    if (s2) { STG_A2(0, t + 2, buf) STG_A2(1, t + 2, buf) }
    BAR();
    __builtin_amdgcn_s_setprio(1);
#pragma unroll
    for (int mt = 0; mt < 4; mt++)
#pragma unroll
      for (int nt = 0; nt < 2; nt++)
#pragma unroll
        for (int kc = 0; kc < 2; kc++)
          acc[mt][nt + 2] = mfma16(af[mt * 2 + kc], bfr[4 + nt * 2 + kc], acc[mt][nt + 2]);
    __builtin_amdgcn_s_setprio(0);
    if (s2) { WAITV(4); } else { WAITV(0); }
    BAR();
  }
#undef STG_A2
#undef STG_B2

#pragma unroll
  for (int mt = 0; mt < 4; mt++)
#pragma unroll
    for (int nt = 0; nt < 4; nt++)
#pragma unroll
      for (int rg = 0; rg < 4; rg++) {
        int row = row0 + wm * 64 + mt * 16 + l4 * 4 + rg;
        int cl = col0 + wn * 16 + nt * 32 + l15;
        C[(size_t)row * N + cl] = acc[mt][nt][rg];
      }
}

// ---------------- Flash attention v5 (unchanged from R7) ----------------
__global__ __launch_bounds__(256, 2) void attn5(const bf16* __restrict__ Q,
                                                const bf16* __restrict__ Kg,
                                                const bf16* __restrict__ VTg,
                                                bf16* __restrict__ O) {
  __shared__ alignas(16) char ldsK[32768];
  __shared__ alignas(16) char ldsV[32768];
  const int tid = threadIdx.x, lane = tid & 63, w = tid >> 6;
  const int l31 = lane & 31, hl = lane >> 5;

  const int nx = gridDim.x, ny = gridDim.y;
  const int nwg = nx * ny * gridDim.z;
  int id = (blockIdx.z * ny + blockIdx.y) * nx + blockIdx.x;
  id = (id & 7) * (nwg >> 3) + (id >> 3);
  const int qt = id % nx; id /= nx;
  const int h = id % ny; const int b = id / ny;
  const int kvh = h >> 1;
  const int qrow = b * SEQ + qt * 128 + w * 32 + l31;

  bf16x8 qf[8];
  const bf16* qp = Q + (size_t)qrow * (NHEAD * HD) + h * HD + hl * 8;
#pragma unroll
  for (int kc = 0; kc < 8; kc++) qf[kc] = *(const bf16x8_a*)(qp + kc * 16);

  f32x16 oT[4];
#pragma unroll
  for (int dt = 0; dt < 4; dt++)
#pragma unroll
    for (int r = 0; r < 16; r++) oT[dt][r] = 0.f;
  f32x2 ls2; ls2[0] = 0.f; ls2[1] = 0.f;

  const int dstc = tid * 16;
  const int rK = tid >> 4, lsK = (tid & 15) ^ rK;
  const int rV = tid >> 3, lsV = (tid & 7) ^ (rV & 7);
  const size_t koff0 = (size_t)(b * SEQ + rK) * (NKV * HD) + kvh * HD + lsK * 8;
  const size_t voff0 = ((size_t)(b * NKV + kvh) * HD + rV) * SEQ + lsV * 8;

  const float C1 = 1.7677669529663689e-3f;
  const float CA = -0.33333333333f;
  const float CB = 0.13333333333f;
  const float C2 = 72.13475204444817f;

  auto STAGE = [&](int buf, int t) {
    char* dK = ldsK + buf * 16384 + dstc;
    char* dV = ldsV + buf * 16384 + dstc;
    const bf16* ks = Kg + koff0 + (size_t)t * (64 * NKV * HD);
    const bf16* vs = VTg + voff0 + (size_t)t * 64;
#pragma unroll
    for (int j = 0; j < 4; j++) async16(dK + j * 4096, ks + j * 16 * (NKV * HD));
#pragma unroll
    for (int j = 0; j < 4; j++) async16(dV + j * 4096, vs + (size_t)j * 32 * SEQ);
  };

  STAGE(0, 0);
  WAITV(0);
  BAR();

  for (int t = 0; t < SEQ / 64; ++t) {
    const int cur = t & 1;
    STAGE(cur ^ 1, (t + 1) & (SEQ / 64 - 1));

    const char* lK = ldsK + cur * 16384;
    const char* lV = ldsV + cur * 16384;

    f32x16 sc[2];
#pragma unroll
    for (int r = 0; r < 16; r++) { sc[0][r] = 0.f; sc[1][r] = 0.f; }
    const int kvr0 = l31;
    const int kvr1 = 32 + l31;
    __builtin_amdgcn_s_setprio(1);
#pragma unroll
    for (int kc = 0; kc < 8; kc++) {
      int slot = kc * 2 + hl;
      int off0 = (kvr0 << 8) | ((slot ^ (kvr0 & 15)) << 4);
      int off1 = (kvr1 << 8) | ((slot ^ (kvr1 & 15)) << 4);
      bf16x8 kf0 = *(const bf16x8_a*)(lK + off0);
      bf16x8 kf1 = *(const bf16x8_a*)(lK + off1);
      sc[0] = mfma32(kf0, qf[kc], sc[0]);
      sc[1] = mfma32(kf1, qf[kc], sc[1]);
    }
    __builtin_amdgcn_s_setprio(0);

#pragma unroll
    for (int ntb = 0; ntb < 2; ntb++) {
      uint u[4][2], us[4][2];
#pragma unroll
      for (int r2 = 0; r2 < 8; r2++) {
        f32x2 s2; s2[0] = sc[ntb][2 * r2]; s2[1] = sc[ntb][2 * r2 + 1];
        f32x2 z = s2 * C1;
        f32x2 z2 = z * z;
        f32x2 wv = z2 * (z2 * CB + CA) + 1.0f;
        f32x2 e = (z * wv) * C2;
        float p0 = ex2(e[0]), p1 = ex2(e[1]);
        ls2[0] += p0; ls2[1] += p1;
        uint uu = pkbf16(p0, p1);
        u[r2 >> 1][r2 & 1] = uu;
        us[r2 >> 1][r2 & 1] = __shfl_xor(uu, 32);
      }
      __builtin_amdgcn_s_setprio(1);
#pragma unroll
      for (int sub = 0; sub < 2; sub++) {
        u32x4 bu;
        bu[0] = hl ? us[2 * sub + 1][0] : u[2 * sub][0];
        bu[1] = hl ? us[2 * sub + 1][1] : u[2 * sub][1];
        bu[2] = hl ? u[2 * sub + 1][0] : us[2 * sub][0];
        bu[3] = hl ? u[2 * sub + 1][1] : us[2 * sub][1];
        bf16x8 pb = __builtin_bit_cast(bf16x8, bu);
        const int kvb = ntb * 2 + sub;
        const int slot = kvb * 2 + hl;
#pragma unroll
        for (int dt = 0; dt < 4; dt++) {
          int d = dt * 32 + l31;
          int off = (d << 7) | ((slot ^ (d & 7)) << 4);
          bf16x8 vf = *(const bf16x8_a*)(lV + off);
          oT[dt] = mfma32(vf, pb, oT[dt]);
        }
      }
      __builtin_amdgcn_s_setprio(0);
    }

    WAITV(0);
    BAR();
  }

  float lsum = ls2[0] + ls2[1];
  float lsf = lsum + __shfl_xor(lsum, 32);
  float inv = 1.0f / lsf;
  bf16* ob = O + (size_t)qrow * (NHEAD * HD) + h * HD;
#pragma unroll
  for (int dt = 0; dt < 4; dt++)
#pragma unroll
    for (int g = 0; g < 4; g++) {
      u32x2 pr;
      pr[0] = pkbf16(oT[dt][4 * g] * inv, oT[dt][4 * g + 1] * inv);
      pr[1] = pkbf16(oT[dt][4 * g + 2] * inv, oT[dt][4 * g + 3] * inv);
      *(u32x2_a*)(ob + dt * 32 + 8 * g + 4 * hl) = pr;
    }
}

extern "C" void kernel_launch(void* const* d_in, const int* in_sizes, int n_in,
                              void* d_out, int out_size, void* d_ws, size_t ws_size,
                              hipStream_t stream) {
  const float* X  = (const float*)d_in[0];
  const float* Wq = (const float*)d_in[1];
  const float* Wk = (const float*)d_in[2];
  const float* Wv = (const float*)d_in[3];
  const float* Wo = (const float*)d_in[4];
  float* out = (float*)d_out;

  char* ws = (char*)d_ws;
  size_t off = 0;
  auto alloc = [&](size_t bytes) {
    void* p = ws + off;
    off += (bytes + 255) & ~(size_t)255;
    return p;
  };
  bf16* Xb  = (bf16*)alloc((size_t)MROWS * HID * 2);
  // WqT/WkT/WvT adjacent & contiguous -> fused BT [4096][2048]
  bf16* WqT = (bf16*)alloc((size_t)2048 * 2048 * 2);
  bf16* WkT = (bf16*)alloc((size_t)1024 * 2048 * 2);
  bf16* WvT = (bf16*)alloc((size_t)1024 * 2048 * 2);
  bf16* WoT = (bf16*)alloc((size_t)2048 * 2048 * 2);
  bf16* Qb  = (bf16*)alloc((size_t)MROWS * 2048 * 2);
  bf16* Kb  = (bf16*)alloc((size_t)MROWS * 1024 * 2);
  bf16* Vb  = (bf16*)alloc((size_t)MROWS * 1024 * 2);
  bf16* VTb = (bf16*)alloc((size_t)16 * 128 * 2048 * 2);
  bf16* AOb = (bf16*)alloc((size_t)MROWS * 2048 * 2);
  float* ct = (float*)alloc((size_t)SEQ * 64 * 4);
  float* st = (float*)alloc((size_t)SEQ * 64 * 4);

  cast_f32_bf16<<<(MROWS * HID) / 1024, 256, 0, stream>>>(X, Xb, MROWS * HID);
  wtrans4<<<dim3(32, 32, 4), 256, 0, stream>>>(Wq, Wk, Wv, Wo, WqT, WkT, WvT, WoT);
  rope_tab<<<SEQ, 64, 0, stream>>>(ct, st);
  gemm8p<1><<<dim3(16, 16), 512, 0, stream>>>(Xb, WqT, Qb, Kb, Vb, MROWS, 4096, 2048, ct, st);
  vtrans<<<dim3(32, 2, 16), 256, 0, stream>>>(Vb, VTb);
  attn5<<<dim3(16, 16, 2), 256, 0, stream>>>(Qb, Kb, VTb, AOb);
  gemm2p<<<dim3(16, 16), 512, 0, stream>>>(AOb, WoT, out, MROWS, 2048, 2048);

  (void)in_sizes; (void)n_in; (void)out_size; (void)ws_size;
}

// Round 9
// 251.432 us; speedup vs baseline: 1.2752x; 1.0260x over previous
//
#include <hip/hip_runtime.h>
#include <math.h>

typedef __bf16 bf16;
typedef __bf16 bf16x8 __attribute__((ext_vector_type(8)));
typedef __bf16 bf16x4 __attribute__((ext_vector_type(4)));
typedef float f32x2 __attribute__((ext_vector_type(2)));
typedef float f32x4 __attribute__((ext_vector_type(4)));
typedef float f32x16 __attribute__((ext_vector_type(16)));
typedef unsigned int uint;
typedef uint u32x4 __attribute__((ext_vector_type(4)));
typedef uint u32x2 __attribute__((ext_vector_type(2)));
typedef __bf16 bf16x8_a __attribute__((ext_vector_type(8), __may_alias__));
typedef uint u32x2_a __attribute__((ext_vector_type(2), __may_alias__));
typedef __bf16 bf16_a __attribute__((__may_alias__));

constexpr int BATCH = 2;
constexpr int SEQ   = 2048;
constexpr int HID   = 2048;
constexpr int NHEAD = 16;
constexpr int NKV   = 8;
constexpr int HD    = 128;
constexpr int MROWS = BATCH * SEQ; // 4096

#define DEVINL __device__ __forceinline__

// raw barrier with compiler reorder fence (no implicit vmcnt/lgkm drain)
#define BAR()                                 \
  do {                                        \
    asm volatile("" ::: "memory");            \
    __builtin_amdgcn_s_barrier();             \
    asm volatile("" ::: "memory");            \
  } while (0)

#define WAITV(N) asm volatile("s_waitcnt vmcnt(" #N ")" ::: "memory")

DEVINL void async16(void* l, const void* g) {
  __builtin_amdgcn_global_load_lds((const __attribute__((address_space(1))) void*)g,
                                   (__attribute__((address_space(3))) void*)l, 16, 0, 0);
}

DEVINL f32x4 mfma16(bf16x8 a, bf16x8 b, f32x4 c) {
  return __builtin_amdgcn_mfma_f32_16x16x32_bf16(a, b, c, 0, 0, 0);
}

DEVINL f32x4 fzero4() { f32x4 z; z[0] = 0.f; z[1] = 0.f; z[2] = 0.f; z[3] = 0.f; return z; }

DEVINL float ex2(float x) {
#if __has_builtin(__builtin_amdgcn_exp2f)
  return __builtin_amdgcn_exp2f(x);
#else
  return __expf(x * 0.6931471805599453f);
#endif
}

DEVINL uint pkbf16(float lo, float hi) {
  unsigned short l = __builtin_bit_cast(unsigned short, (bf16)lo);
  unsigned short h = __builtin_bit_cast(unsigned short, (bf16)hi);
  return (uint)l | ((uint)h << 16);
}

// ---------------- elementwise cast f32 -> bf16 ----------------
__global__ __launch_bounds__(256) void cast_f32_bf16(const float* __restrict__ x,
                                                     bf16* __restrict__ y, int n) {
  int i = (blockIdx.x * 256 + threadIdx.x) * 4;
  if (i + 3 < n) {
    float4 v = *(const float4*)(x + i);
    bf16x4 o;
    o[0] = (bf16)v.x; o[1] = (bf16)v.y; o[2] = (bf16)v.z; o[3] = (bf16)v.w;
    *(bf16x4*)(y + i) = o;
  }
}

// ---------------- all-W transpose f32[K][N] -> bf16 WT[N][K], K=2048 ----------------
__global__ __launch_bounds__(256) void wtrans4(const float* __restrict__ Wq,
                                               const float* __restrict__ Wk,
                                               const float* __restrict__ Wv,
                                               const float* __restrict__ Wo,
                                               bf16* __restrict__ WqT, bf16* __restrict__ WkT,
                                               bf16* __restrict__ WvT, bf16* __restrict__ WoT) {
  __shared__ bf16 t[64][65];
  const float* W; bf16* WT; int N;
  switch (blockIdx.z) {
    case 0: W = Wq; WT = WqT; N = 2048; break;
    case 1: W = Wk; WT = WkT; N = 1024; break;
    case 2: W = Wv; WT = WvT; N = 1024; break;
    default: W = Wo; WT = WoT; N = 2048; break;
  }
  int n0 = blockIdx.x * 64, k0 = blockIdx.y * 64;
  if (n0 >= N) return;
  for (int i = threadIdx.x; i < 4096; i += 256) {
    int r = i >> 6, c = i & 63;
    t[r][c] = (bf16)W[(size_t)(k0 + r) * N + n0 + c];
  }
  __syncthreads();
  for (int i = threadIdx.x; i < 4096; i += 256) {
    int r = i >> 6, c = i & 63;
    WT[(size_t)(n0 + r) * 2048 + k0 + c] = t[c][r];
  }
}

// ---------------- V[b*S+s][kvh*128+d] -> VT[(b*8+kvh)*128+d][s] ----------------
__global__ __launch_bounds__(256) void vtrans(const bf16* __restrict__ V, bf16* __restrict__ VT) {
  __shared__ bf16 t[64][65];
  int s0 = blockIdx.x * 64, d0 = blockIdx.y * 64;
  int bh = blockIdx.z, b = bh >> 3, kvh = bh & 7;
  for (int i = threadIdx.x; i < 4096; i += 256) {
    int r = i >> 6, c = i & 63;
    t[r][c] = V[(size_t)(b * SEQ + s0 + r) * (NKV * HD) + kvh * HD + d0 + c];
  }
  __syncthreads();
  for (int i = threadIdx.x; i < 4096; i += 256) {
    int r = i >> 6, c = i & 63;
    VT[((size_t)bh * HD + d0 + r) * SEQ + s0 + c] = t[c][r];
  }
}

// ---------------- RoPE tables: cos/sin [SEQ][64] ----------------
__global__ void rope_tab(float* __restrict__ ct, float* __restrict__ st) {
  int s = blockIdx.x, d = threadIdx.x;
  float freq = powf(10000.0f, -(float)d * (1.0f / 64.0f));
  float a = (float)s * freq;
  ct[s * 64 + d] = cosf(a);
  st[s * 64 + d] = sinf(a);
}

// ================= 256x256 8-phase GEMM (m201-style, from R8) =================
// EPI 1 now additionally pre-scales the Q range (cl<2048) by 1/(50*sqrt(128))
// so attention's softcap-tanh argument needs no per-element scaling.
template <int EPI>
__global__ __launch_bounds__(512, 2) void gemm8p(const bf16* __restrict__ A,
                                                 const bf16* __restrict__ BT,
                                                 void* __restrict__ C0, void* __restrict__ C1,
                                                 void* __restrict__ C2, int M, int N, int K,
                                                 const float* __restrict__ ct,
                                                 const float* __restrict__ st) {
  __shared__ alignas(16) char ldsA[65536];  // [buf][half][128r][64k]
  __shared__ alignas(16) char ldsB[65536];
  const int tid = threadIdx.x, lane = tid & 63, w = tid >> 6;
  const int l15 = lane & 15, l4 = lane >> 4;
  const int wm = w >> 2, wn = w & 3;
  const int gx = gridDim.x;
  const int nwg = gx * gridDim.y;
  int id = blockIdx.y * gx + blockIdx.x;
  id = (id & 7) * (nwg >> 3) + (id >> 3);
  const int row0 = (id / gx) * 256;
  const int col0 = (id % gx) * 256;

  f32x4 acc[8][4];
#pragma unroll
  for (int mt = 0; mt < 8; mt++)
#pragma unroll
    for (int nt = 0; nt < 4; nt++) acc[mt][nt] = fzero4();

  const int rG0 = tid >> 3, sG0 = ((tid & 7) ^ (rG0 & 7)) * 8;
  const int ci1 = 512 + tid;
  const int rG1 = ci1 >> 3, sG1 = ((ci1 & 7) ^ (rG1 & 7)) * 8;
  const int dst0 = tid * 16, dst1 = (512 + tid) * 16;

  const bf16* Asrc = A + (size_t)row0 * K;
  const bf16* Bsrc = BT + (size_t)col0 * K;
  const int nk = K >> 6;

#define STG_A(half, kt, buf)                                         \
  {                                                                  \
    char* d = ldsA + (buf) * 32768 + (half) * 16384;                 \
    const bf16* s = Asrc + (size_t)((half) * 128) * K + (kt) * 64;   \
    async16(d + dst0, s + (size_t)rG0 * K + sG0);                    \
    async16(d + dst1, s + (size_t)rG1 * K + sG1);                    \
  }
#define STG_B(half, kt, buf)                                         \
  {                                                                  \
    char* d = ldsB + (buf) * 32768 + (half) * 16384;                 \
    const bf16* s = Bsrc + (size_t)((half) * 128) * K + (kt) * 64;   \
    async16(d + dst0, s + (size_t)rG0 * K + sG0);                    \
    async16(d + dst1, s + (size_t)rG1 * K + sG1);                    \
  }

  // prologue: tiles 0 and 1 fully staged (16 loads)
  STG_A(0, 0, 0) STG_A(1, 0, 0) STG_B(0, 0, 0) STG_B(1, 0, 0)
  STG_B(0, 1, 1) STG_B(1, 1, 1) STG_A(0, 1, 1) STG_A(1, 1, 1)
  WAITV(8);
  BAR();

  bf16x8 af[8];
  bf16x8 bfr[2][4];

  for (int t = 0; t < nk; ++t) {
    const int buf = t & 1;
    const char* bA = ldsA + buf * 32768 + wm * 16384;
    const char* bB = ldsB + buf * 32768;
    const bool s2 = (t + 2) < nk;

    // ---- p0: read A-lo + B-half0; MFMA Q00 ----
#pragma unroll
    for (int mtp = 0; mtp < 4; mtp++)
#pragma unroll
      for (int kc = 0; kc < 2; kc++) {
        int r = mtp * 16 + l15;
        int off = ((r << 7) + ((kc * 4 + l4) << 4)) ^ ((r & 7) << 4);
        af[mtp * 2 + kc] = *(const bf16x8_a*)(bA + off);
      }
#pragma unroll
    for (int ntp = 0; ntp < 2; ntp++)
#pragma unroll
      for (int kc = 0; kc < 2; kc++) {
        int c = wn * 16 + ntp * 64 + l15;
        int off = ((c << 7) + ((kc * 4 + l4) << 4)) ^ ((c & 7) << 4);
        bfr[0][ntp * 2 + kc] = *(const bf16x8_a*)(bB + off);
      }
    BAR();
    __builtin_amdgcn_s_setprio(1);
#pragma unroll
    for (int mtp = 0; mtp < 4; mtp++)
#pragma unroll
      for (int ntp = 0; ntp < 2; ntp++)
#pragma unroll
        for (int kc = 0; kc < 2; kc++)
          acc[mtp][ntp] = mfma16(af[mtp * 2 + kc], bfr[0][ntp * 2 + kc], acc[mtp][ntp]);
    __builtin_amdgcn_s_setprio(0);
    BAR();

    // ---- p1: read B-half1; stage B0(t+2); MFMA Q01 ----
#pragma unroll
    for (int ntp = 0; ntp < 2; ntp++)
#pragma unroll
      for (int kc = 0; kc < 2; kc++) {
        int c = wn * 16 + ntp * 64 + l15;
        int off = 16384 + (((c << 7) + ((kc * 4 + l4) << 4)) ^ ((c & 7) << 4));
        bfr[1][ntp * 2 + kc] = *(const bf16x8_a*)(bB + off);
      }
    if (s2) STG_B(0, t + 2, buf)
    BAR();
    __builtin_amdgcn_s_setprio(1);
#pragma unroll
    for (int mtp = 0; mtp < 4; mtp++)
#pragma unroll
      for (int ntp = 0; ntp < 2; ntp++)
#pragma unroll
        for (int kc = 0; kc < 2; kc++)
          acc[mtp][ntp + 2] = mfma16(af[mtp * 2 + kc], bfr[1][ntp * 2 + kc], acc[mtp][ntp + 2]);
    __builtin_amdgcn_s_setprio(0);
    BAR();

    // ---- p2: read A-hi; stage B1(t+2); MFMA Q11 ----
#pragma unroll
    for (int mtp = 0; mtp < 4; mtp++)
#pragma unroll
      for (int kc = 0; kc < 2; kc++) {
        int r = 64 + mtp * 16 + l15;
        int off = ((r << 7) + ((kc * 4 + l4) << 4)) ^ ((r & 7) << 4);
        af[mtp * 2 + kc] = *(const bf16x8_a*)(bA + off);
      }
    if (s2) STG_B(1, t + 2, buf)
    BAR();
    __builtin_amdgcn_s_setprio(1);
#pragma unroll
    for (int mtp = 0; mtp < 4; mtp++)
#pragma unroll
      for (int ntp = 0; ntp < 2; ntp++)
#pragma unroll
        for (int kc = 0; kc < 2; kc++)
          acc[mtp + 4][ntp + 2] = mfma16(af[mtp * 2 + kc], bfr[1][ntp * 2 + kc], acc[mtp + 4][ntp + 2]);
    __builtin_amdgcn_s_setprio(0);
    BAR();

    // ---- p3: stage A0,A1(t+2); MFMA Q10; vmcnt; BAR ----
    if (s2) { STG_A(0, t + 2, buf) STG_A(1, t + 2, buf) }
    BAR();
    __builtin_amdgcn_s_setprio(1);
#pragma unroll
    for (int mtp = 0; mtp < 4; mtp++)
#pragma unroll
      for (int ntp = 0; ntp < 2; ntp++)
#pragma unroll
        for (int kc = 0; kc < 2; kc++)
          acc[mtp + 4][ntp] = mfma16(af[mtp * 2 + kc], bfr[0][ntp * 2 + kc], acc[mtp + 4][ntp]);
    __builtin_amdgcn_s_setprio(0);
    if (s2) { WAITV(8); } else { WAITV(0); }
    BAR();
  }
#undef STG_A
#undef STG_B

  // ---- epilogue ----
#pragma unroll
  for (int mt = 0; mt < 8; mt++)
#pragma unroll
    for (int nt = 0; nt < 4; nt++)
#pragma unroll
      for (int rg = 0; rg < 4; rg++) {
        int row = row0 + wm * 128 + mt * 16 + l4 * 4 + rg;
        int cl = col0 + wn * 16 + nt * 64 + l15;
        float v = acc[mt][nt][rg];
        if (EPI == 2) {
          ((float*)C0)[(size_t)row * N + cl] = v;
        } else {
          if (cl < 3072) {
            int s = row & (SEQ - 1);
            float cc = ct[s * 64 + wn * 16 + l15];
            float ss = st[s * 64 + wn * 16 + l15];
            float pv = acc[mt][nt ^ 1][rg];
            v = (nt & 1) ? fmaf(v, cc, pv * ss) : fmaf(v, cc, -pv * ss);
          }
          if (cl < 2048) {
            v *= 1.7677669529663689e-3f;  // pre-scale Q by 1/(50*sqrt(128))
            ((bf16*)C0)[(size_t)row * 2048 + cl] = (bf16)v;
          } else if (cl < 3072) {
            ((bf16*)C1)[(size_t)row * 1024 + (cl - 2048)] = (bf16)v;
          } else {
            ((bf16*)C2)[(size_t)row * 1024 + (cl - 3072)] = (bf16)v;
          }
        }
      }
}

// ================= 256x128 2-phase GEMM (Wo, unchanged from R8) =================
__global__ __launch_bounds__(512, 2) void gemm2p(const bf16* __restrict__ A,
                                                 const bf16* __restrict__ BT,
                                                 float* __restrict__ C, int M, int N, int K) {
  __shared__ alignas(16) char ldsA[65536];
  __shared__ alignas(16) char ldsB[32768];
  const int tid = threadIdx.x, lane = tid & 63, w = tid >> 6;
  const int l15 = lane & 15, l4 = lane >> 4;
  const int wm = w >> 1, wn = w & 1;
  const int gx = gridDim.x;
  const int nwg = gx * gridDim.y;
  int id = blockIdx.y * gx + blockIdx.x;
  id = (id & 7) * (nwg >> 3) + (id >> 3);
  const int row0 = (id / gx) * 256;
  const int col0 = (id % gx) * 128;

  f32x4 acc[4][4];
#pragma unroll
  for (int mt = 0; mt < 4; mt++)
#pragma unroll
    for (int nt = 0; nt < 4; nt++) acc[mt][nt] = fzero4();

  const int rG0 = tid >> 3, sG0 = ((tid & 7) ^ (rG0 & 7)) * 8;
  const int ci1 = 512 + tid;
  const int rG1 = ci1 >> 3, sG1 = ((ci1 & 7) ^ (rG1 & 7)) * 8;
  const int dst0 = tid * 16, dst1 = (512 + tid) * 16;

  const bf16* Asrc = A + (size_t)row0 * K;
  const bf16* Bsrc = BT + (size_t)col0 * K;
  const int nk = K >> 6;

#define STG_A2(half, kt, buf)                                        \
  {                                                                  \
    char* d = ldsA + (buf) * 32768 + (half) * 16384;                 \
    const bf16* s = Asrc + (size_t)((half) * 128) * K + (kt) * 64;   \
    async16(d + dst0, s + (size_t)rG0 * K + sG0);                    \
    async16(d + dst1, s + (size_t)rG1 * K + sG1);                    \
  }
#define STG_B2(kt, buf)                                              \
  {                                                                  \
    char* d = ldsB + (buf) * 16384;                                  \
    const bf16* s = Bsrc + (kt) * 64;                                \
    async16(d + dst0, s + (size_t)rG0 * K + sG0);                    \
    async16(d + dst1, s + (size_t)rG1 * K + sG1);                    \
  }

  STG_A2(0, 0, 0) STG_A2(1, 0, 0) STG_B2(0, 0)
  STG_A2(0, 1, 1) STG_A2(1, 1, 1)
  WAITV(4);
  BAR();

  bf16x8 af[8];
  bf16x8 bfr[8];

  for (int t = 0; t < nk; ++t) {
    const int buf = t & 1;
    const char* bA = ldsA + buf * 32768 + (wm >> 1) * 16384;
    const char* bB = ldsB + buf * 16384;
    const bool s1 = (t + 1) < nk;
    const bool s2 = (t + 2) < nk;

    // ---- p0 ----
#pragma unroll
    for (int mt = 0; mt < 4; mt++)
#pragma unroll
      for (int kc = 0; kc < 2; kc++) {
        int r = (wm & 1) * 64 + mt * 16 + l15;
        int off = ((r << 7) + ((kc * 4 + l4) << 4)) ^ ((r & 7) << 4);
        af[mt * 2 + kc] = *(const bf16x8_a*)(bA + off);
      }
#pragma unroll
    for (int nt = 0; nt < 2; nt++)
#pragma unroll
      for (int kc = 0; kc < 2; kc++) {
        int c = wn * 16 + nt * 32 + l15;
        int off = ((c << 7) + ((kc * 4 + l4) << 4)) ^ ((c & 7) << 4);
        bfr[nt * 2 + kc] = *(const bf16x8_a*)(bB + off);
      }
    if (s1) STG_B2(t + 1, buf ^ 1)
    BAR();
    __builtin_amdgcn_s_setprio(1);
#pragma unroll
    for (int mt = 0; mt < 4; mt++)
#pragma unroll
      for (int nt = 0; nt < 2; nt++)
#pragma unroll
        for (int kc = 0; kc < 2; kc++)
          acc[mt][nt] = mfma16(af[mt * 2 + kc], bfr[nt * 2 + kc], acc[mt][nt]);
    __builtin_amdgcn_s_setprio(0);
    BAR();

    // ---- p1 ----
#pragma unroll
    for (int nt = 0; nt < 2; nt++)
#pragma unroll
      for (int kc = 0; kc < 2; kc++) {
        int c = wn * 16 + (nt + 2) * 32 + l15;
        int off = ((c << 7) + ((kc * 4 + l4) << 4)) ^ ((c & 7) << 4);
        bfr[4 + nt * 2 + kc] = *(const bf16x8_a*)(bB + off);
      }
    if (s2) { STG_A2(0, t + 2, buf) STG_A2(1, t + 2, buf) }
    BAR();
    __builtin_amdgcn_s_setprio(1);
#pragma unroll
    for (int mt = 0; mt < 4; mt++)
#pragma unroll
      for (int nt = 0; nt < 2; nt++)
#pragma unroll
        for (int kc = 0; kc < 2; kc++)
          acc[mt][nt + 2] = mfma16(af[mt * 2 + kc], bfr[4 + nt * 2 + kc], acc[mt][nt + 2]);
    __builtin_amdgcn_s_setprio(0);
    if (s2) { WAITV(4); } else { WAITV(0); }
    BAR();
  }
#undef STG_A2
#undef STG_B2

#pragma unroll
  for (int mt = 0; mt < 4; mt++)
#pragma unroll
    for (int nt = 0; nt < 4; nt++)
#pragma unroll
      for (int rg = 0; rg < 4; rg++) {
        int row = row0 + wm * 64 + mt * 16 + l4 * 4 + rg;
        int cl = col0 + wn * 16 + nt * 32 + l15;
        C[(size_t)row * N + cl] = acc[mt][nt][rg];
      }
}

// ================= Flash attention v6: 16q waves, 8 waves/block, 50% occ =================
// grid (qt=16, h=16, b=2) swizzled, 512 thr / 8 waves; wave = 16 q-rows.
// K/V double-buffered swizzled LDS; swapped QK^T via mfma16 (S^T[64kv][16q]);
// Q pre-scaled in projection; folded softcap poly (4 ops + exp per elem);
// P via per-wave 2KB swizzled LDS; PV O^T[128d][16q]. LDS 80KB -> 2 blocks/CU.
__global__ __launch_bounds__(512, 4) void attn6(const bf16* __restrict__ Q,
                                                const bf16* __restrict__ Kg,
                                                const bf16* __restrict__ VTg,
                                                bf16* __restrict__ O) {
  __shared__ alignas(16) char ldsK[32768];   // 2 x [64 kv][128 d], 16-slot swizzle
  __shared__ alignas(16) char ldsV[32768];   // 2 x [128 d][64 kv], 8-slot swizzle
  __shared__ alignas(16) char ldsP[16384];   // 8 waves x P[16 q][64 kv]
  const int tid = threadIdx.x, lane = tid & 63, w = tid >> 6;
  const int l15 = lane & 15, l4 = lane >> 4;

  const int nx = gridDim.x, ny = gridDim.y;
  const int nwg = nx * ny * gridDim.z;  // 512
  int id = (blockIdx.z * ny + blockIdx.y) * nx + blockIdx.x;
  id = (id & 7) * (nwg >> 3) + (id >> 3);
  const int qt = id % nx; id /= nx;
  const int h = id % ny; const int b = id / ny;
  const int kvh = h >> 1;
  const int qrow = b * SEQ + qt * 128 + w * 16 + l15;

  // Q B-fragments: col = q = l15, k(d) = kc*32 + l4*8 + j   (Q pre-scaled)
  bf16x8 qf[4];
  const bf16* qp = Q + (size_t)qrow * (NHEAD * HD) + h * HD + l4 * 8;
#pragma unroll
  for (int kc = 0; kc < 4; kc++) qf[kc] = *(const bf16x8_a*)(qp + kc * 32);

  f32x4 oT[8];
#pragma unroll
  for (int dt = 0; dt < 8; dt++) oT[dt] = fzero4();
  f32x4 ls4 = fzero4();

  // staging: 512 thr, 2 K granules + 2 V granules each (linear dest, inv-swz src)
  const int rK = tid >> 4, sK = (tid & 15) ^ (rK & 15);
  const int rV = tid >> 3, sV = (tid & 7) ^ (rV & 7);
  const size_t koff0 = (size_t)(b * SEQ + rK) * (NKV * HD) + kvh * HD + sK * 8;
  const size_t voff0 = ((size_t)(b * NKV + kvh) * HD + rV) * SEQ + sV * 8;

  char* myP = ldsP + w * 2048;  // P[16 q][64 kv], 128B rows, 8-slot swizzle
  const float Ac = 72.13475204444817f;    // 50*log2(e)
  const float Bc = -24.044917348149389f;  // Ac * (-1/3)
  const float Cc = 9.6179669392597558f;   // Ac * (2/15)

  auto STAGE = [&](int buf, int t) {
    char* dK = ldsK + buf * 16384;
    char* dV = ldsV + buf * 16384;
    const bf16* ks = Kg + koff0 + (size_t)t * (64 * NKV * HD);
    const bf16* vs = VTg + voff0 + (size_t)t * 64;
    async16(dK + tid * 16, ks);
    async16(dK + (512 + tid) * 16, ks + (size_t)32 * (NKV * HD));
    async16(dV + tid * 16, vs);
    async16(dV + (512 + tid) * 16, vs + (size_t)64 * SEQ);
  };

  STAGE(0, 0);
  WAITV(0);
  BAR();

  for (int t = 0; t < SEQ / 64; ++t) {
    const int cur = t & 1;
    STAGE(cur ^ 1, (t + 1) & (SEQ / 64 - 1));  // issue next-tile loads first

    const char* lK = ldsK + cur * 16384;
    const char* lV = ldsV + cur * 16384;

    // ---- swapped QK^T: S^T[64 kv][16 q] = 4 rt x 4 kc mfma16 ----
    f32x4 sc[4];
#pragma unroll
    for (int rt = 0; rt < 4; rt++) sc[rt] = fzero4();
    __builtin_amdgcn_s_setprio(1);
#pragma unroll
    for (int rt = 0; rt < 4; rt++) {
#pragma unroll
      for (int kc = 0; kc < 4; kc++) {
        int r = rt * 16 + l15;
        int slot = kc * 4 + l4;
        int off = (r << 8) | ((slot ^ (r & 15)) << 4);
        bf16x8 kf = *(const bf16x8_a*)(lK + off);
        sc[rt] = mfma16(kf, qf[kc], sc[rt]);
      }
    }
    __builtin_amdgcn_s_setprio(0);

    // ---- softcap+exp (folded poly; z = capped-score/(50*sqrt128) directly) ----
    // lane owns kv = rt*16 + l4*4 + reg for q = l15
#pragma unroll
    for (int rt = 0; rt < 4; rt++) {
      f32x4 z = sc[rt];
      f32x4 z2 = z * z;
      f32x4 wv = z2 * (z2 * Cc + Bc) + Ac;
      f32x4 e = z * wv;
      f32x4 p;
      p[0] = ex2(e[0]); p[1] = ex2(e[1]); p[2] = ex2(e[2]); p[3] = ex2(e[3]);
      ls4 += p;
      u32x2 pw;
      pw[0] = pkbf16(p[0], p[1]);
      pw[1] = pkbf16(p[2], p[3]);
      int slot = 2 * rt + (l4 >> 1);
      int off = (l15 << 7) | ((slot ^ (l15 & 7)) << 4) | ((l4 & 1) << 3);
      *(u32x2_a*)(myP + off) = pw;
    }
    asm volatile("s_waitcnt lgkmcnt(0)" ::: "memory");
    __builtin_amdgcn_sched_barrier(0);

    // ---- P B-frags: col = q = l15, k = kc*32 + l4*8 + j ----
    bf16x8 pf[2];
#pragma unroll
    for (int kc = 0; kc < 2; kc++) {
      int slot = kc * 4 + l4;
      int off = (l15 << 7) | ((slot ^ (l15 & 7)) << 4);
      pf[kc] = *(const bf16x8_a*)(myP + off);
    }

    // ---- PV: O^T[128 d][16 q] = 8 dt x 2 kc mfma16 ----
    __builtin_amdgcn_s_setprio(1);
#pragma unroll
    for (int dt = 0; dt < 8; dt++) {
#pragma unroll
      for (int kc = 0; kc < 2; kc++) {
        int d = dt * 16 + l15;
        int slot = kc * 4 + l4;
        int off = (d << 7) | ((slot ^ (d & 7)) << 4);
        bf16x8 vf = *(const bf16x8_a*)(lV + off);
        oT[dt] = mfma16(vf, pf[kc], oT[dt]);
      }
    }
    __builtin_amdgcn_s_setprio(0);

    WAITV(0);
    BAR();
  }

  // ---- epilogue: row-sum over l4 groups, normalize, store ----
  float lsum = ls4[0] + ls4[1] + ls4[2] + ls4[3];
  lsum += __shfl_xor(lsum, 16);
  lsum += __shfl_xor(lsum, 32);
  float inv = 1.0f / lsum;

  bf16* ob = O + (size_t)qrow * (NHEAD * HD) + h * HD + l4 * 4;
#pragma unroll
  for (int dt = 0; dt < 8; dt++) {
    u32x2 pr;
    pr[0] = pkbf16(oT[dt][0] * inv, oT[dt][1] * inv);
    pr[1] = pkbf16(oT[dt][2] * inv, oT[dt][3] * inv);
    *(u32x2_a*)(ob + dt * 16) = pr;
  }
}

extern "C" void kernel_launch(void* const* d_in, const int* in_sizes, int n_in,
                              void* d_out, int out_size, void* d_ws, size_t ws_size,
                              hipStream_t stream) {
  const float* X  = (const float*)d_in[0];
  const float* Wq = (const float*)d_in[1];
  const float* Wk = (const float*)d_in[2];
  const float* Wv = (const float*)d_in[3];
  const float* Wo = (const float*)d_in[4];
  float* out = (float*)d_out;

  char* ws = (char*)d_ws;
  size_t off = 0;
  auto alloc = [&](size_t bytes) {
    void* p = ws + off;
    off += (bytes + 255) & ~(size_t)255;
    return p;
  };
  bf16* Xb  = (bf16*)alloc((size_t)MROWS * HID * 2);
  // WqT/WkT/WvT adjacent & contiguous -> fused BT [4096][2048]
  bf16* WqT = (bf16*)alloc((size_t)2048 * 2048 * 2);
  bf16* WkT = (bf16*)alloc((size_t)1024 * 2048 * 2);
  bf16* WvT = (bf16*)alloc((size_t)1024 * 2048 * 2);
  bf16* WoT = (bf16*)alloc((size_t)2048 * 2048 * 2);
  bf16* Qb  = (bf16*)alloc((size_t)MROWS * 2048 * 2);
  bf16* Kb  = (bf16*)alloc((size_t)MROWS * 1024 * 2);
  bf16* Vb  = (bf16*)alloc((size_t)MROWS * 1024 * 2);
  bf16* VTb = (bf16*)alloc((size_t)16 * 128 * 2048 * 2);
  bf16* AOb = (bf16*)alloc((size_t)MROWS * 2048 * 2);
  float* ct = (float*)alloc((size_t)SEQ * 64 * 4);
  float* st = (float*)alloc((size_t)SEQ * 64 * 4);

  cast_f32_bf16<<<(MROWS * HID) / 1024, 256, 0, stream>>>(X, Xb, MROWS * HID);
  wtrans4<<<dim3(32, 32, 4), 256, 0, stream>>>(Wq, Wk, Wv, Wo, WqT, WkT, WvT, WoT);
  rope_tab<<<SEQ, 64, 0, stream>>>(ct, st);
  gemm8p<1><<<dim3(16, 16), 512, 0, stream>>>(Xb, WqT, Qb, Kb, Vb, MROWS, 4096, 2048, ct, st);
  vtrans<<<dim3(32, 2, 16), 256, 0, stream>>>(Vb, VTb);
  attn6<<<dim3(16, 16, 2), 512, 0, stream>>>(Qb, Kb, VTb, AOb);
  gemm2p<<<dim3(16, 16), 512, 0, stream>>>(AOb, WoT, out, MROWS, 2048, 2048);

  (void)in_sizes; (void)n_in; (void)out_size; (void)ws_size;
}

// Round 10
// 251.270 us; speedup vs baseline: 1.2760x; 1.0006x over previous
//
#include <hip/hip_runtime.h>
#include <math.h>

typedef __bf16 bf16;
typedef __bf16 bf16x8 __attribute__((ext_vector_type(8)));
typedef __bf16 bf16x4 __attribute__((ext_vector_type(4)));
typedef float f32x2 __attribute__((ext_vector_type(2)));
typedef float f32x4 __attribute__((ext_vector_type(4)));
typedef float f32x16 __attribute__((ext_vector_type(16)));
typedef unsigned int uint;
typedef uint u32x4 __attribute__((ext_vector_type(4)));
typedef uint u32x2 __attribute__((ext_vector_type(2)));
typedef __bf16 bf16x8_a __attribute__((ext_vector_type(8), __may_alias__));
typedef uint u32x2_a __attribute__((ext_vector_type(2), __may_alias__));
typedef __bf16 bf16_a __attribute__((__may_alias__));

constexpr int BATCH = 2;
constexpr int SEQ   = 2048;
constexpr int HID   = 2048;
constexpr int NHEAD = 16;
constexpr int NKV   = 8;
constexpr int HD    = 128;
constexpr int MROWS = BATCH * SEQ; // 4096

#define DEVINL __device__ __forceinline__

// raw barrier with compiler reorder fence (no implicit vmcnt/lgkm drain)
#define BAR()                                 \
  do {                                        \
    asm volatile("" ::: "memory");            \
    __builtin_amdgcn_s_barrier();             \
    asm volatile("" ::: "memory");            \
  } while (0)

#define WAITV(N) asm volatile("s_waitcnt vmcnt(" #N ")" ::: "memory")

DEVINL void async16(void* l, const void* g) {
  __builtin_amdgcn_global_load_lds((const __attribute__((address_space(1))) void*)g,
                                   (__attribute__((address_space(3))) void*)l, 16, 0, 0);
}

DEVINL f32x4 mfma16(bf16x8 a, bf16x8 b, f32x4 c) {
  return __builtin_amdgcn_mfma_f32_16x16x32_bf16(a, b, c, 0, 0, 0);
}
DEVINL f32x16 mfma32(bf16x8 a, bf16x8 b, f32x16 c) {
  return __builtin_amdgcn_mfma_f32_32x32x16_bf16(a, b, c, 0, 0, 0);
}

DEVINL f32x4 fzero4() { f32x4 z; z[0] = 0.f; z[1] = 0.f; z[2] = 0.f; z[3] = 0.f; return z; }

DEVINL float ex2(float x) {
#if __has_builtin(__builtin_amdgcn_exp2f)
  return __builtin_amdgcn_exp2f(x);
#else
  return __expf(x * 0.6931471805599453f);
#endif
}

DEVINL uint pkbf16(float lo, float hi) {
  unsigned short l = __builtin_bit_cast(unsigned short, (bf16)lo);
  unsigned short h = __builtin_bit_cast(unsigned short, (bf16)hi);
  return (uint)l | ((uint)h << 16);
}

// ---------------- elementwise cast f32 -> bf16 ----------------
__global__ __launch_bounds__(256) void cast_f32_bf16(const float* __restrict__ x,
                                                     bf16* __restrict__ y, int n) {
  int i = (blockIdx.x * 256 + threadIdx.x) * 4;
  if (i + 3 < n) {
    float4 v = *(const float4*)(x + i);
    bf16x4 o;
    o[0] = (bf16)v.x; o[1] = (bf16)v.y; o[2] = (bf16)v.z; o[3] = (bf16)v.w;
    *(bf16x4*)(y + i) = o;
  }
}

// ---------------- all-W transpose f32[K][N] -> bf16 WT[N][K], K=2048 ----------------
__global__ __launch_bounds__(256) void wtrans4(const float* __restrict__ Wq,
                                               const float* __restrict__ Wk,
                                               const float* __restrict__ Wv,
                                               const float* __restrict__ Wo,
                                               bf16* __restrict__ WqT, bf16* __restrict__ WkT,
                                               bf16* __restrict__ WvT, bf16* __restrict__ WoT) {
  __shared__ bf16 t[64][65];
  const float* W; bf16* WT; int N;
  switch (blockIdx.z) {
    case 0: W = Wq; WT = WqT; N = 2048; break;
    case 1: W = Wk; WT = WkT; N = 1024; break;
    case 2: W = Wv; WT = WvT; N = 1024; break;
    default: W = Wo; WT = WoT; N = 2048; break;
  }
  int n0 = blockIdx.x * 64, k0 = blockIdx.y * 64;
  if (n0 >= N) return;
  for (int i = threadIdx.x; i < 4096; i += 256) {
    int r = i >> 6, c = i & 63;
    t[r][c] = (bf16)W[(size_t)(k0 + r) * N + n0 + c];
  }
  __syncthreads();
  for (int i = threadIdx.x; i < 4096; i += 256) {
    int r = i >> 6, c = i & 63;
    WT[(size_t)(n0 + r) * 2048 + k0 + c] = t[c][r];
  }
}

// ---------------- V[b*S+s][kvh*128+d] -> VT[(b*8+kvh)*128+d][s] ----------------
__global__ __launch_bounds__(256) void vtrans(const bf16* __restrict__ V, bf16* __restrict__ VT) {
  __shared__ bf16 t[64][65];
  int s0 = blockIdx.x * 64, d0 = blockIdx.y * 64;
  int bh = blockIdx.z, b = bh >> 3, kvh = bh & 7;
  for (int i = threadIdx.x; i < 4096; i += 256) {
    int r = i >> 6, c = i & 63;
    t[r][c] = V[(size_t)(b * SEQ + s0 + r) * (NKV * HD) + kvh * HD + d0 + c];
  }
  __syncthreads();
  for (int i = threadIdx.x; i < 4096; i += 256) {
    int r = i >> 6, c = i & 63;
    VT[((size_t)bh * HD + d0 + r) * SEQ + s0 + c] = t[c][r];
  }
}

// ---------------- RoPE tables: cos/sin [SEQ][64] ----------------
__global__ void rope_tab(float* __restrict__ ct, float* __restrict__ st) {
  int s = blockIdx.x, d = threadIdx.x;
  float freq = powf(10000.0f, -(float)d * (1.0f / 64.0f));
  float a = (float)s * freq;
  ct[s * 64 + d] = cosf(a);
  st[s * 64 + d] = sinf(a);
}

// ================= 256x256 8-phase GEMM (m201-style, from R8) =================
// EPI 1 pre-scales the Q range (cl<2048) by 1/(50*sqrt(128)).
template <int EPI>
__global__ __launch_bounds__(512, 2) void gemm8p(const bf16* __restrict__ A,
                                                 const bf16* __restrict__ BT,
                                                 void* __restrict__ C0, void* __restrict__ C1,
                                                 void* __restrict__ C2, int M, int N, int K,
                                                 const float* __restrict__ ct,
                                                 const float* __restrict__ st) {
  __shared__ alignas(16) char ldsA[65536];  // [buf][half][128r][64k]
  __shared__ alignas(16) char ldsB[65536];
  const int tid = threadIdx.x, lane = tid & 63, w = tid >> 6;
  const int l15 = lane & 15, l4 = lane >> 4;
  const int wm = w >> 2, wn = w & 3;
  const int gx = gridDim.x;
  const int nwg = gx * gridDim.y;
  int id = blockIdx.y * gx + blockIdx.x;
  id = (id & 7) * (nwg >> 3) + (id >> 3);
  const int row0 = (id / gx) * 256;
  const int col0 = (id % gx) * 256;

  f32x4 acc[8][4];
#pragma unroll
  for (int mt = 0; mt < 8; mt++)
#pragma unroll
    for (int nt = 0; nt < 4; nt++) acc[mt][nt] = fzero4();

  const int rG0 = tid >> 3, sG0 = ((tid & 7) ^ (rG0 & 7)) * 8;
  const int ci1 = 512 + tid;
  const int rG1 = ci1 >> 3, sG1 = ((ci1 & 7) ^ (rG1 & 7)) * 8;
  const int dst0 = tid * 16, dst1 = (512 + tid) * 16;

  const bf16* Asrc = A + (size_t)row0 * K;
  const bf16* Bsrc = BT + (size_t)col0 * K;
  const int nk = K >> 6;

#define STG_A(half, kt, buf)                                         \
  {                                                                  \
    char* d = ldsA + (buf) * 32768 + (half) * 16384;                 \
    const bf16* s = Asrc + (size_t)((half) * 128) * K + (kt) * 64;   \
    async16(d + dst0, s + (size_t)rG0 * K + sG0);                    \
    async16(d + dst1, s + (size_t)rG1 * K + sG1);                    \
  }
#define STG_B(half, kt, buf)                                         \
  {                                                                  \
    char* d = ldsB + (buf) * 32768 + (half) * 16384;                 \
    const bf16* s = Bsrc + (size_t)((half) * 128) * K + (kt) * 64;   \
    async16(d + dst0, s + (size_t)rG0 * K + sG0);                    \
    async16(d + dst1, s + (size_t)rG1 * K + sG1);                    \
  }

  // prologue: tiles 0 and 1 fully staged (16 loads)
  STG_A(0, 0, 0) STG_A(1, 0, 0) STG_B(0, 0, 0) STG_B(1, 0, 0)
  STG_B(0, 1, 1) STG_B(1, 1, 1) STG_A(0, 1, 1) STG_A(1, 1, 1)
  WAITV(8);
  BAR();

  bf16x8 af[8];
  bf16x8 bfr[2][4];

  for (int t = 0; t < nk; ++t) {
    const int buf = t & 1;
    const char* bA = ldsA + buf * 32768 + wm * 16384;
    const char* bB = ldsB + buf * 32768;
    const bool s2 = (t + 2) < nk;

    // ---- p0: read A-lo + B-half0; MFMA Q00 ----
#pragma unroll
    for (int mtp = 0; mtp < 4; mtp++)
#pragma unroll
      for (int kc = 0; kc < 2; kc++) {
        int r = mtp * 16 + l15;
        int off = ((r << 7) + ((kc * 4 + l4) << 4)) ^ ((r & 7) << 4);
        af[mtp * 2 + kc] = *(const bf16x8_a*)(bA + off);
      }
#pragma unroll
    for (int ntp = 0; ntp < 2; ntp++)
#pragma unroll
      for (int kc = 0; kc < 2; kc++) {
        int c = wn * 16 + ntp * 64 + l15;
        int off = ((c << 7) + ((kc * 4 + l4) << 4)) ^ ((c & 7) << 4);
        bfr[0][ntp * 2 + kc] = *(const bf16x8_a*)(bB + off);
      }
    BAR();
    __builtin_amdgcn_s_setprio(1);
#pragma unroll
    for (int mtp = 0; mtp < 4; mtp++)
#pragma unroll
      for (int ntp = 0; ntp < 2; ntp++)
#pragma unroll
        for (int kc = 0; kc < 2; kc++)
          acc[mtp][ntp] = mfma16(af[mtp * 2 + kc], bfr[0][ntp * 2 + kc], acc[mtp][ntp]);
    __builtin_amdgcn_s_setprio(0);
    BAR();

    // ---- p1: read B-half1; stage B0(t+2); MFMA Q01 ----
#pragma unroll
    for (int ntp = 0; ntp < 2; ntp++)
#pragma unroll
      for (int kc = 0; kc < 2; kc++) {
        int c = wn * 16 + ntp * 64 + l15;
        int off = 16384 + (((c << 7) + ((kc * 4 + l4) << 4)) ^ ((c & 7) << 4));
        bfr[1][ntp * 2 + kc] = *(const bf16x8_a*)(bB + off);
      }
    if (s2) STG_B(0, t + 2, buf)
    BAR();
    __builtin_amdgcn_s_setprio(1);
#pragma unroll
    for (int mtp = 0; mtp < 4; mtp++)
#pragma unroll
      for (int ntp = 0; ntp < 2; ntp++)
#pragma unroll
        for (int kc = 0; kc < 2; kc++)
          acc[mtp][ntp + 2] = mfma16(af[mtp * 2 + kc], bfr[1][ntp * 2 + kc], acc[mtp][ntp + 2]);
    __builtin_amdgcn_s_setprio(0);
    BAR();

    // ---- p2: read A-hi; stage B1(t+2); MFMA Q11 ----
#pragma unroll
    for (int mtp = 0; mtp < 4; mtp++)
#pragma unroll
      for (int kc = 0; kc < 2; kc++) {
        int r = 64 + mtp * 16 + l15;
        int off = ((r << 7) + ((kc * 4 + l4) << 4)) ^ ((r & 7) << 4);
        af[mtp * 2 + kc] = *(const bf16x8_a*)(bA + off);
      }
    if (s2) STG_B(1, t + 2, buf)
    BAR();
    __builtin_amdgcn_s_setprio(1);
#pragma unroll
    for (int mtp = 0; mtp < 4; mtp++)
#pragma unroll
      for (int ntp = 0; ntp < 2; ntp++)
#pragma unroll
        for (int kc = 0; kc < 2; kc++)
          acc[mtp + 4][ntp + 2] = mfma16(af[mtp * 2 + kc], bfr[1][ntp * 2 + kc], acc[mtp + 4][ntp + 2]);
    __builtin_amdgcn_s_setprio(0);
    BAR();

    // ---- p3: stage A0,A1(t+2); MFMA Q10; vmcnt; BAR ----
    if (s2) { STG_A(0, t + 2, buf) STG_A(1, t + 2, buf) }
    BAR();
    __builtin_amdgcn_s_setprio(1);
#pragma unroll
    for (int mtp = 0; mtp < 4; mtp++)
#pragma unroll
      for (int ntp = 0; ntp < 2; ntp++)
#pragma unroll
        for (int kc = 0; kc < 2; kc++)
          acc[mtp + 4][ntp] = mfma16(af[mtp * 2 + kc], bfr[0][ntp * 2 + kc], acc[mtp + 4][ntp]);
    __builtin_amdgcn_s_setprio(0);
    if (s2) { WAITV(8); } else { WAITV(0); }
    BAR();
  }
#undef STG_A
#undef STG_B

  // ---- epilogue ----
#pragma unroll
  for (int mt = 0; mt < 8; mt++)
#pragma unroll
    for (int nt = 0; nt < 4; nt++)
#pragma unroll
      for (int rg = 0; rg < 4; rg++) {
        int row = row0 + wm * 128 + mt * 16 + l4 * 4 + rg;
        int cl = col0 + wn * 16 + nt * 64 + l15;
        float v = acc[mt][nt][rg];
        if (EPI == 2) {
          ((float*)C0)[(size_t)row * N + cl] = v;
        } else {
          if (cl < 3072) {
            int s = row & (SEQ - 1);
            float cc = ct[s * 64 + wn * 16 + l15];
            float ss = st[s * 64 + wn * 16 + l15];
            float pv = acc[mt][nt ^ 1][rg];
            v = (nt & 1) ? fmaf(v, cc, pv * ss) : fmaf(v, cc, -pv * ss);
          }
          if (cl < 2048) {
            v *= 1.7677669529663689e-3f;  // pre-scale Q by 1/(50*sqrt(128))
            ((bf16*)C0)[(size_t)row * 2048 + cl] = (bf16)v;
          } else if (cl < 3072) {
            ((bf16*)C1)[(size_t)row * 1024 + (cl - 2048)] = (bf16)v;
          } else {
            ((bf16*)C2)[(size_t)row * 1024 + (cl - 3072)] = (bf16)v;
          }
        }
      }
}

// ================= 256x128 2-phase GEMM (Wo, unchanged from R8) =================
__global__ __launch_bounds__(512, 2) void gemm2p(const bf16* __restrict__ A,
                                                 const bf16* __restrict__ BT,
                                                 float* __restrict__ C, int M, int N, int K) {
  __shared__ alignas(16) char ldsA[65536];
  __shared__ alignas(16) char ldsB[32768];
  const int tid = threadIdx.x, lane = tid & 63, w = tid >> 6;
  const int l15 = lane & 15, l4 = lane >> 4;
  const int wm = w >> 1, wn = w & 1;
  const int gx = gridDim.x;
  const int nwg = gx * gridDim.y;
  int id = blockIdx.y * gx + blockIdx.x;
  id = (id & 7) * (nwg >> 3) + (id >> 3);
  const int row0 = (id / gx) * 256;
  const int col0 = (id % gx) * 128;

  f32x4 acc[4][4];
#pragma unroll
  for (int mt = 0; mt < 4; mt++)
#pragma unroll
    for (int nt = 0; nt < 4; nt++) acc[mt][nt] = fzero4();

  const int rG0 = tid >> 3, sG0 = ((tid & 7) ^ (rG0 & 7)) * 8;
  const int ci1 = 512 + tid;
  const int rG1 = ci1 >> 3, sG1 = ((ci1 & 7) ^ (rG1 & 7)) * 8;
  const int dst0 = tid * 16, dst1 = (512 + tid) * 16;

  const bf16* Asrc = A + (size_t)row0 * K;
  const bf16* Bsrc = BT + (size_t)col0 * K;
  const int nk = K >> 6;

#define STG_A2(half, kt, buf)                                        \
  {                                                                  \
    char* d = ldsA + (buf) * 32768 + (half) * 16384;                 \
    const bf16* s = Asrc + (size_t)((half) * 128) * K + (kt) * 64;   \
    async16(d + dst0, s + (size_t)rG0 * K + sG0);                    \
    async16(d + dst1, s + (size_t)rG1 * K + sG1);                    \
  }
#define STG_B2(kt, buf)                                              \
  {                                                                  \
    char* d = ldsB + (buf) * 16384;                                  \
    const bf16* s = Bsrc + (kt) * 64;                                \
    async16(d + dst0, s + (size_t)rG0 * K + sG0);                    \
    async16(d + dst1, s + (size_t)rG1 * K + sG1);                    \
  }

  STG_A2(0, 0, 0) STG_A2(1, 0, 0) STG_B2(0, 0)
  STG_A2(0, 1, 1) STG_A2(1, 1, 1)
  WAITV(4);
  BAR();

  bf16x8 af[8];
  bf16x8 bfr[8];

  for (int t = 0; t < nk; ++t) {
    const int buf = t & 1;
    const char* bA = ldsA + buf * 32768 + (wm >> 1) * 16384;
    const char* bB = ldsB + buf * 16384;
    const bool s1 = (t + 1) < nk;
    const bool s2 = (t + 2) < nk;

    // ---- p0 ----
#pragma unroll
    for (int mt = 0; mt < 4; mt++)
#pragma unroll
      for (int kc = 0; kc < 2; kc++) {
        int r = (wm & 1) * 64 + mt * 16 + l15;
        int off = ((r << 7) + ((kc * 4 + l4) << 4)) ^ ((r & 7) << 4);
        af[mt * 2 + kc] = *(const bf16x8_a*)(bA + off);
      }
#pragma unroll
    for (int nt = 0; nt < 2; nt++)
#pragma unroll
      for (int kc = 0; kc < 2; kc++) {
        int c = wn * 16 + nt * 32 + l15;
        int off = ((c << 7) + ((kc * 4 + l4) << 4)) ^ ((c & 7) << 4);
        bfr[nt * 2 + kc] = *(const bf16x8_a*)(bB + off);
      }
    if (s1) STG_B2(t + 1, buf ^ 1)
    BAR();
    __builtin_amdgcn_s_setprio(1);
#pragma unroll
    for (int mt = 0; mt < 4; mt++)
#pragma unroll
      for (int nt = 0; nt < 2; nt++)
#pragma unroll
        for (int kc = 0; kc < 2; kc++)
          acc[mt][nt] = mfma16(af[mt * 2 + kc], bfr[nt * 2 + kc], acc[mt][nt]);
    __builtin_amdgcn_s_setprio(0);
    BAR();

    // ---- p1 ----
#pragma unroll
    for (int nt = 0; nt < 2; nt++)
#pragma unroll
      for (int kc = 0; kc < 2; kc++) {
        int c = wn * 16 + (nt + 2) * 32 + l15;
        int off = ((c << 7) + ((kc * 4 + l4) << 4)) ^ ((c & 7) << 4);
        bfr[4 + nt * 2 + kc] = *(const bf16x8_a*)(bB + off);
      }
    if (s2) { STG_A2(0, t + 2, buf) STG_A2(1, t + 2, buf) }
    BAR();
    __builtin_amdgcn_s_setprio(1);
#pragma unroll
    for (int mt = 0; mt < 4; mt++)
#pragma unroll
      for (int nt = 0; nt < 2; nt++)
#pragma unroll
        for (int kc = 0; kc < 2; kc++)
          acc[mt][nt + 2] = mfma16(af[mt * 2 + kc], bfr[4 + nt * 2 + kc], acc[mt][nt + 2]);
    __builtin_amdgcn_s_setprio(0);
    if (s2) { WAITV(4); } else { WAITV(0); }
    BAR();
  }
#undef STG_A2
#undef STG_B2

#pragma unroll
  for (int mt = 0; mt < 4; mt++)
#pragma unroll
    for (int nt = 0; nt < 4; nt++)
#pragma unroll
      for (int rg = 0; rg < 4; rg++) {
        int row = row0 + wm * 64 + mt * 16 + l4 * 4 + rg;
        int cl = col0 + wn * 16 + nt * 32 + l15;
        C[(size_t)row * N + cl] = acc[mt][nt][rg];
      }
}

// ========== Flash attention v7: 8 waves x 32q, in-register P, triple-buffered K/V ==========
// grid (qt=8, h=16, b=2) = 256 blocks (1/CU), 512 thr / 8 waves; wave = 32 q-rows.
// K/V LDS triple-buffered (96 KB): per tile {vmcnt(8); BAR; stage(t+2); compute}.
// Swapped QK^T via mfma32 (S^T[64kv][32q], q = lane col); softcap poly folded
// (Q pre-scaled in projection); P packed bf16 + shfl_xor(32) -> PV B-frags in-register.
__global__ __launch_bounds__(512, 2) void attn7(const bf16* __restrict__ Q,
                                                const bf16* __restrict__ Kg,
                                                const bf16* __restrict__ VTg,
                                                bf16* __restrict__ O) {
  __shared__ alignas(16) char ldsK[49152];   // 3 x [64 kv][128 d], 16-slot swizzle
  __shared__ alignas(16) char ldsV[49152];   // 3 x [128 d][64 kv], 8-slot swizzle
  const int tid = threadIdx.x, lane = tid & 63, w = tid >> 6;
  const int l31 = lane & 31, hl = lane >> 5;

  const int nx = gridDim.x, ny = gridDim.y;
  const int nwg = nx * ny * gridDim.z;  // 256
  int id = (blockIdx.z * ny + blockIdx.y) * nx + blockIdx.x;
  id = (id & 7) * (nwg >> 3) + (id >> 3);
  const int qt = id % nx; id /= nx;
  const int h = id % ny; const int b = id / ny;
  const int kvh = h >> 1;
  const int qrow = b * SEQ + qt * 256 + w * 32 + l31;

  // Q B-fragments: col=q=l31, k(d) = kc*16 + hl*8 + j  (Q pre-scaled by 1/(50*sqrt128))
  bf16x8 qf[8];
  const bf16* qp = Q + (size_t)qrow * (NHEAD * HD) + h * HD + hl * 8;
#pragma unroll
  for (int kc = 0; kc < 8; kc++) qf[kc] = *(const bf16x8_a*)(qp + kc * 16);

  f32x16 oT[4];
#pragma unroll
  for (int dt = 0; dt < 4; dt++)
#pragma unroll
    for (int r = 0; r < 16; r++) oT[dt][r] = 0.f;
  f32x2 ls2; ls2[0] = 0.f; ls2[1] = 0.f;

  // staging: 512 thr x (2 K + 2 V granules); linear LDS dest, inverse-swizzled source
  const int rK = tid >> 4, sK = (tid & 15) ^ (rK & 15);  // 16-slot swizzle
  const int rV = tid >> 3, sV = (tid & 7) ^ (rV & 7);    // 8-slot swizzle
  const size_t koff0 = (size_t)(b * SEQ + rK) * (NKV * HD) + kvh * HD + sK * 8;
  const size_t voff0 = ((size_t)(b * NKV + kvh) * HD + rV) * SEQ + sV * 8;

  const float Ac = 72.13475204444817f;    // 50*log2(e)
  const float Bc = -24.044917348149389f;  // Ac * (-1/3)
  const float Cc = 9.6179669392597558f;   // Ac * (2/15)

  auto STAGE = [&](int buf, int t) {
    char* dK = ldsK + buf * 16384;
    char* dV = ldsV + buf * 16384;
    const bf16* ks = Kg + koff0 + (size_t)t * (64 * NKV * HD);
    const bf16* vs = VTg + voff0 + (size_t)t * 64;
    async16(dK + tid * 16, ks);
    async16(dK + (512 + tid) * 16, ks + (size_t)32 * (NKV * HD));
    async16(dV + tid * 16, vs);
    async16(dV + (512 + tid) * 16, vs + (size_t)64 * SEQ);
  };

  constexpr int NT = SEQ / 64;  // 32
  STAGE(0, 0);
  STAGE(1, 1);

  int cur = 0;
  for (int t = 0; t < NT; ++t) {
    // own tile-t loads are the oldest; <=8 newer (t+1's) may remain
    if (t < NT - 1) { WAITV(8); } else { WAITV(0); }
    BAR();  // all waves' tile-t loads landed; tile-(t-1) readers done
    if (t + 2 < NT) {
      int nb = cur + 2; if (nb >= 3) nb -= 3;
      STAGE(nb, t + 2);  // overwrites tile-(t-1)'s buffer
    }

    const char* lK = ldsK + cur * 16384;
    const char* lV = ldsV + cur * 16384;

    // ---- swapped QK^T: S^T[64 kv][32 q] ----
    f32x16 sc[2];
#pragma unroll
    for (int r = 0; r < 16; r++) { sc[0][r] = 0.f; sc[1][r] = 0.f; }
    const int kvr0 = l31;
    const int kvr1 = 32 + l31;
    __builtin_amdgcn_s_setprio(1);
#pragma unroll
    for (int kc = 0; kc < 8; kc++) {
      int slot = kc * 2 + hl;
      int off0 = (kvr0 << 8) | ((slot ^ (kvr0 & 15)) << 4);
      int off1 = (kvr1 << 8) | ((slot ^ (kvr1 & 15)) << 4);
      bf16x8 kf0 = *(const bf16x8_a*)(lK + off0);
      bf16x8 kf1 = *(const bf16x8_a*)(lK + off1);
      sc[0] = mfma32(kf0, qf[kc], sc[0]);
      sc[1] = mfma32(kf1, qf[kc], sc[1]);
    }
    __builtin_amdgcn_s_setprio(0);

    // ---- softcap+exp (folded poly; z = capped/(50*sqrt128) pre-scaled) + PV ----
#pragma unroll
    for (int ntb = 0; ntb < 2; ntb++) {
      uint u[4][2], us[4][2];
#pragma unroll
      for (int r2 = 0; r2 < 8; r2++) {
        f32x2 z; z[0] = sc[ntb][2 * r2]; z[1] = sc[ntb][2 * r2 + 1];
        f32x2 z2 = z * z;
        f32x2 wv = z2 * (z2 * Cc + Bc) + Ac;
        f32x2 e = z * wv;
        float p0 = ex2(e[0]), p1 = ex2(e[1]);
        ls2[0] += p0; ls2[1] += p1;
        uint uu = pkbf16(p0, p1);
        u[r2 >> 1][r2 & 1] = uu;
        us[r2 >> 1][r2 & 1] = __shfl_xor(uu, 32);
      }
      __builtin_amdgcn_s_setprio(1);
#pragma unroll
      for (int sub = 0; sub < 2; sub++) {
        u32x4 bu;
        bu[0] = hl ? us[2 * sub + 1][0] : u[2 * sub][0];
        bu[1] = hl ? us[2 * sub + 1][1] : u[2 * sub][1];
        bu[2] = hl ? u[2 * sub + 1][0] : us[2 * sub][0];
        bu[3] = hl ? u[2 * sub + 1][1] : us[2 * sub][1];
        bf16x8 pb = __builtin_bit_cast(bf16x8, bu);
        const int kvb = ntb * 2 + sub;
        const int slot = kvb * 2 + hl;
#pragma unroll
        for (int dt = 0; dt < 4; dt++) {
          int d = dt * 32 + l31;
          int off = (d << 7) | ((slot ^ (d & 7)) << 4);
          bf16x8 vf = *(const bf16x8_a*)(lV + off);
          oT[dt] = mfma32(vf, pb, oT[dt]);
        }
      }
      __builtin_amdgcn_s_setprio(0);
    }

    cur = (cur == 2) ? 0 : cur + 1;
  }

  // ---- epilogue: full row-sum (two lanes per q), normalize, store O ----
  float lsum = ls2[0] + ls2[1];
  float lsf = lsum + __shfl_xor(lsum, 32);
  float inv = 1.0f / lsf;
  bf16* ob = O + (size_t)qrow * (NHEAD * HD) + h * HD;
#pragma unroll
  for (int dt = 0; dt < 4; dt++)
#pragma unroll
    for (int g = 0; g < 4; g++) {
      u32x2 pr;
      pr[0] = pkbf16(oT[dt][4 * g] * inv, oT[dt][4 * g + 1] * inv);
      pr[1] = pkbf16(oT[dt][4 * g + 2] * inv, oT[dt][4 * g + 3] * inv);
      *(u32x2_a*)(ob + dt * 32 + 8 * g + 4 * hl) = pr;
    }
}

extern "C" void kernel_launch(void* const* d_in, const int* in_sizes, int n_in,
                              void* d_out, int out_size, void* d_ws, size_t ws_size,
                              hipStream_t stream) {
  const float* X  = (const float*)d_in[0];
  const float* Wq = (const float*)d_in[1];
  const float* Wk = (const float*)d_in[2];
  const float* Wv = (const float*)d_in[3];
  const float* Wo = (const float*)d_in[4];
  float* out = (float*)d_out;

  char* ws = (char*)d_ws;
  size_t off = 0;
  auto alloc = [&](size_t bytes) {
    void* p = ws + off;
    off += (bytes + 255) & ~(size_t)255;
    return p;
  };
  bf16* Xb  = (bf16*)alloc((size_t)MROWS * HID * 2);
  // WqT/WkT/WvT adjacent & contiguous -> fused BT [4096][2048]
  bf16* WqT = (bf16*)alloc((size_t)2048 * 2048 * 2);
  bf16* WkT = (bf16*)alloc((size_t)1024 * 2048 * 2);
  bf16* WvT = (bf16*)alloc((size_t)1024 * 2048 * 2);
  bf16* WoT = (bf16*)alloc((size_t)2048 * 2048 * 2);
  bf16* Qb  = (bf16*)alloc((size_t)MROWS * 2048 * 2);
  bf16* Kb  = (bf16*)alloc((size_t)MROWS * 1024 * 2);
  bf16* Vb  = (bf16*)alloc((size_t)MROWS * 1024 * 2);
  bf16* VTb = (bf16*)alloc((size_t)16 * 128 * 2048 * 2);
  bf16* AOb = (bf16*)alloc((size_t)MROWS * 2048 * 2);
  float* ct = (float*)alloc((size_t)SEQ * 64 * 4);
  float* st = (float*)alloc((size_t)SEQ * 64 * 4);

  cast_f32_bf16<<<(MROWS * HID) / 1024, 256, 0, stream>>>(X, Xb, MROWS * HID);
  wtrans4<<<dim3(32, 32, 4), 256, 0, stream>>>(Wq, Wk, Wv, Wo, WqT, WkT, WvT, WoT);
  rope_tab<<<SEQ, 64, 0, stream>>>(ct, st);
  gemm8p<1><<<dim3(16, 16), 512, 0, stream>>>(Xb, WqT, Qb, Kb, Vb, MROWS, 4096, 2048, ct, st);
  vtrans<<<dim3(32, 2, 16), 256, 0, stream>>>(Vb, VTb);
  attn7<<<dim3(8, 16, 2), 512, 0, stream>>>(Qb, Kb, VTb, AOb);
  gemm2p<<<dim3(16, 16), 512, 0, stream>>>(AOb, WoT, out, MROWS, 2048, 2048);

  (void)in_sizes; (void)n_in; (void)out_size; (void)ws_size;
}

// Round 11
// 248.886 us; speedup vs baseline: 1.2882x; 1.0096x over previous
//
#include <hip/hip_runtime.h>
#include <math.h>

typedef __bf16 bf16;
typedef __bf16 bf16x8 __attribute__((ext_vector_type(8)));
typedef __bf16 bf16x4 __attribute__((ext_vector_type(4)));
typedef float f32x2 __attribute__((ext_vector_type(2)));
typedef float f32x4 __attribute__((ext_vector_type(4)));
typedef float f32x16 __attribute__((ext_vector_type(16)));
typedef unsigned int uint;
typedef uint u32x4 __attribute__((ext_vector_type(4)));
typedef uint u32x2 __attribute__((ext_vector_type(2)));
typedef __bf16 bf16x8_a __attribute__((ext_vector_type(8), __may_alias__));
typedef uint u32x2_a __attribute__((ext_vector_type(2), __may_alias__));
typedef __bf16 bf16_a __attribute__((__may_alias__));

constexpr int BATCH = 2;
constexpr int SEQ   = 2048;
constexpr int HID   = 2048;
constexpr int NHEAD = 16;
constexpr int NKV   = 8;
constexpr int HD    = 128;
constexpr int MROWS = BATCH * SEQ; // 4096

#define DEVINL __device__ __forceinline__

// raw barrier with compiler reorder fence (no implicit vmcnt/lgkm drain)
#define BAR()                                 \
  do {                                        \
    asm volatile("" ::: "memory");            \
    __builtin_amdgcn_s_barrier();             \
    asm volatile("" ::: "memory");            \
  } while (0)

#define WAITV(N) asm volatile("s_waitcnt vmcnt(" #N ")" ::: "memory")

DEVINL void async16(void* l, const void* g) {
  __builtin_amdgcn_global_load_lds((const __attribute__((address_space(1))) void*)g,
                                   (__attribute__((address_space(3))) void*)l, 16, 0, 0);
}

DEVINL f32x4 mfma16(bf16x8 a, bf16x8 b, f32x4 c) {
  return __builtin_amdgcn_mfma_f32_16x16x32_bf16(a, b, c, 0, 0, 0);
}
DEVINL f32x16 mfma32(bf16x8 a, bf16x8 b, f32x16 c) {
  return __builtin_amdgcn_mfma_f32_32x32x16_bf16(a, b, c, 0, 0, 0);
}

DEVINL f32x4 fzero4() { f32x4 z; z[0] = 0.f; z[1] = 0.f; z[2] = 0.f; z[3] = 0.f; return z; }

DEVINL float ex2(float x) {
#if __has_builtin(__builtin_amdgcn_exp2f)
  return __builtin_amdgcn_exp2f(x);
#else
  return __expf(x * 0.6931471805599453f);
#endif
}

DEVINL uint pkbf16(float lo, float hi) {
  unsigned short l = __builtin_bit_cast(unsigned short, (bf16)lo);
  unsigned short h = __builtin_bit_cast(unsigned short, (bf16)hi);
  return (uint)l | ((uint)h << 16);
}

// ---------------- elementwise cast f32 -> bf16 ----------------
__global__ __launch_bounds__(256) void cast_f32_bf16(const float* __restrict__ x,
                                                     bf16* __restrict__ y, int n) {
  int i = (blockIdx.x * 256 + threadIdx.x) * 4;
  if (i + 3 < n) {
    float4 v = *(const float4*)(x + i);
    bf16x4 o;
    o[0] = (bf16)v.x; o[1] = (bf16)v.y; o[2] = (bf16)v.z; o[3] = (bf16)v.w;
    *(bf16x4*)(y + i) = o;
  }
}

// ---------------- all-W transpose f32[K][N] -> bf16 WT[N][K], K=2048 ----------------
__global__ __launch_bounds__(256) void wtrans4(const float* __restrict__ Wq,
                                               const float* __restrict__ Wk,
                                               const float* __restrict__ Wv,
                                               const float* __restrict__ Wo,
                                               bf16* __restrict__ WqT, bf16* __restrict__ WkT,
                                               bf16* __restrict__ WvT, bf16* __restrict__ WoT) {
  __shared__ bf16 t[64][65];
  const float* W; bf16* WT; int N;
  switch (blockIdx.z) {
    case 0: W = Wq; WT = WqT; N = 2048; break;
    case 1: W = Wk; WT = WkT; N = 1024; break;
    case 2: W = Wv; WT = WvT; N = 1024; break;
    default: W = Wo; WT = WoT; N = 2048; break;
  }
  int n0 = blockIdx.x * 64, k0 = blockIdx.y * 64;
  if (n0 >= N) return;
  for (int i = threadIdx.x; i < 4096; i += 256) {
    int r = i >> 6, c = i & 63;
    t[r][c] = (bf16)W[(size_t)(k0 + r) * N + n0 + c];
  }
  __syncthreads();
  for (int i = threadIdx.x; i < 4096; i += 256) {
    int r = i >> 6, c = i & 63;
    WT[(size_t)(n0 + r) * 2048 + k0 + c] = t[c][r];
  }
}

// ---------------- V[b*S+s][kvh*128+d] -> VT[(b*8+kvh)*128+d][s] ----------------
__global__ __launch_bounds__(256) void vtrans(const bf16* __restrict__ V, bf16* __restrict__ VT) {
  __shared__ bf16 t[64][65];
  int s0 = blockIdx.x * 64, d0 = blockIdx.y * 64;
  int bh = blockIdx.z, b = bh >> 3, kvh = bh & 7;
  for (int i = threadIdx.x; i < 4096; i += 256) {
    int r = i >> 6, c = i & 63;
    t[r][c] = V[(size_t)(b * SEQ + s0 + r) * (NKV * HD) + kvh * HD + d0 + c];
  }
  __syncthreads();
  for (int i = threadIdx.x; i < 4096; i += 256) {
    int r = i >> 6, c = i & 63;
    VT[((size_t)bh * HD + d0 + r) * SEQ + s0 + c] = t[c][r];
  }
}

// ---------------- RoPE tables: cos/sin [SEQ][64] ----------------
__global__ void rope_tab(float* __restrict__ ct, float* __restrict__ st) {
  int s = blockIdx.x, d = threadIdx.x;
  float freq = powf(10000.0f, -(float)d * (1.0f / 64.0f));
  float a = (float)s * freq;
  ct[s * 64 + d] = cosf(a);
  st[s * 64 + d] = sinf(a);
}

// ================= 256x256 8-phase GEMM (m201-style, unchanged from R10) =================
template <int EPI>
__global__ __launch_bounds__(512, 2) void gemm8p(const bf16* __restrict__ A,
                                                 const bf16* __restrict__ BT,
                                                 void* __restrict__ C0, void* __restrict__ C1,
                                                 void* __restrict__ C2, int M, int N, int K,
                                                 const float* __restrict__ ct,
                                                 const float* __restrict__ st) {
  __shared__ alignas(16) char ldsA[65536];  // [buf][half][128r][64k]
  __shared__ alignas(16) char ldsB[65536];
  const int tid = threadIdx.x, lane = tid & 63, w = tid >> 6;
  const int l15 = lane & 15, l4 = lane >> 4;
  const int wm = w >> 2, wn = w & 3;
  const int gx = gridDim.x;
  const int nwg = gx * gridDim.y;
  int id = blockIdx.y * gx + blockIdx.x;
  id = (id & 7) * (nwg >> 3) + (id >> 3);
  const int row0 = (id / gx) * 256;
  const int col0 = (id % gx) * 256;

  f32x4 acc[8][4];
#pragma unroll
  for (int mt = 0; mt < 8; mt++)
#pragma unroll
    for (int nt = 0; nt < 4; nt++) acc[mt][nt] = fzero4();

  const int rG0 = tid >> 3, sG0 = ((tid & 7) ^ (rG0 & 7)) * 8;
  const int ci1 = 512 + tid;
  const int rG1 = ci1 >> 3, sG1 = ((ci1 & 7) ^ (rG1 & 7)) * 8;
  const int dst0 = tid * 16, dst1 = (512 + tid) * 16;

  const bf16* Asrc = A + (size_t)row0 * K;
  const bf16* Bsrc = BT + (size_t)col0 * K;
  const int nk = K >> 6;

#define STG_A(half, kt, buf)                                         \
  {                                                                  \
    char* d = ldsA + (buf) * 32768 + (half) * 16384;                 \
    const bf16* s = Asrc + (size_t)((half) * 128) * K + (kt) * 64;   \
    async16(d + dst0, s + (size_t)rG0 * K + sG0);                    \
    async16(d + dst1, s + (size_t)rG1 * K + sG1);                    \
  }
#define STG_B(half, kt, buf)                                         \
  {                                                                  \
    char* d = ldsB + (buf) * 32768 + (half) * 16384;                 \
    const bf16* s = Bsrc + (size_t)((half) * 128) * K + (kt) * 64;   \
    async16(d + dst0, s + (size_t)rG0 * K + sG0);                    \
    async16(d + dst1, s + (size_t)rG1 * K + sG1);                    \
  }

  // prologue: tiles 0 and 1 fully staged (16 loads)
  STG_A(0, 0, 0) STG_A(1, 0, 0) STG_B(0, 0, 0) STG_B(1, 0, 0)
  STG_B(0, 1, 1) STG_B(1, 1, 1) STG_A(0, 1, 1) STG_A(1, 1, 1)
  WAITV(8);
  BAR();

  bf16x8 af[8];
  bf16x8 bfr[2][4];

  for (int t = 0; t < nk; ++t) {
    const int buf = t & 1;
    const char* bA = ldsA + buf * 32768 + wm * 16384;
    const char* bB = ldsB + buf * 32768;
    const bool s2 = (t + 2) < nk;

    // ---- p0: read A-lo + B-half0; MFMA Q00 ----
#pragma unroll
    for (int mtp = 0; mtp < 4; mtp++)
#pragma unroll
      for (int kc = 0; kc < 2; kc++) {
        int r = mtp * 16 + l15;
        int off = ((r << 7) + ((kc * 4 + l4) << 4)) ^ ((r & 7) << 4);
        af[mtp * 2 + kc] = *(const bf16x8_a*)(bA + off);
      }
#pragma unroll
    for (int ntp = 0; ntp < 2; ntp++)
#pragma unroll
      for (int kc = 0; kc < 2; kc++) {
        int c = wn * 16 + ntp * 64 + l15;
        int off = ((c << 7) + ((kc * 4 + l4) << 4)) ^ ((c & 7) << 4);
        bfr[0][ntp * 2 + kc] = *(const bf16x8_a*)(bB + off);
      }
    BAR();
    __builtin_amdgcn_s_setprio(1);
#pragma unroll
    for (int mtp = 0; mtp < 4; mtp++)
#pragma unroll
      for (int ntp = 0; ntp < 2; ntp++)
#pragma unroll
        for (int kc = 0; kc < 2; kc++)
          acc[mtp][ntp] = mfma16(af[mtp * 2 + kc], bfr[0][ntp * 2 + kc], acc[mtp][ntp]);
    __builtin_amdgcn_s_setprio(0);
    BAR();

    // ---- p1: read B-half1; stage B0(t+2); MFMA Q01 ----
#pragma unroll
    for (int ntp = 0; ntp < 2; ntp++)
#pragma unroll
      for (int kc = 0; kc < 2; kc++) {
        int c = wn * 16 + ntp * 64 + l15;
        int off = 16384 + (((c << 7) + ((kc * 4 + l4) << 4)) ^ ((c & 7) << 4));
        bfr[1][ntp * 2 + kc] = *(const bf16x8_a*)(bB + off);
      }
    if (s2) STG_B(0, t + 2, buf)
    BAR();
    __builtin_amdgcn_s_setprio(1);
#pragma unroll
    for (int mtp = 0; mtp < 4; mtp++)
#pragma unroll
      for (int ntp = 0; ntp < 2; ntp++)
#pragma unroll
        for (int kc = 0; kc < 2; kc++)
          acc[mtp][ntp + 2] = mfma16(af[mtp * 2 + kc], bfr[1][ntp * 2 + kc], acc[mtp][ntp + 2]);
    __builtin_amdgcn_s_setprio(0);
    BAR();

    // ---- p2: read A-hi; stage B1(t+2); MFMA Q11 ----
#pragma unroll
    for (int mtp = 0; mtp < 4; mtp++)
#pragma unroll
      for (int kc = 0; kc < 2; kc++) {
        int r = 64 + mtp * 16 + l15;
        int off = ((r << 7) + ((kc * 4 + l4) << 4)) ^ ((r & 7) << 4);
        af[mtp * 2 + kc] = *(const bf16x8_a*)(bA + off);
      }
    if (s2) STG_B(1, t + 2, buf)
    BAR();
    __builtin_amdgcn_s_setprio(1);
#pragma unroll
    for (int mtp = 0; mtp < 4; mtp++)
#pragma unroll
      for (int ntp = 0; ntp < 2; ntp++)
#pragma unroll
        for (int kc = 0; kc < 2; kc++)
          acc[mtp + 4][ntp + 2] = mfma16(af[mtp * 2 + kc], bfr[1][ntp * 2 + kc], acc[mtp + 4][ntp + 2]);
    __builtin_amdgcn_s_setprio(0);
    BAR();

    // ---- p3: stage A0,A1(t+2); MFMA Q10; vmcnt; BAR ----
    if (s2) { STG_A(0, t + 2, buf) STG_A(1, t + 2, buf) }
    BAR();
    __builtin_amdgcn_s_setprio(1);
#pragma unroll
    for (int mtp = 0; mtp < 4; mtp++)
#pragma unroll
      for (int ntp = 0; ntp < 2; ntp++)
#pragma unroll
        for (int kc = 0; kc < 2; kc++)
          acc[mtp + 4][ntp] = mfma16(af[mtp * 2 + kc], bfr[0][ntp * 2 + kc], acc[mtp + 4][ntp]);
    __builtin_amdgcn_s_setprio(0);
    if (s2) { WAITV(8); } else { WAITV(0); }
    BAR();
  }
#undef STG_A
#undef STG_B

  // ---- epilogue ----
#pragma unroll
  for (int mt = 0; mt < 8; mt++)
#pragma unroll
    for (int nt = 0; nt < 4; nt++)
#pragma unroll
      for (int rg = 0; rg < 4; rg++) {
        int row = row0 + wm * 128 + mt * 16 + l4 * 4 + rg;
        int cl = col0 + wn * 16 + nt * 64 + l15;
        float v = acc[mt][nt][rg];
        if (EPI == 2) {
          ((float*)C0)[(size_t)row * N + cl] = v;
        } else {
          if (cl < 3072) {
            int s = row & (SEQ - 1);
            float cc = ct[s * 64 + wn * 16 + l15];
            float ss = st[s * 64 + wn * 16 + l15];
            float pv = acc[mt][nt ^ 1][rg];
            v = (nt & 1) ? fmaf(v, cc, pv * ss) : fmaf(v, cc, -pv * ss);
          }
          if (cl < 2048) {
            v *= 1.7677669529663689e-3f;  // pre-scale Q by 1/(50*sqrt(128))
            ((bf16*)C0)[(size_t)row * 2048 + cl] = (bf16)v;
          } else if (cl < 3072) {
            ((bf16*)C1)[(size_t)row * 1024 + (cl - 2048)] = (bf16)v;
          } else {
            ((bf16*)C2)[(size_t)row * 1024 + (cl - 3072)] = (bf16)v;
          }
        }
      }
}

// ================= 256x128 2-phase GEMM (Wo, unchanged from R10) =================
__global__ __launch_bounds__(512, 2) void gemm2p(const bf16* __restrict__ A,
                                                 const bf16* __restrict__ BT,
                                                 float* __restrict__ C, int M, int N, int K) {
  __shared__ alignas(16) char ldsA[65536];
  __shared__ alignas(16) char ldsB[32768];
  const int tid = threadIdx.x, lane = tid & 63, w = tid >> 6;
  const int l15 = lane & 15, l4 = lane >> 4;
  const int wm = w >> 1, wn = w & 1;
  const int gx = gridDim.x;
  const int nwg = gx * gridDim.y;
  int id = blockIdx.y * gx + blockIdx.x;
  id = (id & 7) * (nwg >> 3) + (id >> 3);
  const int row0 = (id / gx) * 256;
  const int col0 = (id % gx) * 128;

  f32x4 acc[4][4];
#pragma unroll
  for (int mt = 0; mt < 4; mt++)
#pragma unroll
    for (int nt = 0; nt < 4; nt++) acc[mt][nt] = fzero4();

  const int rG0 = tid >> 3, sG0 = ((tid & 7) ^ (rG0 & 7)) * 8;
  const int ci1 = 512 + tid;
  const int rG1 = ci1 >> 3, sG1 = ((ci1 & 7) ^ (rG1 & 7)) * 8;
  const int dst0 = tid * 16, dst1 = (512 + tid) * 16;

  const bf16* Asrc = A + (size_t)row0 * K;
  const bf16* Bsrc = BT + (size_t)col0 * K;
  const int nk = K >> 6;

#define STG_A2(half, kt, buf)                                        \
  {                                                                  \
    char* d = ldsA + (buf) * 32768 + (half) * 16384;                 \
    const bf16* s = Asrc + (size_t)((half) * 128) * K + (kt) * 64;   \
    async16(d + dst0, s + (size_t)rG0 * K + sG0);                    \
    async16(d + dst1, s + (size_t)rG1 * K + sG1);                    \
  }
#define STG_B2(kt, buf)                                              \
  {                                                                  \
    char* d = ldsB + (buf) * 16384;                                  \
    const bf16* s = Bsrc + (kt) * 64;                                \
    async16(d + dst0, s + (size_t)rG0 * K + sG0);                    \
    async16(d + dst1, s + (size_t)rG1 * K + sG1);                    \
  }

  STG_A2(0, 0, 0) STG_A2(1, 0, 0) STG_B2(0, 0)
  STG_A2(0, 1, 1) STG_A2(1, 1, 1)
  WAITV(4);
  BAR();

  bf16x8 af[8];
  bf16x8 bfr[8];

  for (int t = 0; t < nk; ++t) {
    const int buf = t & 1;
    const char* bA = ldsA + buf * 32768 + (wm >> 1) * 16384;
    const char* bB = ldsB + buf * 16384;
    const bool s1 = (t + 1) < nk;
    const bool s2 = (t + 2) < nk;

    // ---- p0 ----
#pragma unroll
    for (int mt = 0; mt < 4; mt++)
#pragma unroll
      for (int kc = 0; kc < 2; kc++) {
        int r = (wm & 1) * 64 + mt * 16 + l15;
        int off = ((r << 7) + ((kc * 4 + l4) << 4)) ^ ((r & 7) << 4);
        af[mt * 2 + kc] = *(const bf16x8_a*)(bA + off);
      }
#pragma unroll
    for (int nt = 0; nt < 2; nt++)
#pragma unroll
      for (int kc = 0; kc < 2; kc++) {
        int c = wn * 16 + nt * 32 + l15;
        int off = ((c << 7) + ((kc * 4 + l4) << 4)) ^ ((c & 7) << 4);
        bfr[nt * 2 + kc] = *(const bf16x8_a*)(bB + off);
      }
    if (s1) STG_B2(t + 1, buf ^ 1)
    BAR();
    __builtin_amdgcn_s_setprio(1);
#pragma unroll
    for (int mt = 0; mt < 4; mt++)
#pragma unroll
      for (int nt = 0; nt < 2; nt++)
#pragma unroll
        for (int kc = 0; kc < 2; kc++)
          acc[mt][nt] = mfma16(af[mt * 2 + kc], bfr[nt * 2 + kc], acc[mt][nt]);
    __builtin_amdgcn_s_setprio(0);
    BAR();

    // ---- p1 ----
#pragma unroll
    for (int nt = 0; nt < 2; nt++)
#pragma unroll
      for (int kc = 0; kc < 2; kc++) {
        int c = wn * 16 + (nt + 2) * 32 + l15;
        int off = ((c << 7) + ((kc * 4 + l4) << 4)) ^ ((c & 7) << 4);
        bfr[4 + nt * 2 + kc] = *(const bf16x8_a*)(bB + off);
      }
    if (s2) { STG_A2(0, t + 2, buf) STG_A2(1, t + 2, buf) }
    BAR();
    __builtin_amdgcn_s_setprio(1);
#pragma unroll
    for (int mt = 0; mt < 4; mt++)
#pragma unroll
      for (int nt = 0; nt < 2; nt++)
#pragma unroll
        for (int kc = 0; kc < 2; kc++)
          acc[mt][nt + 2] = mfma16(af[mt * 2 + kc], bfr[4 + nt * 2 + kc], acc[mt][nt + 2]);
    __builtin_amdgcn_s_setprio(0);
    if (s2) { WAITV(4); } else { WAITV(0); }
    BAR();
  }
#undef STG_A2
#undef STG_B2

#pragma unroll
  for (int mt = 0; mt < 4; mt++)
#pragma unroll
    for (int nt = 0; nt < 4; nt++)
#pragma unroll
      for (int rg = 0; rg < 4; rg++) {
        int row = row0 + wm * 64 + mt * 16 + l4 * 4 + rg;
        int cl = col0 + wn * 16 + nt * 32 + l15;
        C[(size_t)row * N + cl] = acc[mt][nt][rg];
      }
}

// ========== Flash attention v8: 2-deep pipeline (softmax(t) || QK^T(t+1)) ==========
// grid (qt=8, h=16, b=2) = 256 blocks, 512 thr / 8 waves; wave = 32 q-rows.
// Triple-buffered K/V LDS. Per iter: {BAR; stage(t+2); softmax(t); WAITV(4);
// QK(t+1)+PV(t) MFMA cluster}. scA/scB named 2-deep score regs (unroll x2).
__global__ __launch_bounds__(512, 2) void attn8(const bf16* __restrict__ Q,
                                                const bf16* __restrict__ Kg,
                                                const bf16* __restrict__ VTg,
                                                bf16* __restrict__ O) {
  __shared__ alignas(16) char ldsK[49152];   // 3 x [64 kv][128 d], 16-slot swizzle
  __shared__ alignas(16) char ldsV[49152];   // 3 x [128 d][64 kv], 8-slot swizzle
  const int tid = threadIdx.x, lane = tid & 63, w = tid >> 6;
  const int l31 = lane & 31, hl = lane >> 5;

  const int nx = gridDim.x, ny = gridDim.y;
  const int nwg = nx * ny * gridDim.z;  // 256
  int id = (blockIdx.z * ny + blockIdx.y) * nx + blockIdx.x;
  id = (id & 7) * (nwg >> 3) + (id >> 3);
  const int qt = id % nx; id /= nx;
  const int h = id % ny; const int b = id / ny;
  const int kvh = h >> 1;
  const int qrow = b * SEQ + qt * 256 + w * 32 + l31;

  // Q B-fragments: col=q=l31, k(d) = kc*16 + hl*8 + j  (Q pre-scaled by 1/(50*sqrt128))
  bf16x8 qf[8];
  const bf16* qp = Q + (size_t)qrow * (NHEAD * HD) + h * HD + hl * 8;
#pragma unroll
  for (int kc = 0; kc < 8; kc++) qf[kc] = *(const bf16x8_a*)(qp + kc * 16);

  f32x16 oT[4];
#pragma unroll
  for (int dt = 0; dt < 4; dt++)
#pragma unroll
    for (int r = 0; r < 16; r++) oT[dt][r] = 0.f;
  f32x2 ls2; ls2[0] = 0.f; ls2[1] = 0.f;

  // staging: 512 thr x (2 K + 2 V granules); linear LDS dest, inverse-swizzled source
  const int rK = tid >> 4, sK = (tid & 15) ^ (rK & 15);  // 16-slot swizzle
  const int rV = tid >> 3, sV = (tid & 7) ^ (rV & 7);    // 8-slot swizzle
  const size_t koff0 = (size_t)(b * SEQ + rK) * (NKV * HD) + kvh * HD + sK * 8;
  const size_t voff0 = ((size_t)(b * NKV + kvh) * HD + rV) * SEQ + sV * 8;

  const float Ac = 72.13475204444817f;    // 50*log2(e)
  const float Bc = -24.044917348149389f;  // Ac * (-1/3)
  const float Cc = 9.6179669392597558f;   // Ac * (2/15)

  auto STAGE = [&](int buf, int t) {
    char* dK = ldsK + buf * 16384;
    char* dV = ldsV + buf * 16384;
    const bf16* ks = Kg + koff0 + (size_t)t * (64 * NKV * HD);
    const bf16* vs = VTg + voff0 + (size_t)t * 64;
    async16(dK + tid * 16, ks);
    async16(dK + (512 + tid) * 16, ks + (size_t)32 * (NKV * HD));
    async16(dV + tid * 16, vs);
    async16(dV + (512 + tid) * 16, vs + (size_t)64 * SEQ);
  };

  const int kvr0 = l31, kvr1 = 32 + l31;

  // QK^T into SC (S^T[64 kv][32 q]); lK = base of K buffer
#define QKT(SC, lKp)                                                     \
  do {                                                                   \
    _Pragma("unroll")                                                    \
    for (int r = 0; r < 16; r++) { (SC)[0][r] = 0.f; (SC)[1][r] = 0.f; } \
    _Pragma("unroll")                                                    \
    for (int kc = 0; kc < 8; kc++) {                                     \
      int slot = kc * 2 + hl;                                            \
      int off0 = (kvr0 << 8) | ((slot ^ (kvr0 & 15)) << 4);              \
      int off1 = (kvr1 << 8) | ((slot ^ (kvr1 & 15)) << 4);              \
      bf16x8 kf0 = *(const bf16x8_a*)((lKp) + off0);                     \
      bf16x8 kf1 = *(const bf16x8_a*)((lKp) + off1);                     \
      (SC)[0] = mfma32(kf0, qf[kc], (SC)[0]);                            \
      (SC)[1] = mfma32(kf1, qf[kc], (SC)[1]);                            \
    }                                                                    \
  } while (0)

  // softcap+exp+pack+half-exchange: SC -> pb[4] (PV A-frags, kvb = 0..3)
#define SOFTMAX(SC, PB)                                                  \
  do {                                                                   \
    _Pragma("unroll")                                                    \
    for (int ntb = 0; ntb < 2; ntb++) {                                  \
      uint u[4][2], us[4][2];                                            \
      _Pragma("unroll")                                                  \
      for (int r2 = 0; r2 < 8; r2++) {                                   \
        f32x2 z; z[0] = (SC)[ntb][2 * r2]; z[1] = (SC)[ntb][2 * r2 + 1]; \
        f32x2 z2 = z * z;                                                \
        f32x2 wv = z2 * (z2 * Cc + Bc) + Ac;                             \
        f32x2 e = z * wv;                                                \
        float p0 = ex2(e[0]), p1 = ex2(e[1]);                            \
        ls2[0] += p0; ls2[1] += p1;                                      \
        uint uu = pkbf16(p0, p1);                                        \
        u[r2 >> 1][r2 & 1] = uu;                                         \
        us[r2 >> 1][r2 & 1] = __shfl_xor(uu, 32);                        \
      }                                                                  \
      _Pragma("unroll")                                                  \
      for (int sub = 0; sub < 2; sub++) {                                \
        u32x4 bu;                                                        \
        bu[0] = hl ? us[2 * sub + 1][0] : u[2 * sub][0];                 \
        bu[1] = hl ? us[2 * sub + 1][1] : u[2 * sub][1];                 \
        bu[2] = hl ? u[2 * sub + 1][0] : us[2 * sub][0];                 \
        bu[3] = hl ? u[2 * sub + 1][1] : us[2 * sub][1];                 \
        (PB)[ntb * 2 + sub] = __builtin_bit_cast(bf16x8, bu);            \
      }                                                                  \
    }                                                                    \
  } while (0)

  // PV: oT += V^T(buf) x PB
#define PVACC(PB, lVp)                                                   \
  do {                                                                   \
    _Pragma("unroll")                                                    \
    for (int kvb = 0; kvb < 4; kvb++) {                                  \
      int slot = kvb * 2 + hl;                                           \
      _Pragma("unroll")                                                  \
      for (int dt = 0; dt < 4; dt++) {                                   \
        int d = dt * 32 + l31;                                           \
        int off = (d << 7) | ((slot ^ (d & 7)) << 4);                    \
        bf16x8 vf = *(const bf16x8_a*)((lVp) + off);                     \
        oT[dt] = mfma32(vf, (PB)[kvb], oT[dt]);                          \
      }                                                                  \
    }                                                                    \
  } while (0)

  constexpr int NT = SEQ / 64;  // 32
  STAGE(0, 0);
  STAGE(1, 1);
  WAITV(4);  // tile 0 landed (tile 1's 4 loads may be pending)
  BAR();

  f32x16 scA[2], scB[2];
  bf16x8 pb[4];
  QKT(scA, ldsK);  // tile 0, buf 0

  // 2-deep pipeline, unrolled x2 so score registers are compile-time named
  for (int it = 0; it < NT / 2; ++it) {
    const int t0 = 2 * it;
    // ---- even sub-iter: cur = scA, next = scB ----
    {
      const int t = t0;
      BAR();  // all waves finished QK(t) & PV(t-1) LDS reads
      if (t + 2 < NT) STAGE((t + 2) % 3, t + 2);
      SOFTMAX(scA, pb);
      if (t + 1 < NT) {
        WAITV(4);  // tile t+1 landed
        __builtin_amdgcn_s_setprio(1);
        QKT(scB, ldsK + ((t + 1) % 3) * 16384);
        PVACC(pb, ldsV + (t % 3) * 16384);
        __builtin_amdgcn_s_setprio(0);
      } else {
        __builtin_amdgcn_s_setprio(1);
        PVACC(pb, ldsV + (t % 3) * 16384);
        __builtin_amdgcn_s_setprio(0);
      }
    }
    // ---- odd sub-iter: cur = scB, next = scA ----
    {
      const int t = t0 + 1;
      BAR();
      if (t + 2 < NT) STAGE((t + 2) % 3, t + 2);
      SOFTMAX(scB, pb);
      if (t + 1 < NT) {
        WAITV(4);
        __builtin_amdgcn_s_setprio(1);
        QKT(scA, ldsK + ((t + 1) % 3) * 16384);
        PVACC(pb, ldsV + (t % 3) * 16384);
        __builtin_amdgcn_s_setprio(0);
      } else {
        __builtin_amdgcn_s_setprio(1);
        PVACC(pb, ldsV + (t % 3) * 16384);
        __builtin_amdgcn_s_setprio(0);
      }
    }
  }
#undef QKT
#undef SOFTMAX
#undef PVACC

  // ---- epilogue: full row-sum (two lanes per q), normalize, store O ----
  float lsum = ls2[0] + ls2[1];
  float lsf = lsum + __shfl_xor(lsum, 32);
  float inv = 1.0f / lsf;
  bf16* ob = O + (size_t)qrow * (NHEAD * HD) + h * HD;
#pragma unroll
  for (int dt = 0; dt < 4; dt++)
#pragma unroll
    for (int g = 0; g < 4; g++) {
      u32x2 pr;
      pr[0] = pkbf16(oT[dt][4 * g] * inv, oT[dt][4 * g + 1] * inv);
      pr[1] = pkbf16(oT[dt][4 * g + 2] * inv, oT[dt][4 * g + 3] * inv);
      *(u32x2_a*)(ob + dt * 32 + 8 * g + 4 * hl) = pr;
    }
}

extern "C" void kernel_launch(void* const* d_in, const int* in_sizes, int n_in,
                              void* d_out, int out_size, void* d_ws, size_t ws_size,
                              hipStream_t stream) {
  const float* X  = (const float*)d_in[0];
  const float* Wq = (const float*)d_in[1];
  const float* Wk = (const float*)d_in[2];
  const float* Wv = (const float*)d_in[3];
  const float* Wo = (const float*)d_in[4];
  float* out = (float*)d_out;

  char* ws = (char*)d_ws;
  size_t off = 0;
  auto alloc = [&](size_t bytes) {
    void* p = ws + off;
    off += (bytes + 255) & ~(size_t)255;
    return p;
  };
  bf16* Xb  = (bf16*)alloc((size_t)MROWS * HID * 2);
  // WqT/WkT/WvT adjacent & contiguous -> fused BT [4096][2048]
  bf16* WqT = (bf16*)alloc((size_t)2048 * 2048 * 2);
  bf16* WkT = (bf16*)alloc((size_t)1024 * 2048 * 2);
  bf16* WvT = (bf16*)alloc((size_t)1024 * 2048 * 2);
  bf16* WoT = (bf16*)alloc((size_t)2048 * 2048 * 2);
  bf16* Qb  = (bf16*)alloc((size_t)MROWS * 2048 * 2);
  bf16* Kb  = (bf16*)alloc((size_t)MROWS * 1024 * 2);
  bf16* Vb  = (bf16*)alloc((size_t)MROWS * 1024 * 2);
  bf16* VTb = (bf16*)alloc((size_t)16 * 128 * 2048 * 2);
  bf16* AOb = (bf16*)alloc((size_t)MROWS * 2048 * 2);
  float* ct = (float*)alloc((size_t)SEQ * 64 * 4);
  float* st = (float*)alloc((size_t)SEQ * 64 * 4);

  cast_f32_bf16<<<(MROWS * HID) / 1024, 256, 0, stream>>>(X, Xb, MROWS * HID);
  wtrans4<<<dim3(32, 32, 4), 256, 0, stream>>>(Wq, Wk, Wv, Wo, WqT, WkT, WvT, WoT);
  rope_tab<<<SEQ, 64, 0, stream>>>(ct, st);
  gemm8p<1><<<dim3(16, 16), 512, 0, stream>>>(Xb, WqT, Qb, Kb, Vb, MROWS, 4096, 2048, ct, st);
  vtrans<<<dim3(32, 2, 16), 256, 0, stream>>>(Vb, VTb);
  attn8<<<dim3(8, 16, 2), 512, 0, stream>>>(Qb, Kb, VTb, AOb);
  gemm2p<<<dim3(16, 16), 512, 0, stream>>>(AOb, WoT, out, MROWS, 2048, 2048);

  (void)in_sizes; (void)n_in; (void)out_size; (void)ws_size;
}

// Round 12
// 241.833 us; speedup vs baseline: 1.3258x; 1.0292x over previous
//
#include <hip/hip_runtime.h>
#include <math.h>

typedef __bf16 bf16;
typedef __bf16 bf16x8 __attribute__((ext_vector_type(8)));
typedef __bf16 bf16x4 __attribute__((ext_vector_type(4)));
typedef float f32x2 __attribute__((ext_vector_type(2)));
typedef float f32x4 __attribute__((ext_vector_type(4)));
typedef float f32x16 __attribute__((ext_vector_type(16)));
typedef unsigned int uint;
typedef uint u32x4 __attribute__((ext_vector_type(4)));
typedef uint u32x2 __attribute__((ext_vector_type(2)));
typedef __bf16 bf16x8_a __attribute__((ext_vector_type(8), __may_alias__));
typedef uint u32x2_a __attribute__((ext_vector_type(2), __may_alias__));
typedef __bf16 bf16x4_a __attribute__((ext_vector_type(4), __may_alias__));
typedef __bf16 bf16_a __attribute__((__may_alias__));

constexpr int BATCH = 2;
constexpr int SEQ   = 2048;
constexpr int HID   = 2048;
constexpr int NHEAD = 16;
constexpr int NKV   = 8;
constexpr int HD    = 128;
constexpr int MROWS = BATCH * SEQ; // 4096

#define DEVINL __device__ __forceinline__

// raw barrier with compiler reorder fence (no implicit vmcnt/lgkm drain)
#define BAR()                                 \
  do {                                        \
    asm volatile("" ::: "memory");            \
    __builtin_amdgcn_s_barrier();             \
    asm volatile("" ::: "memory");            \
  } while (0)

#define WAITV(N) asm volatile("s_waitcnt vmcnt(" #N ")" ::: "memory")

DEVINL void async16(void* l, const void* g) {
  __builtin_amdgcn_global_load_lds((const __attribute__((address_space(1))) void*)g,
                                   (__attribute__((address_space(3))) void*)l, 16, 0, 0);
}

DEVINL f32x4 mfma16(bf16x8 a, bf16x8 b, f32x4 c) {
  return __builtin_amdgcn_mfma_f32_16x16x32_bf16(a, b, c, 0, 0, 0);
}
DEVINL f32x16 mfma32(bf16x8 a, bf16x8 b, f32x16 c) {
  return __builtin_amdgcn_mfma_f32_32x32x16_bf16(a, b, c, 0, 0, 0);
}

DEVINL f32x4 fzero4() { f32x4 z; z[0] = 0.f; z[1] = 0.f; z[2] = 0.f; z[3] = 0.f; return z; }

DEVINL float ex2(float x) {
#if __has_builtin(__builtin_amdgcn_exp2f)
  return __builtin_amdgcn_exp2f(x);
#else
  return __expf(x * 0.6931471805599453f);
#endif
}

DEVINL uint pkbf16(float lo, float hi) {
  unsigned short l = __builtin_bit_cast(unsigned short, (bf16)lo);
  unsigned short h = __builtin_bit_cast(unsigned short, (bf16)hi);
  return (uint)l | ((uint)h << 16);
}

// ---------------- fused prep: W transposes (z=0..3), rope tables (z=4), X cast (z=5) ----
__global__ __launch_bounds__(256) void prep(const float* __restrict__ X,
                                            const float* __restrict__ Wq,
                                            const float* __restrict__ Wk,
                                            const float* __restrict__ Wv,
                                            const float* __restrict__ Wo,
                                            bf16* __restrict__ Xb,
                                            bf16* __restrict__ WqT, bf16* __restrict__ WkT,
                                            bf16* __restrict__ WvT, bf16* __restrict__ WoT,
                                            float* __restrict__ ct, float* __restrict__ st) {
  const int tid = threadIdx.x;
  const int z = blockIdx.z;
  if (z == 4) {
    // rope tables: 2048 x 64
    int idx = (blockIdx.y * 32 + blockIdx.x) * 256 + tid;
    if (idx < SEQ * 64) {
      int s = idx >> 6, d = idx & 63;
      float freq = powf(10000.0f, -(float)d * (1.0f / 64.0f));
      float a = (float)s * freq;
      ct[idx] = cosf(a);
      st[idx] = sinf(a);
    }
    return;
  }
  if (z == 5) {
    // cast X f32 -> bf16 (8M elems), grid-stride float4
    int j = (blockIdx.y * 32 + blockIdx.x) * 256 + tid;
#pragma unroll
    for (int it = 0; it < 8; it++) {
      int e = (it * 262144 + j) * 4;
      float4 v = *(const float4*)(X + e);
      bf16x4 o;
      o[0] = (bf16)v.x; o[1] = (bf16)v.y; o[2] = (bf16)v.z; o[3] = (bf16)v.w;
      *(bf16x4*)(Xb + e) = o;
    }
    return;
  }
  // W transpose f32[K=2048][N] -> bf16 WT[N][2048]
  __shared__ bf16 t[64][65];
  const float* W; bf16* WT; int N;
  switch (z) {
    case 0: W = Wq; WT = WqT; N = 2048; break;
    case 1: W = Wk; WT = WkT; N = 1024; break;
    case 2: W = Wv; WT = WvT; N = 1024; break;
    default: W = Wo; WT = WoT; N = 2048; break;
  }
  int n0 = blockIdx.x * 64, k0 = blockIdx.y * 64;
  if (n0 >= N) return;
#pragma unroll
  for (int p = 0; p < 4; p++) {
    int r = (tid >> 4) + p * 16;
    int c4 = (tid & 15) * 4;
    float4 v = *(const float4*)(&W[(size_t)(k0 + r) * N + n0 + c4]);
    t[r][c4 + 0] = (bf16)v.x;
    t[r][c4 + 1] = (bf16)v.y;
    t[r][c4 + 2] = (bf16)v.z;
    t[r][c4 + 3] = (bf16)v.w;
  }
  __syncthreads();
#pragma unroll
  for (int p = 0; p < 4; p++) {
    int nr = (tid >> 4) + p * 16;
    int kb = (tid & 15) * 4;
    bf16x4 o;
    o[0] = t[kb + 0][nr];
    o[1] = t[kb + 1][nr];
    o[2] = t[kb + 2][nr];
    o[3] = t[kb + 3][nr];
    *(bf16x4_a*)(&WT[(size_t)(n0 + nr) * 2048 + k0 + kb]) = o;
  }
}

// ---------------- V[b*S+s][kvh*128+d] -> VT[(b*8+kvh)*128+d][s] ----------------
__global__ __launch_bounds__(256) void vtrans(const bf16* __restrict__ V, bf16* __restrict__ VT) {
  __shared__ bf16 t[64][65];
  int s0 = blockIdx.x * 64, d0 = blockIdx.y * 64;
  int bh = blockIdx.z, b = bh >> 3, kvh = bh & 7;
  for (int i = threadIdx.x; i < 4096; i += 256) {
    int r = i >> 6, c = i & 63;
    t[r][c] = V[(size_t)(b * SEQ + s0 + r) * (NKV * HD) + kvh * HD + d0 + c];
  }
  __syncthreads();
  for (int i = threadIdx.x; i < 4096; i += 256) {
    int r = i >> 6, c = i & 63;
    VT[((size_t)bh * HD + d0 + r) * SEQ + s0 + c] = t[c][r];
  }
}

// ================= 256x256 8-phase GEMM (m201-style, unchanged from R11) =================
template <int EPI>
__global__ __launch_bounds__(512, 2) void gemm8p(const bf16* __restrict__ A,
                                                 const bf16* __restrict__ BT,
                                                 void* __restrict__ C0, void* __restrict__ C1,
                                                 void* __restrict__ C2, int M, int N, int K,
                                                 const float* __restrict__ ct,
                                                 const float* __restrict__ st) {
  __shared__ alignas(16) char ldsA[65536];  // [buf][half][128r][64k]
  __shared__ alignas(16) char ldsB[65536];
  const int tid = threadIdx.x, lane = tid & 63, w = tid >> 6;
  const int l15 = lane & 15, l4 = lane >> 4;
  const int wm = w >> 2, wn = w & 3;
  const int gx = gridDim.x;
  const int nwg = gx * gridDim.y;
  int id = blockIdx.y * gx + blockIdx.x;
  id = (id & 7) * (nwg >> 3) + (id >> 3);
  const int row0 = (id / gx) * 256;
  const int col0 = (id % gx) * 256;

  f32x4 acc[8][4];
#pragma unroll
  for (int mt = 0; mt < 8; mt++)
#pragma unroll
    for (int nt = 0; nt < 4; nt++) acc[mt][nt] = fzero4();

  const int rG0 = tid >> 3, sG0 = ((tid & 7) ^ (rG0 & 7)) * 8;
  const int ci1 = 512 + tid;
  const int rG1 = ci1 >> 3, sG1 = ((ci1 & 7) ^ (rG1 & 7)) * 8;
  const int dst0 = tid * 16, dst1 = (512 + tid) * 16;

  const bf16* Asrc = A + (size_t)row0 * K;
  const bf16* Bsrc = BT + (size_t)col0 * K;
  const int nk = K >> 6;

#define STG_A(half, kt, buf)                                         \
  {                                                                  \
    char* d = ldsA + (buf) * 32768 + (half) * 16384;                 \
    const bf16* s = Asrc + (size_t)((half) * 128) * K + (kt) * 64;   \
    async16(d + dst0, s + (size_t)rG0 * K + sG0);                    \
    async16(d + dst1, s + (size_t)rG1 * K + sG1);                    \
  }
#define STG_B(half, kt, buf)                                         \
  {                                                                  \
    char* d = ldsB + (buf) * 32768 + (half) * 16384;                 \
    const bf16* s = Bsrc + (size_t)((half) * 128) * K + (kt) * 64;   \
    async16(d + dst0, s + (size_t)rG0 * K + sG0);                    \
    async16(d + dst1, s + (size_t)rG1 * K + sG1);                    \
  }

  // prologue: tiles 0 and 1 fully staged (16 loads)
  STG_A(0, 0, 0) STG_A(1, 0, 0) STG_B(0, 0, 0) STG_B(1, 0, 0)
  STG_B(0, 1, 1) STG_B(1, 1, 1) STG_A(0, 1, 1) STG_A(1, 1, 1)
  WAITV(8);
  BAR();

  bf16x8 af[8];
  bf16x8 bfr[2][4];

  for (int t = 0; t < nk; ++t) {
    const int buf = t & 1;
    const char* bA = ldsA + buf * 32768 + wm * 16384;
    const char* bB = ldsB + buf * 32768;
    const bool s2 = (t + 2) < nk;

    // ---- p0: read A-lo + B-half0; MFMA Q00 ----
#pragma unroll
    for (int mtp = 0; mtp < 4; mtp++)
#pragma unroll
      for (int kc = 0; kc < 2; kc++) {
        int r = mtp * 16 + l15;
        int off = ((r << 7) + ((kc * 4 + l4) << 4)) ^ ((r & 7) << 4);
        af[mtp * 2 + kc] = *(const bf16x8_a*)(bA + off);
      }
#pragma unroll
    for (int ntp = 0; ntp < 2; ntp++)
#pragma unroll
      for (int kc = 0; kc < 2; kc++) {
        int c = wn * 16 + ntp * 64 + l15;
        int off = ((c << 7) + ((kc * 4 + l4) << 4)) ^ ((c & 7) << 4);
        bfr[0][ntp * 2 + kc] = *(const bf16x8_a*)(bB + off);
      }
    BAR();
    __builtin_amdgcn_s_setprio(1);
#pragma unroll
    for (int mtp = 0; mtp < 4; mtp++)
#pragma unroll
      for (int ntp = 0; ntp < 2; ntp++)
#pragma unroll
        for (int kc = 0; kc < 2; kc++)
          acc[mtp][ntp] = mfma16(af[mtp * 2 + kc], bfr[0][ntp * 2 + kc], acc[mtp][ntp]);
    __builtin_amdgcn_s_setprio(0);
    BAR();

    // ---- p1: read B-half1; stage B0(t+2); MFMA Q01 ----
#pragma unroll
    for (int ntp = 0; ntp < 2; ntp++)
#pragma unroll
      for (int kc = 0; kc < 2; kc++) {
        int c = wn * 16 + ntp * 64 + l15;
        int off = 16384 + (((c << 7) + ((kc * 4 + l4) << 4)) ^ ((c & 7) << 4));
        bfr[1][ntp * 2 + kc] = *(const bf16x8_a*)(bB + off);
      }
    if (s2) STG_B(0, t + 2, buf)
    BAR();
    __builtin_amdgcn_s_setprio(1);
#pragma unroll
    for (int mtp = 0; mtp < 4; mtp++)
#pragma unroll
      for (int ntp = 0; ntp < 2; ntp++)
#pragma unroll
        for (int kc = 0; kc < 2; kc++)
          acc[mtp][ntp + 2] = mfma16(af[mtp * 2 + kc], bfr[1][ntp * 2 + kc], acc[mtp][ntp + 2]);
    __builtin_amdgcn_s_setprio(0);
    BAR();

    // ---- p2: read A-hi; stage B1(t+2); MFMA Q11 ----
#pragma unroll
    for (int mtp = 0; mtp < 4; mtp++)
#pragma unroll
      for (int kc = 0; kc < 2; kc++) {
        int r = 64 + mtp * 16 + l15;
        int off = ((r << 7) + ((kc * 4 + l4) << 4)) ^ ((r & 7) << 4);
        af[mtp * 2 + kc] = *(const bf16x8_a*)(bA + off);
      }
    if (s2) STG_B(1, t + 2, buf)
    BAR();
    __builtin_amdgcn_s_setprio(1);
#pragma unroll
    for (int mtp = 0; mtp < 4; mtp++)
#pragma unroll
      for (int ntp = 0; ntp < 2; ntp++)
#pragma unroll
        for (int kc = 0; kc < 2; kc++)
          acc[mtp + 4][ntp + 2] = mfma16(af[mtp * 2 + kc], bfr[1][ntp * 2 + kc], acc[mtp + 4][ntp + 2]);
    __builtin_amdgcn_s_setprio(0);
    BAR();

    // ---- p3: stage A0,A1(t+2); MFMA Q10; vmcnt; BAR ----
    if (s2) { STG_A(0, t + 2, buf) STG_A(1, t + 2, buf) }
    BAR();
    __builtin_amdgcn_s_setprio(1);
#pragma unroll
    for (int mtp = 0; mtp < 4; mtp++)
#pragma unroll
      for (int ntp = 0; ntp < 2; ntp++)
#pragma unroll
        for (int kc = 0; kc < 2; kc++)
          acc[mtp + 4][ntp] = mfma16(af[mtp * 2 + kc], bfr[0][ntp * 2 + kc], acc[mtp + 4][ntp]);
    __builtin_amdgcn_s_setprio(0);
    if (s2) { WAITV(8); } else { WAITV(0); }
    BAR();
  }
#undef STG_A
#undef STG_B

  // ---- epilogue ----
#pragma unroll
  for (int mt = 0; mt < 8; mt++)
#pragma unroll
    for (int nt = 0; nt < 4; nt++)
#pragma unroll
      for (int rg = 0; rg < 4; rg++) {
        int row = row0 + wm * 128 + mt * 16 + l4 * 4 + rg;
        int cl = col0 + wn * 16 + nt * 64 + l15;
        float v = acc[mt][nt][rg];
        if (EPI == 2) {
          ((float*)C0)[(size_t)row * N + cl] = v;
        } else {
          if (cl < 3072) {
            int s = row & (SEQ - 1);
            float cc = ct[s * 64 + wn * 16 + l15];
            float ss = st[s * 64 + wn * 16 + l15];
            float pv = acc[mt][nt ^ 1][rg];
            v = (nt & 1) ? fmaf(v, cc, pv * ss) : fmaf(v, cc, -pv * ss);
          }
          if (cl < 2048) {
            v *= 1.7677669529663689e-3f;  // pre-scale Q by 1/(50*sqrt(128))
            ((bf16*)C0)[(size_t)row * 2048 + cl] = (bf16)v;
          } else if (cl < 3072) {
            ((bf16*)C1)[(size_t)row * 1024 + (cl - 2048)] = (bf16)v;
          } else {
            ((bf16*)C2)[(size_t)row * 1024 + (cl - 3072)] = (bf16)v;
          }
        }
      }
}

// ================= 256x128 2-phase GEMM (Wo) — B triple-buffered, pass-through waits =========
// 512 thr / 8 waves (4M x 2N); wave tile 64x64. A: 2 bufs (in-place t+2 staging);
// B: 3 bufs. Stage B(t+2)@p0, A(t+2)@p1; steady-state WAITV(6) is a pass-through
// (waits only for tile t+1's loads, issued a full tile earlier).
__global__ __launch_bounds__(512, 2) void gemm2p(const bf16* __restrict__ A,
                                                 const bf16* __restrict__ BT,
                                                 float* __restrict__ C, int M, int N, int K) {
  __shared__ alignas(16) char ldsA[65536];  // [buf:2][half:2][128r][64k]
  __shared__ alignas(16) char ldsB[49152];  // [buf:3][128c][64k]
  const int tid = threadIdx.x, lane = tid & 63, w = tid >> 6;
  const int l15 = lane & 15, l4 = lane >> 4;
  const int wm = w >> 1, wn = w & 1;
  const int gx = gridDim.x;
  const int nwg = gx * gridDim.y;
  int id = blockIdx.y * gx + blockIdx.x;
  id = (id & 7) * (nwg >> 3) + (id >> 3);
  const int row0 = (id / gx) * 256;
  const int col0 = (id % gx) * 128;

  f32x4 acc[4][4];
#pragma unroll
  for (int mt = 0; mt < 4; mt++)
#pragma unroll
    for (int nt = 0; nt < 4; nt++) acc[mt][nt] = fzero4();

  const int rG0 = tid >> 3, sG0 = ((tid & 7) ^ (rG0 & 7)) * 8;
  const int ci1 = 512 + tid;
  const int rG1 = ci1 >> 3, sG1 = ((ci1 & 7) ^ (rG1 & 7)) * 8;
  const int dst0 = tid * 16, dst1 = (512 + tid) * 16;

  const bf16* Asrc = A + (size_t)row0 * K;
  const bf16* Bsrc = BT + (size_t)col0 * K;
  const int nk = K >> 6;

#define STG_A2(half, kt, buf)                                        \
  {                                                                  \
    char* d = ldsA + (buf) * 32768 + (half) * 16384;                 \
    const bf16* s = Asrc + (size_t)((half) * 128) * K + (kt) * 64;   \
    async16(d + dst0, s + (size_t)rG0 * K + sG0);                    \
    async16(d + dst1, s + (size_t)rG1 * K + sG1);                    \
  }
#define STG_B2(kt, buf)                                              \
  {                                                                  \
    char* d = ldsB + (buf) * 16384;                                  \
    const bf16* s = Bsrc + (kt) * 64;                                \
    async16(d + dst0, s + (size_t)rG0 * K + sG0);                    \
    async16(d + dst1, s + (size_t)rG1 * K + sG1);                    \
  }

  // prologue: B(0),A(0) then B(1),A(1)  (12 loads; oldest 6 = tile 0)
  STG_B2(0, 0) STG_A2(0, 0, 0) STG_A2(1, 0, 0)
  STG_B2(1, 1) STG_A2(0, 1, 1) STG_A2(1, 1, 1)
  WAITV(6);  // tile 0 landed; tile 1's 6 loads pending
  BAR();

  bf16x8 af[8];
  bf16x8 bfr[8];

  for (int t = 0; t < nk; ++t) {
    const int abuf = t & 1;
    int bb = t % 3;
    const char* bA = ldsA + abuf * 32768 + (wm >> 1) * 16384;
    const char* bB = ldsB + bb * 16384;
    const bool s2 = (t + 2) < nk;
    int bb2 = bb + 2; if (bb2 >= 3) bb2 -= 3;  // (t+2)%3

    // ---- p0: read all A-frags + B nt0,1; stage B(t+2); MFMA ----
#pragma unroll
    for (int mt = 0; mt < 4; mt++)
#pragma unroll
      for (int kc = 0; kc < 2; kc++) {
        int r = (wm & 1) * 64 + mt * 16 + l15;
        int off = ((r << 7) + ((kc * 4 + l4) << 4)) ^ ((r & 7) << 4);
        af[mt * 2 + kc] = *(const bf16x8_a*)(bA + off);
      }
#pragma unroll
    for (int nt = 0; nt < 2; nt++)
#pragma unroll
      for (int kc = 0; kc < 2; kc++) {
        int c = wn * 16 + nt * 32 + l15;
        int off = ((c << 7) + ((kc * 4 + l4) << 4)) ^ ((c & 7) << 4);
        bfr[nt * 2 + kc] = *(const bf16x8_a*)(bB + off);
      }
    if (s2) STG_B2(t + 2, bb2)
    BAR();
    __builtin_amdgcn_s_setprio(1);
#pragma unroll
    for (int mt = 0; mt < 4; mt++)
#pragma unroll
      for (int nt = 0; nt < 2; nt++)
#pragma unroll
        for (int kc = 0; kc < 2; kc++)
          acc[mt][nt] = mfma16(af[mt * 2 + kc], bfr[nt * 2 + kc], acc[mt][nt]);
    __builtin_amdgcn_s_setprio(0);
    BAR();

    // ---- p1: read B nt2,3; stage A(t+2) (in-place, A reads done at p0); MFMA ----
#pragma unroll
    for (int nt = 0; nt < 2; nt++)
#pragma unroll
      for (int kc = 0; kc < 2; kc++) {
        int c = wn * 16 + (nt + 2) * 32 + l15;
        int off = ((c << 7) + ((kc * 4 + l4) << 4)) ^ ((c & 7) << 4);
        bfr[4 + nt * 2 + kc] = *(const bf16x8_a*)(bB + off);
      }
    if (s2) { STG_A2(0, t + 2, abuf) STG_A2(1, t + 2, abuf) }
    BAR();
    __builtin_amdgcn_s_setprio(1);
#pragma unroll
    for (int mt = 0; mt < 4; mt++)
#pragma unroll
      for (int nt = 0; nt < 2; nt++)
#pragma unroll
        for (int kc = 0; kc < 2; kc++)
          acc[mt][nt + 2] = mfma16(af[mt * 2 + kc], bfr[4 + nt * 2 + kc], acc[mt][nt + 2]);
    __builtin_amdgcn_s_setprio(0);
    if (s2) { WAITV(6); } else { WAITV(0); }
    BAR();
  }
#undef STG_A2
#undef STG_B2

#pragma unroll
  for (int mt = 0; mt < 4; mt++)
#pragma unroll
    for (int nt = 0; nt < 4; nt++)
#pragma unroll
      for (int rg = 0; rg < 4; rg++) {
        int row = row0 + wm * 64 + mt * 16 + l4 * 4 + rg;
        int cl = col0 + wn * 16 + nt * 32 + l15;
        C[(size_t)row * N + cl] = acc[mt][nt][rg];
      }
}

// ========== Flash attention v8 (R11 structure; z^5 poly term dropped) ==========
__global__ __launch_bounds__(512, 2) void attn8(const bf16* __restrict__ Q,
                                                const bf16* __restrict__ Kg,
                                                const bf16* __restrict__ VTg,
                                                bf16* __restrict__ O) {
  __shared__ alignas(16) char ldsK[49152];   // 3 x [64 kv][128 d], 16-slot swizzle
  __shared__ alignas(16) char ldsV[49152];   // 3 x [128 d][64 kv], 8-slot swizzle
  const int tid = threadIdx.x, lane = tid & 63, w = tid >> 6;
  const int l31 = lane & 31, hl = lane >> 5;

  const int nx = gridDim.x, ny = gridDim.y;
  const int nwg = nx * ny * gridDim.z;  // 256
  int id = (blockIdx.z * ny + blockIdx.y) * nx + blockIdx.x;
  id = (id & 7) * (nwg >> 3) + (id >> 3);
  const int qt = id % nx; id /= nx;
  const int h = id % ny; const int b = id / ny;
  const int kvh = h >> 1;
  const int qrow = b * SEQ + qt * 256 + w * 32 + l31;

  bf16x8 qf[8];
  const bf16* qp = Q + (size_t)qrow * (NHEAD * HD) + h * HD + hl * 8;
#pragma unroll
  for (int kc = 0; kc < 8; kc++) qf[kc] = *(const bf16x8_a*)(qp + kc * 16);

  f32x16 oT[4];
#pragma unroll
  for (int dt = 0; dt < 4; dt++)
#pragma unroll
    for (int r = 0; r < 16; r++) oT[dt][r] = 0.f;
  f32x2 ls2; ls2[0] = 0.f; ls2[1] = 0.f;

  const int rK = tid >> 4, sK = (tid & 15) ^ (rK & 15);  // 16-slot swizzle
  const int rV = tid >> 3, sV = (tid & 7) ^ (rV & 7);    // 8-slot swizzle
  const size_t koff0 = (size_t)(b * SEQ + rK) * (NKV * HD) + kvh * HD + sK * 8;
  const size_t voff0 = ((size_t)(b * NKV + kvh) * HD + rV) * SEQ + sV * 8;

  const float Ac = 72.13475204444817f;    // 50*log2(e)
  const float Bc = -24.044917348149389f;  // Ac * (-1/3)

  auto STAGE = [&](int buf, int t) {
    char* dK = ldsK + buf * 16384;
    char* dV = ldsV + buf * 16384;
    const bf16* ks = Kg + koff0 + (size_t)t * (64 * NKV * HD);
    const bf16* vs = VTg + voff0 + (size_t)t * 64;
    async16(dK + tid * 16, ks);
    async16(dK + (512 + tid) * 16, ks + (size_t)32 * (NKV * HD));
    async16(dV + tid * 16, vs);
    async16(dV + (512 + tid) * 16, vs + (size_t)64 * SEQ);
  };

  const int kvr0 = l31, kvr1 = 32 + l31;

#define QKT(SC, lKp)                                                     \
  do {                                                                   \
    _Pragma("unroll")                                                    \
    for (int r = 0; r < 16; r++) { (SC)[0][r] = 0.f; (SC)[1][r] = 0.f; } \
    _Pragma("unroll")                                                    \
    for (int kc = 0; kc < 8; kc++) {                                     \
      int slot = kc * 2 + hl;                                            \
      int off0 = (kvr0 << 8) | ((slot ^ (kvr0 & 15)) << 4);              \
      int off1 = (kvr1 << 8) | ((slot ^ (kvr1 & 15)) << 4);              \
      bf16x8 kf0 = *(const bf16x8_a*)((lKp) + off0);                     \
      bf16x8 kf1 = *(const bf16x8_a*)((lKp) + off1);                     \
      (SC)[0] = mfma32(kf0, qf[kc], (SC)[0]);                            \
      (SC)[1] = mfma32(kf1, qf[kc], (SC)[1]);                            \
    }                                                                    \
  } while (0)

#define SOFTMAX(SC, PB)                                                  \
  do {                                                                   \
    _Pragma("unroll")                                                    \
    for (int ntb = 0; ntb < 2; ntb++) {                                  \
      uint u[4][2], us[4][2];                                            \
      _Pragma("unroll")                                                  \
      for (int r2 = 0; r2 < 8; r2++) {                                   \
        f32x2 z; z[0] = (SC)[ntb][2 * r2]; z[1] = (SC)[ntb][2 * r2 + 1]; \
        f32x2 z2 = z * z;                                                \
        f32x2 wv = z2 * Bc + Ac;                                         \
        f32x2 e = z * wv;                                                \
        float p0 = ex2(e[0]), p1 = ex2(e[1]);                            \
        ls2[0] += p0; ls2[1] += p1;                                      \
        uint uu = pkbf16(p0, p1);                                        \
        u[r2 >> 1][r2 & 1] = uu;                                         \
        us[r2 >> 1][r2 & 1] = __shfl_xor(uu, 32);                        \
      }                                                                  \
      _Pragma("unroll")                                                  \
      for (int sub = 0; sub < 2; sub++) {                                \
        u32x4 bu;                                                        \
        bu[0] = hl ? us[2 * sub + 1][0] : u[2 * sub][0];                 \
        bu[1] = hl ? us[2 * sub + 1][1] : u[2 * sub][1];                 \
        bu[2] = hl ? u[2 * sub + 1][0] : us[2 * sub][0];                 \
        bu[3] = hl ? u[2 * sub + 1][1] : us[2 * sub][1];                 \
        (PB)[ntb * 2 + sub] = __builtin_bit_cast(bf16x8, bu);            \
      }                                                                  \
    }                                                                    \
  } while (0)

#define PVACC(PB, lVp)                                                   \
  do {                                                                   \
    _Pragma("unroll")                                                    \
    for (int kvb = 0; kvb < 4; kvb++) {                                  \
      int slot = kvb * 2 + hl;                                           \
      _Pragma("unroll")                                                  \
      for (int dt = 0; dt < 4; dt++) {                                   \
        int d = dt * 32 + l31;                                           \
        int off = (d << 7) | ((slot ^ (d & 7)) << 4);                    \
        bf16x8 vf = *(const bf16x8_a*)((lVp) + off);                     \
        oT[dt] = mfma32(vf, (PB)[kvb], oT[dt]);                          \
      }                                                                  \
    }                                                                    \
  } while (0)

  constexpr int NT = SEQ / 64;  // 32
  STAGE(0, 0);
  STAGE(1, 1);
  WAITV(4);  // tile 0 landed
  BAR();

  f32x16 scA[2], scB[2];
  bf16x8 pb[4];
  QKT(scA, ldsK);  // tile 0, buf 0

  for (int it = 0; it < NT / 2; ++it) {
    const int t0 = 2 * it;
    {
      const int t = t0;
      BAR();
      if (t + 2 < NT) STAGE((t + 2) % 3, t + 2);
      SOFTMAX(scA, pb);
      if (t + 1 < NT) {
        WAITV(4);
        __builtin_amdgcn_s_setprio(1);
        QKT(scB, ldsK + ((t + 1) % 3) * 16384);
        PVACC(pb, ldsV + (t % 3) * 16384);
        __builtin_amdgcn_s_setprio(0);
      } else {
        __builtin_amdgcn_s_setprio(1);
        PVACC(pb, ldsV + (t % 3) * 16384);
        __builtin_amdgcn_s_setprio(0);
      }
    }
    {
      const int t = t0 + 1;
      BAR();
      if (t + 2 < NT) STAGE((t + 2) % 3, t + 2);
      SOFTMAX(scB, pb);
      if (t + 1 < NT) {
        WAITV(4);
        __builtin_amdgcn_s_setprio(1);
        QKT(scA, ldsK + ((t + 1) % 3) * 16384);
        PVACC(pb, ldsV + (t % 3) * 16384);
        __builtin_amdgcn_s_setprio(0);
      } else {
        __builtin_amdgcn_s_setprio(1);
        PVACC(pb, ldsV + (t % 3) * 16384);
        __builtin_amdgcn_s_setprio(0);
      }
    }
  }
#undef QKT
#undef SOFTMAX
#undef PVACC

  float lsum = ls2[0] + ls2[1];
  float lsf = lsum + __shfl_xor(lsum, 32);
  float inv = 1.0f / lsf;
  bf16* ob = O + (size_t)qrow * (NHEAD * HD) + h * HD;
#pragma unroll
  for (int dt = 0; dt < 4; dt++)
#pragma unroll
    for (int g = 0; g < 4; g++) {
      u32x2 pr;
      pr[0] = pkbf16(oT[dt][4 * g] * inv, oT[dt][4 * g + 1] * inv);
      pr[1] = pkbf16(oT[dt][4 * g + 2] * inv, oT[dt][4 * g + 3] * inv);
      *(u32x2_a*)(ob + dt * 32 + 8 * g + 4 * hl) = pr;
    }
}

extern "C" void kernel_launch(void* const* d_in, const int* in_sizes, int n_in,
                              void* d_out, int out_size, void* d_ws, size_t ws_size,
                              hipStream_t stream) {
  const float* X  = (const float*)d_in[0];
  const float* Wq = (const float*)d_in[1];
  const float* Wk = (const float*)d_in[2];
  const float* Wv = (const float*)d_in[3];
  const float* Wo = (const float*)d_in[4];
  float* out = (float*)d_out;

  char* ws = (char*)d_ws;
  size_t off = 0;
  auto alloc = [&](size_t bytes) {
    void* p = ws + off;
    off += (bytes + 255) & ~(size_t)255;
    return p;
  };
  bf16* Xb  = (bf16*)alloc((size_t)MROWS * HID * 2);
  // WqT/WkT/WvT adjacent & contiguous -> fused BT [4096][2048]
  bf16* WqT = (bf16*)alloc((size_t)2048 * 2048 * 2);
  bf16* WkT = (bf16*)alloc((size_t)1024 * 2048 * 2);
  bf16* WvT = (bf16*)alloc((size_t)1024 * 2048 * 2);
  bf16* WoT = (bf16*)alloc((size_t)2048 * 2048 * 2);
  bf16* Qb  = (bf16*)alloc((size_t)MROWS * 2048 * 2);
  bf16* Kb  = (bf16*)alloc((size_t)MROWS * 1024 * 2);
  bf16* Vb  = (bf16*)alloc((size_t)MROWS * 1024 * 2);
  bf16* VTb = (bf16*)alloc((size_t)16 * 128 * 2048 * 2);
  bf16* AOb = (bf16*)alloc((size_t)MROWS * 2048 * 2);
  float* ct = (float*)alloc((size_t)SEQ * 64 * 4);
  float* st = (float*)alloc((size_t)SEQ * 64 * 4);

  prep<<<dim3(32, 32, 6), 256, 0, stream>>>(X, Wq, Wk, Wv, Wo, Xb, WqT, WkT, WvT, WoT, ct, st);
  gemm8p<1><<<dim3(16, 16), 512, 0, stream>>>(Xb, WqT, Qb, Kb, Vb, MROWS, 4096, 2048, ct, st);
  vtrans<<<dim3(32, 2, 16), 256, 0, stream>>>(Vb, VTb);
  attn8<<<dim3(8, 16, 2), 512, 0, stream>>>(Qb, Kb, VTb, AOb);
  gemm2p<<<dim3(16, 16), 512, 0, stream>>>(AOb, WoT, out, MROWS, 2048, 2048);

  (void)in_sizes; (void)n_in; (void)out_size; (void)ws_size;
}

// Round 14
// 235.417 us; speedup vs baseline: 1.3619x; 1.0273x over previous
//
#include <hip/hip_runtime.h>
#include <math.h>

typedef __bf16 bf16;
typedef __bf16 bf16x8 __attribute__((ext_vector_type(8)));
typedef __bf16 bf16x4 __attribute__((ext_vector_type(4)));
typedef float f32x2 __attribute__((ext_vector_type(2)));
typedef float f32x4 __attribute__((ext_vector_type(4)));
typedef float f32x16 __attribute__((ext_vector_type(16)));
typedef unsigned int uint;
typedef uint u32x4 __attribute__((ext_vector_type(4)));
typedef uint u32x2 __attribute__((ext_vector_type(2)));
typedef __bf16 bf16x8_a __attribute__((ext_vector_type(8), __may_alias__));
typedef uint u32x2_a __attribute__((ext_vector_type(2), __may_alias__));
typedef __bf16 bf16x4_a __attribute__((ext_vector_type(4), __may_alias__));
typedef __bf16 bf16_a __attribute__((__may_alias__));

constexpr int BATCH = 2;
constexpr int SEQ   = 2048;
constexpr int HID   = 2048;
constexpr int NHEAD = 16;
constexpr int NKV   = 8;
constexpr int HD    = 128;
constexpr int MROWS = BATCH * SEQ; // 4096

#define DEVINL __device__ __forceinline__

// raw barrier with compiler reorder fence (no implicit vmcnt/lgkm drain)
#define BAR()                                 \
  do {                                        \
    asm volatile("" ::: "memory");            \
    __builtin_amdgcn_s_barrier();             \
    asm volatile("" ::: "memory");            \
  } while (0)

#define WAITV(N) asm volatile("s_waitcnt vmcnt(" #N ")" ::: "memory")

DEVINL void async16(void* l, const void* g) {
  __builtin_amdgcn_global_load_lds((const __attribute__((address_space(1))) void*)g,
                                   (__attribute__((address_space(3))) void*)l, 16, 0, 0);
}

DEVINL f32x4 mfma16(bf16x8 a, bf16x8 b, f32x4 c) {
  return __builtin_amdgcn_mfma_f32_16x16x32_bf16(a, b, c, 0, 0, 0);
}
DEVINL f32x16 mfma32(bf16x8 a, bf16x8 b, f32x16 c) {
  return __builtin_amdgcn_mfma_f32_32x32x16_bf16(a, b, c, 0, 0, 0);
}

DEVINL f32x4 fzero4() { f32x4 z; z[0] = 0.f; z[1] = 0.f; z[2] = 0.f; z[3] = 0.f; return z; }

DEVINL float ex2(float x) {
#if __has_builtin(__builtin_amdgcn_exp2f)
  return __builtin_amdgcn_exp2f(x);
#else
  return __expf(x * 0.6931471805599453f);
#endif
}

DEVINL uint pkbf16(float lo, float hi) {
  unsigned short l = __builtin_bit_cast(unsigned short, (bf16)lo);
  unsigned short h = __builtin_bit_cast(unsigned short, (bf16)hi);
  return (uint)l | ((uint)h << 16);
}

// hardware half-wave swap: returns {.x = {a.lo, b.lo}, .y = {a.hi, b.hi}}
DEVINL u32x2 pswap(uint a, uint b) {
#if __has_builtin(__builtin_amdgcn_permlane32_swap)
  return __builtin_amdgcn_permlane32_swap(a, b, false, false);
#else
  int hl = (int)((threadIdx.x >> 5) & 1);
  uint as = __shfl_xor(a, 32), bs = __shfl_xor(b, 32);
  u32x2 r;
  r[0] = hl ? bs : a;  // {a.lo, b.lo}
  r[1] = hl ? b : as;  // {a.hi, b.hi}
  return r;
#endif
}

// ---------------- fused prep: W transposes (z=0..3), rope tables (z=4), X cast (z=5) ----
__global__ __launch_bounds__(256) void prep(const float* __restrict__ X,
                                            const float* __restrict__ Wq,
                                            const float* __restrict__ Wk,
                                            const float* __restrict__ Wv,
                                            const float* __restrict__ Wo,
                                            bf16* __restrict__ Xb,
                                            bf16* __restrict__ WqT, bf16* __restrict__ WkT,
                                            bf16* __restrict__ WvT, bf16* __restrict__ WoT,
                                            float* __restrict__ ct, float* __restrict__ st) {
  const int tid = threadIdx.x;
  const int z = blockIdx.z;
  if (z == 4) {
    int idx = (blockIdx.y * 32 + blockIdx.x) * 256 + tid;
    if (idx < SEQ * 64) {
      int s = idx >> 6, d = idx & 63;
      float freq = powf(10000.0f, -(float)d * (1.0f / 64.0f));
      float a = (float)s * freq;
      ct[idx] = cosf(a);
      st[idx] = sinf(a);
    }
    return;
  }
  if (z == 5) {
    int j = (blockIdx.y * 32 + blockIdx.x) * 256 + tid;
#pragma unroll
    for (int it = 0; it < 8; it++) {
      int e = (it * 262144 + j) * 4;
      float4 v = *(const float4*)(X + e);
      bf16x4 o;
      o[0] = (bf16)v.x; o[1] = (bf16)v.y; o[2] = (bf16)v.z; o[3] = (bf16)v.w;
      *(bf16x4*)(Xb + e) = o;
    }
    return;
  }
  __shared__ bf16 t[64][65];
  const float* W; bf16* WT; int N;
  switch (z) {
    case 0: W = Wq; WT = WqT; N = 2048; break;
    case 1: W = Wk; WT = WkT; N = 1024; break;
    case 2: W = Wv; WT = WvT; N = 1024; break;
    default: W = Wo; WT = WoT; N = 2048; break;
  }
  int n0 = blockIdx.x * 64, k0 = blockIdx.y * 64;
  if (n0 >= N) return;
#pragma unroll
  for (int p = 0; p < 4; p++) {
    int r = (tid >> 4) + p * 16;
    int c4 = (tid & 15) * 4;
    float4 v = *(const float4*)(&W[(size_t)(k0 + r) * N + n0 + c4]);
    t[r][c4 + 0] = (bf16)v.x;
    t[r][c4 + 1] = (bf16)v.y;
    t[r][c4 + 2] = (bf16)v.z;
    t[r][c4 + 3] = (bf16)v.w;
  }
  __syncthreads();
#pragma unroll
  for (int p = 0; p < 4; p++) {
    int nr = (tid >> 4) + p * 16;
    int kb = (tid & 15) * 4;
    bf16x4 o;
    o[0] = t[kb + 0][nr];
    o[1] = t[kb + 1][nr];
    o[2] = t[kb + 2][nr];
    o[3] = t[kb + 3][nr];
    *(bf16x4_a*)(&WT[(size_t)(n0 + nr) * 2048 + k0 + kb]) = o;
  }
}

// ---------------- V[b*S+s][kvh*128+d] -> VT[(b*8+kvh)*128+d][s] ----------------
__global__ __launch_bounds__(256) void vtrans(const bf16* __restrict__ V, bf16* __restrict__ VT) {
  __shared__ bf16 t[64][65];
  int s0 = blockIdx.x * 64, d0 = blockIdx.y * 64;
  int bh = blockIdx.z, b = bh >> 3, kvh = bh & 7;
  for (int i = threadIdx.x; i < 4096; i += 256) {
    int r = i >> 6, c = i & 63;
    t[r][c] = V[(size_t)(b * SEQ + s0 + r) * (NKV * HD) + kvh * HD + d0 + c];
  }
  __syncthreads();
  for (int i = threadIdx.x; i < 4096; i += 256) {
    int r = i >> 6, c = i & 63;
    VT[((size_t)bh * HD + d0 + r) * SEQ + s0 + c] = t[c][r];
  }
}

// ================= 256x256 8-phase GEMM (m201-style, unchanged) =================
template <int EPI>
__global__ __launch_bounds__(512, 2) void gemm8p(const bf16* __restrict__ A,
                                                 const bf16* __restrict__ BT,
                                                 void* __restrict__ C0, void* __restrict__ C1,
                                                 void* __restrict__ C2, int M, int N, int K,
                                                 const float* __restrict__ ct,
                                                 const float* __restrict__ st) {
  __shared__ alignas(16) char ldsA[65536];  // [buf][half][128r][64k]
  __shared__ alignas(16) char ldsB[65536];
  const int tid = threadIdx.x, lane = tid & 63, w = tid >> 6;
  const int l15 = lane & 15, l4 = lane >> 4;
  const int wm = w >> 2, wn = w & 3;
  const int gx = gridDim.x;
  const int nwg = gx * gridDim.y;
  int id = blockIdx.y * gx + blockIdx.x;
  id = (id & 7) * (nwg >> 3) + (id >> 3);
  const int row0 = (id / gx) * 256;
  const int col0 = (id % gx) * 256;

  f32x4 acc[8][4];
#pragma unroll
  for (int mt = 0; mt < 8; mt++)
#pragma unroll
    for (int nt = 0; nt < 4; nt++) acc[mt][nt] = fzero4();

  const int rG0 = tid >> 3, sG0 = ((tid & 7) ^ (rG0 & 7)) * 8;
  const int ci1 = 512 + tid;
  const int rG1 = ci1 >> 3, sG1 = ((ci1 & 7) ^ (rG1 & 7)) * 8;
  const int dst0 = tid * 16, dst1 = (512 + tid) * 16;

  const bf16* Asrc = A + (size_t)row0 * K;
  const bf16* Bsrc = BT + (size_t)col0 * K;
  const int nk = K >> 6;

#define STG_A(half, kt, buf)                                         \
  {                                                                  \
    char* d = ldsA + (buf) * 32768 + (half) * 16384;                 \
    const bf16* s = Asrc + (size_t)((half) * 128) * K + (kt) * 64;   \
    async16(d + dst0, s + (size_t)rG0 * K + sG0);                    \
    async16(d + dst1, s + (size_t)rG1 * K + sG1);                    \
  }
#define STG_B(half, kt, buf)                                         \
  {                                                                  \
    char* d = ldsB + (buf) * 32768 + (half) * 16384;                 \
    const bf16* s = Bsrc + (size_t)((half) * 128) * K + (kt) * 64;   \
    async16(d + dst0, s + (size_t)rG0 * K + sG0);                    \
    async16(d + dst1, s + (size_t)rG1 * K + sG1);                    \
  }

  STG_A(0, 0, 0) STG_A(1, 0, 0) STG_B(0, 0, 0) STG_B(1, 0, 0)
  STG_B(0, 1, 1) STG_B(1, 1, 1) STG_A(0, 1, 1) STG_A(1, 1, 1)
  WAITV(8);
  BAR();

  bf16x8 af[8];
  bf16x8 bfr[2][4];

  for (int t = 0; t < nk; ++t) {
    const int buf = t & 1;
    const char* bA = ldsA + buf * 32768 + wm * 16384;
    const char* bB = ldsB + buf * 32768;
    const bool s2 = (t + 2) < nk;

    // ---- p0: read A-lo + B-half0; MFMA Q00 ----
#pragma unroll
    for (int mtp = 0; mtp < 4; mtp++)
#pragma unroll
      for (int kc = 0; kc < 2; kc++) {
        int r = mtp * 16 + l15;
        int off = ((r << 7) + ((kc * 4 + l4) << 4)) ^ ((r & 7) << 4);
        af[mtp * 2 + kc] = *(const bf16x8_a*)(bA + off);
      }
#pragma unroll
    for (int ntp = 0; ntp < 2; ntp++)
#pragma unroll
      for (int kc = 0; kc < 2; kc++) {
        int c = wn * 16 + ntp * 64 + l15;
        int off = ((c << 7) + ((kc * 4 + l4) << 4)) ^ ((c & 7) << 4);
        bfr[0][ntp * 2 + kc] = *(const bf16x8_a*)(bB + off);
      }
    BAR();
    __builtin_amdgcn_s_setprio(1);
#pragma unroll
    for (int mtp = 0; mtp < 4; mtp++)
#pragma unroll
      for (int ntp = 0; ntp < 2; ntp++)
#pragma unroll
        for (int kc = 0; kc < 2; kc++)
          acc[mtp][ntp] = mfma16(af[mtp * 2 + kc], bfr[0][ntp * 2 + kc], acc[mtp][ntp]);
    __builtin_amdgcn_s_setprio(0);
    BAR();

    // ---- p1: read B-half1; stage B0(t+2); MFMA Q01 ----
#pragma unroll
    for (int ntp = 0; ntp < 2; ntp++)
#pragma unroll
      for (int kc = 0; kc < 2; kc++) {
        int c = wn * 16 + ntp * 64 + l15;
        int off = 16384 + (((c << 7) + ((kc * 4 + l4) << 4)) ^ ((c & 7) << 4));
        bfr[1][ntp * 2 + kc] = *(const bf16x8_a*)(bB + off);
      }
    if (s2) STG_B(0, t + 2, buf)
    BAR();
    __builtin_amdgcn_s_setprio(1);
#pragma unroll
    for (int mtp = 0; mtp < 4; mtp++)
#pragma unroll
      for (int ntp = 0; ntp < 2; ntp++)
#pragma unroll
        for (int kc = 0; kc < 2; kc++)
          acc[mtp][ntp + 2] = mfma16(af[mtp * 2 + kc], bfr[1][ntp * 2 + kc], acc[mtp][ntp + 2]);
    __builtin_amdgcn_s_setprio(0);
    BAR();

    // ---- p2: read A-hi; stage B1(t+2); MFMA Q11 ----
#pragma unroll
    for (int mtp = 0; mtp < 4; mtp++)
#pragma unroll
      for (int kc = 0; kc < 2; kc++) {
        int r = 64 + mtp * 16 + l15;
        int off = ((r << 7) + ((kc * 4 + l4) << 4)) ^ ((r & 7) << 4);
        af[mtp * 2 + kc] = *(const bf16x8_a*)(bA + off);
      }
    if (s2) STG_B(1, t + 2, buf)
    BAR();
    __builtin_amdgcn_s_setprio(1);
#pragma unroll
    for (int mtp = 0; mtp < 4; mtp++)
#pragma unroll
      for (int ntp = 0; ntp < 2; ntp++)
#pragma unroll
        for (int kc = 0; kc < 2; kc++)
          acc[mtp + 4][ntp + 2] = mfma16(af[mtp * 2 + kc], bfr[1][ntp * 2 + kc], acc[mtp + 4][ntp + 2]);
    __builtin_amdgcn_s_setprio(0);
    BAR();

    // ---- p3: stage A0,A1(t+2); MFMA Q10; vmcnt; BAR ----
    if (s2) { STG_A(0, t + 2, buf) STG_A(1, t + 2, buf) }
    BAR();
    __builtin_amdgcn_s_setprio(1);
#pragma unroll
    for (int mtp = 0; mtp < 4; mtp++)
#pragma unroll
      for (int ntp = 0; ntp < 2; ntp++)
#pragma unroll
        for (int kc = 0; kc < 2; kc++)
          acc[mtp + 4][ntp] = mfma16(af[mtp * 2 + kc], bfr[0][ntp * 2 + kc], acc[mtp + 4][ntp]);
    __builtin_amdgcn_s_setprio(0);
    if (s2) { WAITV(8); } else { WAITV(0); }
    BAR();
  }
#undef STG_A
#undef STG_B

  // ---- epilogue ----
#pragma unroll
  for (int mt = 0; mt < 8; mt++)
#pragma unroll
    for (int nt = 0; nt < 4; nt++)
#pragma unroll
      for (int rg = 0; rg < 4; rg++) {
        int row = row0 + wm * 128 + mt * 16 + l4 * 4 + rg;
        int cl = col0 + wn * 16 + nt * 64 + l15;
        float v = acc[mt][nt][rg];
        if (EPI == 2) {
          ((float*)C0)[(size_t)row * N + cl] = v;
        } else {
          if (cl < 3072) {
            int s = row & (SEQ - 1);
            float cc = ct[s * 64 + wn * 16 + l15];
            float ss = st[s * 64 + wn * 16 + l15];
            float pv = acc[mt][nt ^ 1][rg];
            v = (nt & 1) ? fmaf(v, cc, pv * ss) : fmaf(v, cc, -pv * ss);
          }
          if (cl < 2048) {
            v *= 1.7677669529663689e-3f;  // pre-scale Q by 1/(50*sqrt(128))
            ((bf16*)C0)[(size_t)row * 2048 + cl] = (bf16)v;
          } else if (cl < 3072) {
            ((bf16*)C1)[(size_t)row * 1024 + (cl - 2048)] = (bf16)v;
          } else {
            ((bf16*)C2)[(size_t)row * 1024 + (cl - 3072)] = (bf16)v;
          }
        }
      }
}

// ================= 256x128 2-phase GEMM (Wo) — B triple-buffered (unchanged) =================
__global__ __launch_bounds__(512, 2) void gemm2p(const bf16* __restrict__ A,
                                                 const bf16* __restrict__ BT,
                                                 float* __restrict__ C, int M, int N, int K) {
  __shared__ alignas(16) char ldsA[65536];  // [buf:2][half:2][128r][64k]
  __shared__ alignas(16) char ldsB[49152];  // [buf:3][128c][64k]
  const int tid = threadIdx.x, lane = tid & 63, w = tid >> 6;
  const int l15 = lane & 15, l4 = lane >> 4;
  const int wm = w >> 1, wn = w & 1;
  const int gx = gridDim.x;
  const int nwg = gx * gridDim.y;
  int id = blockIdx.y * gx + blockIdx.x;
  id = (id & 7) * (nwg >> 3) + (id >> 3);
  const int row0 = (id / gx) * 256;
  const int col0 = (id % gx) * 128;

  f32x4 acc[4][4];
#pragma unroll
  for (int mt = 0; mt < 4; mt++)
#pragma unroll
    for (int nt = 0; nt < 4; nt++) acc[mt][nt] = fzero4();

  const int rG0 = tid >> 3, sG0 = ((tid & 7) ^ (rG0 & 7)) * 8;
  const int ci1 = 512 + tid;
  const int rG1 = ci1 >> 3, sG1 = ((ci1 & 7) ^ (rG1 & 7)) * 8;
  const int dst0 = tid * 16, dst1 = (512 + tid) * 16;

  const bf16* Asrc = A + (size_t)row0 * K;
  const bf16* Bsrc = BT + (size_t)col0 * K;
  const int nk = K >> 6;

#define STG_A2(half, kt, buf)                                        \
  {                                                                  \
    char* d = ldsA + (buf) * 32768 + (half) * 16384;                 \
    const bf16* s = Asrc + (size_t)((half) * 128) * K + (kt) * 64;   \
    async16(d + dst0, s + (size_t)rG0 * K + sG0);                    \
    async16(d + dst1, s + (size_t)rG1 * K + sG1);                    \
  }
#define STG_B2(kt, buf)                                              \
  {                                                                  \
    char* d = ldsB + (buf) * 16384;                                  \
    const bf16* s = Bsrc + (kt) * 64;                                \
    async16(d + dst0, s + (size_t)rG0 * K + sG0);                    \
    async16(d + dst1, s + (size_t)rG1 * K + sG1);                    \
  }

  STG_B2(0, 0) STG_A2(0, 0, 0) STG_A2(1, 0, 0)
  STG_B2(1, 1) STG_A2(0, 1, 1) STG_A2(1, 1, 1)
  WAITV(6);
  BAR();

  bf16x8 af[8];
  bf16x8 bfr[8];

  for (int t = 0; t < nk; ++t) {
    const int abuf = t & 1;
    int bb = t % 3;
    const char* bA = ldsA + abuf * 32768 + (wm >> 1) * 16384;
    const char* bB = ldsB + bb * 16384;
    const bool s2 = (t + 2) < nk;
    int bb2 = bb + 2; if (bb2 >= 3) bb2 -= 3;

    // ---- p0 ----
#pragma unroll
    for (int mt = 0; mt < 4; mt++)
#pragma unroll
      for (int kc = 0; kc < 2; kc++) {
        int r = (wm & 1) * 64 + mt * 16 + l15;
        int off = ((r << 7) + ((kc * 4 + l4) << 4)) ^ ((r & 7) << 4);
        af[mt * 2 + kc] = *(const bf16x8_a*)(bA + off);
      }
#pragma unroll
    for (int nt = 0; nt < 2; nt++)
#pragma unroll
      for (int kc = 0; kc < 2; kc++) {
        int c = wn * 16 + nt * 32 + l15;
        int off = ((c << 7) + ((kc * 4 + l4) << 4)) ^ ((c & 7) << 4);
        bfr[nt * 2 + kc] = *(const bf16x8_a*)(bB + off);
      }
    if (s2) STG_B2(t + 2, bb2)
    BAR();
    __builtin_amdgcn_s_setprio(1);
#pragma unroll
    for (int mt = 0; mt < 4; mt++)
#pragma unroll
      for (int nt = 0; nt < 2; nt++)
#pragma unroll
        for (int kc = 0; kc < 2; kc++)
          acc[mt][nt] = mfma16(af[mt * 2 + kc], bfr[nt * 2 + kc], acc[mt][nt]);
    __builtin_amdgcn_s_setprio(0);
    BAR();

    // ---- p1 ----
#pragma unroll
    for (int nt = 0; nt < 2; nt++)
#pragma unroll
      for (int kc = 0; kc < 2; kc++) {
        int c = wn * 16 + (nt + 2) * 32 + l15;
        int off = ((c << 7) + ((kc * 4 + l4) << 4)) ^ ((c & 7) << 4);
        bfr[4 + nt * 2 + kc] = *(const bf16x8_a*)(bB + off);
      }
    if (s2) { STG_A2(0, t + 2, abuf) STG_A2(1, t + 2, abuf) }
    BAR();
    __builtin_amdgcn_s_setprio(1);
#pragma unroll
    for (int mt = 0; mt < 4; mt++)
#pragma unroll
      for (int nt = 0; nt < 2; nt++)
#pragma unroll
        for (int kc = 0; kc < 2; kc++)
          acc[mt][nt + 2] = mfma16(af[mt * 2 + kc], bfr[4 + nt * 2 + kc], acc[mt][nt + 2]);
    __builtin_amdgcn_s_setprio(0);
    if (s2) { WAITV(6); } else { WAITV(0); }
    BAR();
  }
#undef STG_A2
#undef STG_B2

#pragma unroll
  for (int mt = 0; mt < 4; mt++)
#pragma unroll
    for (int nt = 0; nt < 4; nt++)
#pragma unroll
      for (int rg = 0; rg < 4; rg++) {
        int row = row0 + wm * 64 + mt * 16 + l4 * 4 + rg;
        int cl = col0 + wn * 16 + nt * 32 + l15;
        C[(size_t)row * N + cl] = acc[mt][nt][rg];
      }
}

// ========== Flash attention v10: race-free pipeline (WAITV -> BAR -> read) ==========
// Per iter t: {BAR; STAGE(t+2); SOFTMAX(t); WAITV(4|0); BAR; QKT(t+1)+PVACC(t)}.
// Invariant: tile X is read only after every wave's WAITV that drains X's loads
// plus a barrier (cross-wave LDS visibility). Overwrite of buf (t-1)%3 by
// STAGE(t+2) is after the top BAR (all waves' tile-(t-1) reads consumed).
__global__ __launch_bounds__(512, 2) void attn10(const bf16* __restrict__ Q,
                                                 const bf16* __restrict__ Kg,
                                                 const bf16* __restrict__ VTg,
                                                 bf16* __restrict__ O) {
  __shared__ alignas(16) char ldsK[49152];   // 3 x [64 kv][128 d], 16-slot swizzle
  __shared__ alignas(16) char ldsV[49152];   // 3 x [128 d][64 kv], 8-slot swizzle
  const int tid = threadIdx.x, lane = tid & 63, w = tid >> 6;
  const int l31 = lane & 31, hl = lane >> 5;

  const int nx = gridDim.x, ny = gridDim.y;
  const int nwg = nx * ny * gridDim.z;  // 256
  int id = (blockIdx.z * ny + blockIdx.y) * nx + blockIdx.x;
  id = (id & 7) * (nwg >> 3) + (id >> 3);
  const int qt = id % nx; id /= nx;
  const int h = id % ny; const int b = id / ny;
  const int kvh = h >> 1;
  const int qrow = b * SEQ + qt * 256 + w * 32 + l31;

  bf16x8 qf[8];
  const bf16* qp = Q + (size_t)qrow * (NHEAD * HD) + h * HD + hl * 8;
#pragma unroll
  for (int kc = 0; kc < 8; kc++) qf[kc] = *(const bf16x8_a*)(qp + kc * 16);

  f32x16 oT[4];
#pragma unroll
  for (int dt = 0; dt < 4; dt++)
#pragma unroll
    for (int r = 0; r < 16; r++) oT[dt][r] = 0.f;
  f32x2 ls2; ls2[0] = 0.f; ls2[1] = 0.f;

  const int rK = tid >> 4, sK = (tid & 15) ^ (rK & 15);  // 16-slot swizzle
  const int rV = tid >> 3, sV = (tid & 7) ^ (rV & 7);    // 8-slot swizzle
  const size_t koff0 = (size_t)(b * SEQ + rK) * (NKV * HD) + kvh * HD + sK * 8;
  const size_t voff0 = ((size_t)(b * NKV + kvh) * HD + rV) * SEQ + sV * 8;

  const float Ac = 72.13475204444817f;    // 50*log2(e)
  const float Bc = -24.044917348149389f;  // Ac * (-1/3)

  auto STAGE = [&](int buf, int t) {
    char* dK = ldsK + buf * 16384;
    char* dV = ldsV + buf * 16384;
    const bf16* ks = Kg + koff0 + (size_t)t * (64 * NKV * HD);
    const bf16* vs = VTg + voff0 + (size_t)t * 64;
    async16(dK + tid * 16, ks);
    async16(dK + (512 + tid) * 16, ks + (size_t)32 * (NKV * HD));
    async16(dV + tid * 16, vs);
    async16(dV + (512 + tid) * 16, vs + (size_t)64 * SEQ);
  };

  const int kvr0 = l31, kvr1 = 32 + l31;

#define QKT(SC, lKp)                                                     \
  do {                                                                   \
    _Pragma("unroll")                                                    \
    for (int r = 0; r < 16; r++) { (SC)[0][r] = 0.f; (SC)[1][r] = 0.f; } \
    _Pragma("unroll")                                                    \
    for (int kc = 0; kc < 8; kc++) {                                     \
      int slot = kc * 2 + hl;                                            \
      int off0 = (kvr0 << 8) | ((slot ^ (kvr0 & 15)) << 4);              \
      int off1 = (kvr1 << 8) | ((slot ^ (kvr1 & 15)) << 4);              \
      bf16x8 kf0 = *(const bf16x8_a*)((lKp) + off0);                     \
      bf16x8 kf1 = *(const bf16x8_a*)((lKp) + off1);                     \
      (SC)[0] = mfma32(kf0, qf[kc], (SC)[0]);                            \
      (SC)[1] = mfma32(kf1, qf[kc], (SC)[1]);                            \
    }                                                                    \
  } while (0)

// softcap+exp+pack; half-exchange via hardware permlane32_swap:
// for pair (a=u[2sub][c], b=u[2sub+1][c]): pswap -> {bu[c], bu[c+2]} directly.
#define SOFTMAX(SC, PB)                                                  \
  do {                                                                   \
    _Pragma("unroll")                                                    \
    for (int ntb = 0; ntb < 2; ntb++) {                                  \
      uint u[4][2];                                                      \
      _Pragma("unroll")                                                  \
      for (int r2 = 0; r2 < 8; r2++) {                                   \
        f32x2 z; z[0] = (SC)[ntb][2 * r2]; z[1] = (SC)[ntb][2 * r2 + 1]; \
        f32x2 z2 = z * z;                                                \
        f32x2 wv = z2 * Bc + Ac;                                         \
        f32x2 e = z * wv;                                                \
        float p0 = ex2(e[0]), p1 = ex2(e[1]);                            \
        ls2[0] += p0; ls2[1] += p1;                                      \
        u[r2 >> 1][r2 & 1] = pkbf16(p0, p1);                             \
      }                                                                  \
      _Pragma("unroll")                                                  \
      for (int sub = 0; sub < 2; sub++) {                                \
        u32x2 r0 = pswap(u[2 * sub][0], u[2 * sub + 1][0]);              \
        u32x2 r1 = pswap(u[2 * sub][1], u[2 * sub + 1][1]);              \
        u32x4 bu;                                                        \
        bu[0] = r0[0];                                                   \
        bu[1] = r1[0];                                                   \
        bu[2] = r0[1];                                                   \
        bu[3] = r1[1];                                                   \
        (PB)[ntb * 2 + sub] = __builtin_bit_cast(bf16x8, bu);            \
      }                                                                  \
    }                                                                    \
  } while (0)

#define PVACC(PB, lVp)                                                   \
  do {                                                                   \
    _Pragma("unroll")                                                    \
    for (int kvb = 0; kvb < 4; kvb++) {                                  \
      int slot = kvb * 2 + hl;                                           \
      _Pragma("unroll")                                                  \
      for (int dt = 0; dt < 4; dt++) {                                   \
        int d = dt * 32 + l31;                                           \
        int off = (d << 7) | ((slot ^ (d & 7)) << 4);                    \
        bf16x8 vf = *(const bf16x8_a*)((lVp) + off);                     \
        oT[dt] = mfma32(vf, (PB)[kvb], oT[dt]);                          \
      }                                                                  \
    }                                                                    \
  } while (0)

  constexpr int NT = SEQ / 64;  // 32
  STAGE(0, 0);
  STAGE(1, 1);
  WAITV(4);  // tile 0 drained (tile 1's 4 may pend)
  BAR();     // cross-wave: tile 0 visible

  f32x16 scA[2], scB[2];
  bf16x8 pb[4];
  QKT(scA, ldsK);  // tile 0, buf 0

  for (int it = 0; it < NT / 2; ++it) {
    const int t0 = 2 * it;
    {
      const int t = t0;
      BAR();  // all waves' tile-(t-1) reads consumed -> safe to overwrite its buf
      if (t + 2 < NT) STAGE((t + 2) % 3, t + 2);
      SOFTMAX(scA, pb);
      if (t + 2 < NT) { WAITV(4); } else { WAITV(0); }  // drain tile t+1
      BAR();  // cross-wave: tile t+1 staged & visible
      __builtin_amdgcn_s_setprio(1);
      if (t + 1 < NT) QKT(scB, ldsK + ((t + 1) % 3) * 16384);
      PVACC(pb, ldsV + (t % 3) * 16384);
      __builtin_amdgcn_s_setprio(0);
    }
    {
      const int t = t0 + 1;
      BAR();
      if (t + 2 < NT) STAGE((t + 2) % 3, t + 2);
      SOFTMAX(scB, pb);
      if (t + 2 < NT) { WAITV(4); } else { WAITV(0); }
      BAR();
      __builtin_amdgcn_s_setprio(1);
      if (t + 1 < NT) QKT(scA, ldsK + ((t + 1) % 3) * 16384);
      PVACC(pb, ldsV + (t % 3) * 16384);
      __builtin_amdgcn_s_setprio(0);
    }
  }
#undef QKT
#undef SOFTMAX
#undef PVACC

  float lsum = ls2[0] + ls2[1];
  float lsf = lsum + __shfl_xor(lsum, 32);
  float inv = 1.0f / lsf;
  bf16* ob = O + (size_t)qrow * (NHEAD * HD) + h * HD;
#pragma unroll
  for (int dt = 0; dt < 4; dt++)
#pragma unroll
    for (int g = 0; g < 4; g++) {
      u32x2 pr;
      pr[0] = pkbf16(oT[dt][4 * g] * inv, oT[dt][4 * g + 1] * inv);
      pr[1] = pkbf16(oT[dt][4 * g + 2] * inv, oT[dt][4 * g + 3] * inv);
      *(u32x2_a*)(ob + dt * 32 + 8 * g + 4 * hl) = pr;
    }
}

extern "C" void kernel_launch(void* const* d_in, const int* in_sizes, int n_in,
                              void* d_out, int out_size, void* d_ws, size_t ws_size,
                              hipStream_t stream) {
  const float* X  = (const float*)d_in[0];
  const float* Wq = (const float*)d_in[1];
  const float* Wk = (const float*)d_in[2];
  const float* Wv = (const float*)d_in[3];
  const float* Wo = (const float*)d_in[4];
  float* out = (float*)d_out;

  char* ws = (char*)d_ws;
  size_t off = 0;
  auto alloc = [&](size_t bytes) {
    void* p = ws + off;
    off += (bytes + 255) & ~(size_t)255;
    return p;
  };
  bf16* Xb  = (bf16*)alloc((size_t)MROWS * HID * 2);
  // WqT/WkT/WvT adjacent & contiguous -> fused BT [4096][2048]
  bf16* WqT = (bf16*)alloc((size_t)2048 * 2048 * 2);
  bf16* WkT = (bf16*)alloc((size_t)1024 * 2048 * 2);
  bf16* WvT = (bf16*)alloc((size_t)1024 * 2048 * 2);
  bf16* WoT = (bf16*)alloc((size_t)2048 * 2048 * 2);
  bf16* Qb  = (bf16*)alloc((size_t)MROWS * 2048 * 2);
  bf16* Kb  = (bf16*)alloc((size_t)MROWS * 1024 * 2);
  bf16* Vb  = (bf16*)alloc((size_t)MROWS * 1024 * 2);
  bf16* VTb = (bf16*)alloc((size_t)16 * 128 * 2048 * 2);
  bf16* AOb = (bf16*)alloc((size_t)MROWS * 2048 * 2);
  float* ct = (float*)alloc((size_t)SEQ * 64 * 4);
  float* st = (float*)alloc((size_t)SEQ * 64 * 4);

  prep<<<dim3(32, 32, 6), 256, 0, stream>>>(X, Wq, Wk, Wv, Wo, Xb, WqT, WkT, WvT, WoT, ct, st);
  gemm8p<1><<<dim3(16, 16), 512, 0, stream>>>(Xb, WqT, Qb, Kb, Vb, MROWS, 4096, 2048, ct, st);
  vtrans<<<dim3(32, 2, 16), 256, 0, stream>>>(Vb, VTb);
  attn10<<<dim3(8, 16, 2), 512, 0, stream>>>(Qb, Kb, VTb, AOb);
  gemm2p<<<dim3(16, 16), 512, 0, stream>>>(AOb, WoT, out, MROWS, 2048, 2048);

  (void)in_sizes; (void)n_in; (void)out_size; (void)ws_size;
}